// Round 5
// baseline (786.066 us; speedup 1.0000x reference)
//
#include <hip/hip_runtime.h>
#include <stdint.h>

#define NN 50000
#define NE 1600000
#define FI 512
#define DD 512
#define NC 40
#define HW 1536
#define SCAN_NB 49        // ceil(NN/1024)
#define CB 256            // histogram blocks
#define EPB (NE / CB)     // 6250 edges per histogram block
#define HWRD 12500        // 50000 bins / 4 bytes per word

typedef __attribute__((ext_vector_type(8))) short short8;
typedef __attribute__((ext_vector_type(4))) float float4v;
typedef __attribute__((ext_vector_type(2))) float f32x2;

static __device__ __forceinline__ unsigned short f2b(float f) {
    union { float f; unsigned int i; } v; v.f = f;
    unsigned int r = v.i + 0x7fffu + ((v.i >> 16) & 1u);
    return (unsigned short)(r >> 16);
}
static __device__ __forceinline__ float blo(unsigned int u) {
    union { unsigned int i; float f; } v; v.i = u << 16; return v.f;
}
static __device__ __forceinline__ float bhi(unsigned int u) {
    union { unsigned int i; float f; } v; v.i = u & 0xffff0000u; return v.f;
}
static __device__ __forceinline__ unsigned char f2e4m3(float f) {
    return (unsigned char)(__builtin_amdgcn_cvt_pk_fp8_f32(f, f, 0, false) & 0xFF);
}
static __device__ __forceinline__ void async_copy16(void* lds, const void* g) {
    __builtin_amdgcn_global_load_lds((const __attribute__((address_space(1))) void*)g,
                                     (__attribute__((address_space(3))) void*)lds, 16, 0, 0);
}

// ================= MEGA1: [count_row | count_col | convx | transpose | wcat] =================
__global__ __launch_bounds__(256) void mega1_kernel(
    const int* __restrict__ er, const int* __restrict__ ec,
    const float* __restrict__ x, const float* __restrict__ W1, const float* __restrict__ W2,
    unsigned char* __restrict__ rank, unsigned* __restrict__ hist_row, unsigned* __restrict__ hist_col,
    unsigned short* __restrict__ xb, unsigned short* __restrict__ w1t, unsigned short* __restrict__ wct) {
    __shared__ unsigned hb[HWRD];
    int bid = blockIdx.x, tid = threadIdx.x;
    if (bid < 2 * CB) {
        for (int w = tid; w < HWRD; w += 256) hb[w] = 0;
        __syncthreads();
        int b = bid & (CB - 1);
        int e0 = b * EPB;
        if (bid < CB) {   // row histogram + rank
            for (int e = e0 + tid; e < e0 + EPB; e += 256) {
                int r = er[e];
                unsigned sh = (r & 3) * 8;
                unsigned old = atomicAdd(&hb[r >> 2], 1u << sh);
                rank[e] = (unsigned char)((old >> sh) & 0xFFu);
            }
        } else {          // col histogram (in-degree)
            for (int e = e0 + tid; e < e0 + EPB; e += 256) {
                int c = ec[e];
                atomicAdd(&hb[c >> 2], 1u << ((c & 3) * 8));
            }
        }
        __syncthreads();
        unsigned* dst = (bid < CB ? hist_row : hist_col) + (size_t)b * HWRD;
        for (int w = tid; w < HWRD; w += 256) dst[w] = hb[w];
        return;
    }
    bid -= 2 * CB;
    if (bid < 12500) {    // convx: fp32 -> bf16, 8 elems/thread
        int t = bid * 256 + tid;
        const float* xf = x + (size_t)t * 8;
        float4 v0 = *(const float4*)(xf);
        float4 v1 = *(const float4*)(xf + 4);
        uint4 u;
        u.x = ((unsigned)f2b(v0.y) << 16) | f2b(v0.x);
        u.y = ((unsigned)f2b(v0.w) << 16) | f2b(v0.z);
        u.z = ((unsigned)f2b(v1.y) << 16) | f2b(v1.x);
        u.w = ((unsigned)f2b(v1.w) << 16) | f2b(v1.z);
        *(uint4*)(xb + (size_t)t * 8) = u;
        return;
    }
    bid -= 12500;
    if (bid < 1024) {     // transpose W1 -> bf16 w1t[n][k]
        int t = bid * 256 + tid;
        int n = t & 511, k = t >> 9;
        w1t[n * 512 + k] = f2b(W1[(size_t)k * 512 + n]);
        return;
    }
    bid -= 1024;
    {                     // wcat: combined final weight, transposed, bf16 (48*1536)
        int t = bid * 256 + tid;
        if (t < 48 * HW) {
            int k = t % HW, n = t / HW;
            float v = 0.f;
            if (n < NC) {
                if (k < 512)       v = W2[(size_t)k * NC + n] + W2[(size_t)(k + 512) * NC + n];
                else if (k < 1024) v = W2[(size_t)(k + 512) * NC + n] + W2[(size_t)(k + 1024) * NC + n];
                else               v = W2[(size_t)(k + 1024) * NC + n];
            }
            wct[n * HW + k] = f2b(v);
        }
    }
}

// ================= PREP: SWAR prefix over blocks (rows) + reduce (cols) =================
__global__ __launch_bounds__(256) void prep_kernel(
    const unsigned* __restrict__ hist_row, const unsigned* __restrict__ hist_col,
    unsigned* __restrict__ base_words, int* __restrict__ cntI, int* __restrict__ degI) {
    int t = blockIdx.x * 256 + threadIdx.x;
    if (t < HWRD) {
        unsigned acc = 0;   // 4 packed byte counters; totals <256/byte so no carry
        for (int b = 0; b < CB; ++b) {
            unsigned h = hist_row[(size_t)b * HWRD + t];
            base_words[(size_t)b * HWRD + t] = acc;
            acc += h;
        }
        int4 o; o.x = acc & 0xFF; o.y = (acc >> 8) & 0xFF; o.z = (acc >> 16) & 0xFF; o.w = (acc >> 24) & 0xFF;
        ((int4*)cntI)[t] = o;
    } else if (t < 2 * HWRD) {
        int w = t - HWRD;
        unsigned acc = 0;
        for (int b = 0; b < CB; ++b) acc += hist_col[(size_t)b * HWRD + w];
        int4 o; o.x = acc & 0xFF; o.y = (acc >> 8) & 0xFF; o.z = (acc >> 16) & 0xFF; o.w = (acc >> 24) & 0xFF;
        ((int4*)degI)[w] = o;
    }
}

// ================= scans =================
__global__ __launch_bounds__(1024) void scan1_kernel(const int* __restrict__ cnt,
                                                     int* __restrict__ excl, int* __restrict__ bsum) {
    __shared__ int buf[1024];
    int tid = threadIdx.x, gid = blockIdx.x * 1024 + tid;
    int v = (gid < NN) ? cnt[gid] : 0;
    buf[tid] = v;
    __syncthreads();
    int acc = v;
    for (int off = 1; off < 1024; off <<= 1) {
        int t = (tid >= off) ? buf[tid - off] : 0;
        __syncthreads();
        acc += t;
        buf[tid] = acc;
        __syncthreads();
    }
    if (gid < NN) excl[gid] = acc - v;
    if (tid == 1023) bsum[blockIdx.x] = acc;
}

__global__ void scan2_kernel(const int* __restrict__ bsum, int* __restrict__ boff) {
    int tid = threadIdx.x;  // one wave, SCAN_NB=49
    int orig = (tid < SCAN_NB) ? bsum[tid] : 0;
    int v = orig;
    #pragma unroll
    for (int off = 1; off < 64; off <<= 1) {
        int t = __shfl_up(v, off, 64);
        if (tid >= off) v += t;
    }
    if (tid < SCAN_NB) boff[tid] = v - orig;
}

__global__ void scan3_kernel(int* __restrict__ rowptr, const int* __restrict__ boff,
                             const int* __restrict__ deg, float* __restrict__ dinv) {
    int gid = blockIdx.x * 256 + threadIdx.x;
    if (gid < NN) {
        rowptr[gid] += boff[gid >> 10];
        dinv[gid] = rsqrtf((float)(deg[gid] + 1));
    }
    if (gid == 0) rowptr[NN] = NE;
}

// ================= MEGA2: [scatter | gemm1]  (R1 structure: known-fastest) =================
__global__ __launch_bounds__(256) void mega2_kernel(
    const int* __restrict__ er, const int* __restrict__ ec, const int* __restrict__ rowptr,
    const unsigned char* __restrict__ rank, const unsigned char* __restrict__ base8,
    int* __restrict__ colss,
    const unsigned short* __restrict__ xb, const unsigned short* __restrict__ w1t,
    const float* __restrict__ b1, unsigned short* __restrict__ tbuf, unsigned char* __restrict__ t8) {
    __shared__ __align__(16) unsigned short As[128 * 32];
    __shared__ __align__(16) unsigned short Bs[128 * 32];
    int bid = blockIdx.x;
    if (bid < CB) {   // scatter (atomic-free), one histogram slice per block
        int tid = threadIdx.x;
        const unsigned char* bb = base8 + (size_t)bid * 50000;
        int e0 = bid * EPB;
        int e = e0 + tid;
        #pragma unroll 4
        for (int it = 0; it < EPB / 256; ++it, e += 256) {
            int r = er[e], c = ec[e];
            colss[rowptr[r] + (int)bb[r] + (int)rank[e]] = c;
        }
        if (e < e0 + EPB) {   // tail: EPB % 256 = 106 edges
            int r = er[e], c = ec[e];
            colss[rowptr[r] + (int)bb[r] + (int)rank[e]] = c;
        }
        return;
    }
    bid -= CB;
    // ---- gemm1: t = relu(x@W1+b1) -> tbuf bf16 + t8 fp8 ----
    const int m0 = (bid >> 2) * 128, n0 = (bid & 3) * 128;
    const int tid = threadIdx.x;
    const int wave = tid >> 6, lane = tid & 63;
    const int q = lane >> 4, c = lane & 15;
    const int wm = wave & 1, wn = wave >> 1;

    float4v acc[4][4];
    for (int i = 0; i < 4; ++i)
        for (int j = 0; j < 4; ++j)
            acc[i][j] = (float4v){0.f, 0.f, 0.f, 0.f};

    for (int k0 = 0; k0 < FI; k0 += 32) {
        __syncthreads();
        #pragma unroll
        for (int h = 0; h < 2; ++h) {
            int chunk = h * 256 + wave * 64 + lane;
            int r = chunk >> 2, kc = chunk & 3;
            int gm = m0 + r; gm = gm < NN ? gm : NN - 1;
            async_copy16((char*)As + (size_t)(h * 256 + wave * 64) * 16,
                         xb + (size_t)gm * FI + k0 + kc * 8);
            async_copy16((char*)Bs + (size_t)(h * 256 + wave * 64) * 16,
                         w1t + (size_t)(n0 + r) * FI + k0 + kc * 8);
        }
        __syncthreads();
        short8 a[4], b[4];
        #pragma unroll
        for (int mi = 0; mi < 4; ++mi)
            a[mi] = *(const short8*)(As + ((wm * 64 + mi * 16 + c) * 32 + q * 8));
        #pragma unroll
        for (int ni = 0; ni < 4; ++ni)
            b[ni] = *(const short8*)(Bs + ((wn * 64 + ni * 16 + c) * 32 + q * 8));
        #pragma unroll
        for (int mi = 0; mi < 4; ++mi)
            #pragma unroll
            for (int ni = 0; ni < 4; ++ni)
                acc[mi][ni] = __builtin_amdgcn_mfma_f32_16x16x32_bf16(a[mi], b[ni], acc[mi][ni], 0, 0, 0);
    }
    #pragma unroll
    for (int ni = 0; ni < 4; ++ni) {
        int col = n0 + wn * 64 + ni * 16 + c;
        float bias = b1[col];
        #pragma unroll
        for (int mi = 0; mi < 4; ++mi) {
            int rbase = m0 + wm * 64 + mi * 16 + q * 4;
            #pragma unroll
            for (int r = 0; r < 4; ++r) {
                int row = rbase + r;
                if (row < NN) {
                    float v = acc[mi][ni][r] + bias;
                    v = v > 0.f ? v : 0.f;
                    tbuf[(size_t)row * FI + col] = f2b(v);
                    t8[(size_t)row * FI + col] = f2e4m3(v);
                }
            }
        }
    }
}

// ================= SpMM (fp8 gather, column-sliced + XCD-pinned) =================
// Feature dim split into 8 slices of 64B fp8. slice = blockIdx%8 -> XCD via round-robin
// dispatch, so each slice's 3.2MB gather working set is resident in ONE XCD's 4MB L2
// (was: 25.6MB working set @ 84% L2 miss -> L3 latency). Per block: 32 rows x 8 thr/row;
// per edge 8 lanes read one contiguous 64B chunk. All output writes whole-line aligned.
#define DEC8(g, vv)                                                        \
    {   f32x2 p0 = __builtin_amdgcn_cvt_pk_f32_fp8((int)(g).x, false);      \
        f32x2 p1 = __builtin_amdgcn_cvt_pk_f32_fp8((int)(g).x, true);       \
        f32x2 p2 = __builtin_amdgcn_cvt_pk_f32_fp8((int)(g).y, false);      \
        f32x2 p3 = __builtin_amdgcn_cvt_pk_f32_fp8((int)(g).y, true);       \
        a0 += (vv) * p0.x; a1 += (vv) * p0.y;                               \
        a2 += (vv) * p1.x; a3 += (vv) * p1.y;                               \
        a4 += (vv) * p2.x; a5 += (vv) * p2.y;                               \
        a6 += (vv) * p3.x; a7 += (vv) * p3.y; }

__global__ __launch_bounds__(256) void spmm_kernel(
    const unsigned char* __restrict__ src8, const unsigned short* __restrict__ srcb,
    unsigned short* __restrict__ dstb, unsigned char* __restrict__ dst8,
    const int* __restrict__ rowptr, const int* __restrict__ cols,
    const float* __restrict__ dinv, int write8) {
    int s = blockIdx.x & 7;            // slice -> XCD (round-robin dispatch)
    int rb = blockIdx.x >> 3;
    int sub = threadIdx.x & 7, rg = threadIdx.x >> 3;
    int i = rb * 32 + rg;
    if (i >= NN) return;
    int fo = s * 64 + sub * 8;         // feature offset within row (shorts for bf16, bytes for fp8)
    const float di = dinv[i];
    const unsigned char* bin = src8 + fo;

    float a0, a1, a2, a3, a4, a5, a6, a7;
    {   // self-loop from the bf16 copy
        uint4 u = *(const uint4*)(srcb + (size_t)i * FI + fo);
        float sc = di * di;
        a0 = sc * blo(u.x); a1 = sc * bhi(u.x);
        a2 = sc * blo(u.y); a3 = sc * bhi(u.y);
        a4 = sc * blo(u.z); a5 = sc * bhi(u.z);
        a6 = sc * blo(u.w); a7 = sc * bhi(u.w);
    }
    int k = rowptr[i], e = rowptr[i + 1];
    for (; k + 4 <= e; k += 4) {
        int c0 = cols[k + 0];
        int c1 = cols[k + 1];
        int c2 = cols[k + 2];
        int c3 = cols[k + 3];
        float w0 = dinv[c0], w1 = dinv[c1], w2 = dinv[c2], w3 = dinv[c3];
        uint2 g0 = *(const uint2*)(bin + (size_t)c0 * FI);
        uint2 g1 = *(const uint2*)(bin + (size_t)c1 * FI);
        uint2 g2 = *(const uint2*)(bin + (size_t)c2 * FI);
        uint2 g3 = *(const uint2*)(bin + (size_t)c3 * FI);
        float v0 = di * w0, v1 = di * w1, v2 = di * w2, v3 = di * w3;
        DEC8(g0, v0) DEC8(g1, v1) DEC8(g2, v2) DEC8(g3, v3)
    }
    for (; k < e; ++k) {
        int cc = cols[k];
        float v = di * dinv[cc];
        uint2 g = *(const uint2*)(bin + (size_t)cc * FI);
        DEC8(g, v)
    }
    uint4 o;
    o.x = ((unsigned int)f2b(a1) << 16) | f2b(a0);
    o.y = ((unsigned int)f2b(a3) << 16) | f2b(a2);
    o.z = ((unsigned int)f2b(a5) << 16) | f2b(a4);
    o.w = ((unsigned int)f2b(a7) << 16) | f2b(a6);
    *(uint4*)(dstb + (size_t)i * FI + fo) = o;
    if (write8) {
        unsigned r0 = (unsigned)__builtin_amdgcn_cvt_pk_fp8_f32(a0, a1, 0, false);
        r0 = (unsigned)__builtin_amdgcn_cvt_pk_fp8_f32(a2, a3, (int)r0, true);
        unsigned r1 = (unsigned)__builtin_amdgcn_cvt_pk_fp8_f32(a4, a5, 0, false);
        r1 = (unsigned)__builtin_amdgcn_cvt_pk_fp8_f32(a6, a7, (int)r1, true);
        uint2 o8; o8.x = r0; o8.y = r1;
        *(uint2*)(dst8 + (size_t)i * FI + fo) = o8;
    }
}

// ================= GEMM2 + log_softmax (fp32 out) =================
__global__ __launch_bounds__(256) void gemm2_kernel(
    const unsigned short* __restrict__ tb, const unsigned short* __restrict__ s1b,
    const unsigned short* __restrict__ s2b, const unsigned short* __restrict__ wct,
    const float* __restrict__ b2p, float* __restrict__ out) {
    int wave = threadIdx.x >> 6, lane = threadIdx.x & 63;
    int q = lane >> 4, c = lane & 15;
    int row0 = blockIdx.x * 64 + wave * 16;
    int ra = row0 + c; ra = ra < NN ? ra : NN - 1;
    const unsigned short* seg[3] = { tb + (size_t)ra * FI + q * 8,
                                     s1b + (size_t)ra * FI + q * 8,
                                     s2b + (size_t)ra * FI + q * 8 };
    const unsigned short* bp0 = wct + (size_t)(c)      * HW + q * 8;
    const unsigned short* bp1 = wct + (size_t)(16 + c) * HW + q * 8;
    const unsigned short* bp2 = wct + (size_t)(32 + c) * HW + q * 8;

    float4v A0 = {0.f,0.f,0.f,0.f}, A1 = {0.f,0.f,0.f,0.f}, A2 = {0.f,0.f,0.f,0.f};
    #pragma unroll
    for (int s = 0; s < 3; ++s) {
        const unsigned short* ap = seg[s];
        #pragma unroll 4
        for (int k0 = 0; k0 < 512; k0 += 32) {
            short8 a  = *(const short8*)(ap + k0);
            short8 b0 = *(const short8*)(bp0 + s * 512 + k0);
            short8 b1 = *(const short8*)(bp1 + s * 512 + k0);
            short8 b2 = *(const short8*)(bp2 + s * 512 + k0);
            A0 = __builtin_amdgcn_mfma_f32_16x16x32_bf16(a, b0, A0, 0, 0, 0);
            A1 = __builtin_amdgcn_mfma_f32_16x16x32_bf16(a, b1, A1, 0, 0, 0);
            A2 = __builtin_amdgcn_mfma_f32_16x16x32_bf16(a, b2, A2, 0, 0, 0);
        }
    }
    float bias0 = b2p[c];
    float bias1 = b2p[16 + c];
    float bias2 = (c < 8) ? b2p[32 + c] : 0.f;
    #pragma unroll
    for (int r = 0; r < 4; ++r) {
        float v0 = A0[r] + bias0;
        float v1 = A1[r] + bias1;
        float v2 = (c < 8) ? (A2[r] + bias2) : -1e30f;
        float mx = fmaxf(fmaxf(v0, v1), v2);
        #pragma unroll
        for (int d = 1; d < 16; d <<= 1) mx = fmaxf(mx, __shfl_xor(mx, d, 64));
        float s = __expf(v0 - mx) + __expf(v1 - mx) + ((c < 8) ? __expf(v2 - mx) : 0.f);
        #pragma unroll
        for (int d = 1; d < 16; d <<= 1) s += __shfl_xor(s, d, 64);
        float lse = mx + __logf(s);
        int rowg = row0 + q * 4 + r;
        if (rowg < NN) {
            out[(size_t)rowg * NC + c]      = v0 - lse;
            out[(size_t)rowg * NC + 16 + c] = v1 - lse;
            if (c < 8) out[(size_t)rowg * NC + 32 + c] = v2 - lse;
        }
    }
}

extern "C" void kernel_launch(void* const* d_in, const int* in_sizes, int n_in,
                              void* d_out, int out_size, void* d_ws, size_t ws_size,
                              hipStream_t stream) {
    const float* x  = (const float*)d_in[0];
    const int*   er = (const int*)d_in[1];
    const int*   ec = (const int*)d_in[2];
    const float* W1 = (const float*)d_in[3];
    const float* b1 = (const float*)d_in[4];
    const float* W2 = (const float*)d_in[5];
    const float* b2 = (const float*)d_in[6];
    float* out = (float*)d_out;

    char* p = (char*)d_ws;
    auto alloc = [&](size_t bytes) { char* r = p; p += (bytes + 255) & ~((size_t)255); return r; };
    int*      cntI   = (int*)      alloc((size_t)NN * 4);
    int*      degI   = (int*)      alloc((size_t)NN * 4);
    int*      rowptr = (int*)      alloc((size_t)(NN + 1) * 4);
    float*    dinv   = (float*)    alloc((size_t)NN * 4);
    int*      bsum   = (int*)      alloc((size_t)SCAN_NB * 4);
    int*      boff   = (int*)      alloc((size_t)SCAN_NB * 4);
    unsigned char* rank = (unsigned char*)alloc((size_t)NE);
    int*      colss  = (int*)      alloc((size_t)NE * 4);
    unsigned* hist_row = (unsigned*)alloc((size_t)CB * HWRD * 4);   // 12.8MB, dead after prep
    unsigned* hist_col = (unsigned*)alloc((size_t)CB * HWRD * 4);   // 12.8MB, dead after prep
    unsigned* base_w   = (unsigned*)alloc((size_t)CB * HWRD * 4);   // 12.8MB, dead after mega2
    unsigned short* w1t  = (unsigned short*)alloc((size_t)512 * 512 * 2);
    unsigned short* wct  = (unsigned short*)alloc((size_t)48 * HW * 2);
    unsigned short* xb   = (unsigned short*)alloc((size_t)NN * FI * 2);
    unsigned short* tbuf = (unsigned short*)alloc((size_t)NN * FI * 2);
    unsigned short* s1b  = (unsigned short*)alloc((size_t)NN * FI * 2);
    unsigned char*  s18  = (unsigned char*)alloc((size_t)NN * FI);
    // aliases: t8 over the (dead after prep) histograms; s2 over (dead after gemm1) xb
    unsigned char*  t8  = (unsigned char*)hist_row;   // 25.6MB needed; hist_row+hist_col = 25.6MB
    unsigned short* s2b = xb;

    // L1: independent prep work, count parts first
    mega1_kernel<<<2 * CB + 12500 + 1024 + 288, 256, 0, stream>>>(
        er, ec, x, W1, W2, rank, hist_row, hist_col, xb, w1t, wct);
    // L2: cross-block prefix (rows) + reduce (cols)
    prep_kernel<<<(2 * HWRD + 255) / 256, 256, 0, stream>>>(hist_row, hist_col, base_w, cntI, degI);
    // L3-5: rowptr scan + dinv
    scan1_kernel<<<SCAN_NB, 1024, 0, stream>>>(cntI, rowptr, bsum);
    scan2_kernel<<<1, 64, 0, stream>>>(bsum, boff);
    scan3_kernel<<<(NN + 255) / 256, 256, 0, stream>>>(rowptr, boff, degI, dinv);
    // L6: scatter (slice blocks) | gemm1 -- t8 overwrites hist_* (dead), base_w still live
    mega2_kernel<<<CB + ((NN + 127) / 128) * 4, 256, 0, stream>>>(
        er, ec, rowptr, rank, (const unsigned char*)base_w, colss, xb, w1t, b1, tbuf, t8);
    // L7-8: SpMMs (fp8 gather, column-sliced, XCD-pinned; 8 slices x 1563 row-blocks)
    spmm_kernel<<<((NN + 31) / 32) * 8, 256, 0, stream>>>(t8, tbuf, s1b, s18, rowptr, colss, dinv, 1);
    spmm_kernel<<<((NN + 31) / 32) * 8, 256, 0, stream>>>(s18, s1b, s2b, (unsigned char*)nullptr, rowptr, colss, dinv, 0);
    // L9: final GEMM + log_softmax
    gemm2_kernel<<<(NN + 63) / 64, 256, 0, stream>>>(tbuf, s1b, s2b, wct, b2, out);
}

// Round 6
// 644.547 us; speedup vs baseline: 1.2196x; 1.2196x over previous
//
#include <hip/hip_runtime.h>
#include <stdint.h>

#define NN 50000
#define NE 1600000
#define FI 512
#define DD 512
#define NC 40
#define HW 1536
#define SCAN_NB 49        // ceil(NN/1024)
#define CB 256            // histogram blocks
#define EPB (NE / CB)     // 6250 edges per histogram block
#define HWRD 12500        // 50000 bins / 4 bytes per word

typedef __attribute__((ext_vector_type(8))) short short8;
typedef __attribute__((ext_vector_type(4))) float float4v;
typedef __attribute__((ext_vector_type(2))) float f32x2;

static __device__ __forceinline__ unsigned short f2b(float f) {
    union { float f; unsigned int i; } v; v.f = f;
    unsigned int r = v.i + 0x7fffu + ((v.i >> 16) & 1u);
    return (unsigned short)(r >> 16);
}
static __device__ __forceinline__ float blo(unsigned int u) {
    union { unsigned int i; float f; } v; v.i = u << 16; return v.f;
}
static __device__ __forceinline__ float bhi(unsigned int u) {
    union { unsigned int i; float f; } v; v.i = u & 0xffff0000u; return v.f;
}
static __device__ __forceinline__ unsigned char f2e4m3(float f) {
    return (unsigned char)(__builtin_amdgcn_cvt_pk_fp8_f32(f, f, 0, false) & 0xFF);
}
static __device__ __forceinline__ void async_copy16(void* lds, const void* g) {
    __builtin_amdgcn_global_load_lds((const __attribute__((address_space(1))) void*)g,
                                     (__attribute__((address_space(3))) void*)lds, 16, 0, 0);
}

// ================= MEGA1: [count_row | count_col | convx | transpose | wcat] =================
__global__ __launch_bounds__(256) void mega1_kernel(
    const int* __restrict__ er, const int* __restrict__ ec,
    const float* __restrict__ x, const float* __restrict__ W1, const float* __restrict__ W2,
    unsigned char* __restrict__ rank, unsigned* __restrict__ hist_row, unsigned* __restrict__ hist_col,
    unsigned short* __restrict__ xb, unsigned short* __restrict__ w1t, unsigned short* __restrict__ wct) {
    __shared__ unsigned hb[HWRD];
    int bid = blockIdx.x, tid = threadIdx.x;
    if (bid < 2 * CB) {
        for (int w = tid; w < HWRD; w += 256) hb[w] = 0;
        __syncthreads();
        int b = bid & (CB - 1);
        int e0 = b * EPB;
        if (bid < CB) {   // row histogram + rank
            for (int e = e0 + tid; e < e0 + EPB; e += 256) {
                int r = er[e];
                unsigned sh = (r & 3) * 8;
                unsigned old = atomicAdd(&hb[r >> 2], 1u << sh);
                rank[e] = (unsigned char)((old >> sh) & 0xFFu);
            }
        } else {          // col histogram (in-degree)
            for (int e = e0 + tid; e < e0 + EPB; e += 256) {
                int c = ec[e];
                atomicAdd(&hb[c >> 2], 1u << ((c & 3) * 8));
            }
        }
        __syncthreads();
        unsigned* dst = (bid < CB ? hist_row : hist_col) + (size_t)b * HWRD;
        for (int w = tid; w < HWRD; w += 256) dst[w] = hb[w];
        return;
    }
    bid -= 2 * CB;
    if (bid < 12500) {    // convx: fp32 -> bf16, 8 elems/thread
        int t = bid * 256 + tid;
        const float* xf = x + (size_t)t * 8;
        float4 v0 = *(const float4*)(xf);
        float4 v1 = *(const float4*)(xf + 4);
        uint4 u;
        u.x = ((unsigned)f2b(v0.y) << 16) | f2b(v0.x);
        u.y = ((unsigned)f2b(v0.w) << 16) | f2b(v0.z);
        u.z = ((unsigned)f2b(v1.y) << 16) | f2b(v1.x);
        u.w = ((unsigned)f2b(v1.w) << 16) | f2b(v1.z);
        *(uint4*)(xb + (size_t)t * 8) = u;
        return;
    }
    bid -= 12500;
    if (bid < 1024) {     // transpose W1 -> bf16 w1t[n][k]
        int t = bid * 256 + tid;
        int n = t & 511, k = t >> 9;
        w1t[n * 512 + k] = f2b(W1[(size_t)k * 512 + n]);
        return;
    }
    bid -= 1024;
    {                     // wcat: combined final weight, transposed, bf16 (48*1536)
        int t = bid * 256 + tid;
        if (t < 48 * HW) {
            int k = t % HW, n = t / HW;
            float v = 0.f;
            if (n < NC) {
                if (k < 512)       v = W2[(size_t)k * NC + n] + W2[(size_t)(k + 512) * NC + n];
                else if (k < 1024) v = W2[(size_t)(k + 512) * NC + n] + W2[(size_t)(k + 1024) * NC + n];
                else               v = W2[(size_t)(k + 1024) * NC + n];
            }
            wct[n * HW + k] = f2b(v);
        }
    }
}

// ================= PREP: SWAR prefix over blocks (rows) + reduce (cols) =================
__global__ __launch_bounds__(256) void prep_kernel(
    const unsigned* __restrict__ hist_row, const unsigned* __restrict__ hist_col,
    unsigned* __restrict__ base_words, int* __restrict__ cntI, int* __restrict__ degI) {
    int t = blockIdx.x * 256 + threadIdx.x;
    if (t < HWRD) {
        unsigned acc = 0;   // 4 packed byte counters; totals <256/byte so no carry
        for (int b = 0; b < CB; ++b) {
            unsigned h = hist_row[(size_t)b * HWRD + t];
            base_words[(size_t)b * HWRD + t] = acc;
            acc += h;
        }
        int4 o; o.x = acc & 0xFF; o.y = (acc >> 8) & 0xFF; o.z = (acc >> 16) & 0xFF; o.w = (acc >> 24) & 0xFF;
        ((int4*)cntI)[t] = o;
    } else if (t < 2 * HWRD) {
        int w = t - HWRD;
        unsigned acc = 0;
        for (int b = 0; b < CB; ++b) acc += hist_col[(size_t)b * HWRD + w];
        int4 o; o.x = acc & 0xFF; o.y = (acc >> 8) & 0xFF; o.z = (acc >> 16) & 0xFF; o.w = (acc >> 24) & 0xFF;
        ((int4*)degI)[w] = o;
    }
}

// ================= scans =================
__global__ __launch_bounds__(1024) void scan1_kernel(const int* __restrict__ cnt,
                                                     int* __restrict__ excl, int* __restrict__ bsum) {
    __shared__ int buf[1024];
    int tid = threadIdx.x, gid = blockIdx.x * 1024 + tid;
    int v = (gid < NN) ? cnt[gid] : 0;
    buf[tid] = v;
    __syncthreads();
    int acc = v;
    for (int off = 1; off < 1024; off <<= 1) {
        int t = (tid >= off) ? buf[tid - off] : 0;
        __syncthreads();
        acc += t;
        buf[tid] = acc;
        __syncthreads();
    }
    if (gid < NN) excl[gid] = acc - v;
    if (tid == 1023) bsum[blockIdx.x] = acc;
}

__global__ void scan2_kernel(const int* __restrict__ bsum, int* __restrict__ boff) {
    int tid = threadIdx.x;  // one wave, SCAN_NB=49
    int orig = (tid < SCAN_NB) ? bsum[tid] : 0;
    int v = orig;
    #pragma unroll
    for (int off = 1; off < 64; off <<= 1) {
        int t = __shfl_up(v, off, 64);
        if (tid >= off) v += t;
    }
    if (tid < SCAN_NB) boff[tid] = v - orig;
}

__global__ void scan3_kernel(int* __restrict__ rowptr, const int* __restrict__ boff,
                             const int* __restrict__ deg, float* __restrict__ dinv) {
    int gid = blockIdx.x * 256 + threadIdx.x;
    if (gid < NN) {
        rowptr[gid] += boff[gid >> 10];
        dinv[gid] = rsqrtf((float)(deg[gid] + 1));
    }
    if (gid == 0) rowptr[NN] = NE;
}

// ================= MEGA2: [scatter | gemm1]  (R1 structure; t8 now PRESCALED by dinv) ======
__global__ __launch_bounds__(256) void mega2_kernel(
    const int* __restrict__ er, const int* __restrict__ ec, const int* __restrict__ rowptr,
    const unsigned char* __restrict__ rank, const unsigned char* __restrict__ base8,
    int* __restrict__ colss,
    const unsigned short* __restrict__ xb, const unsigned short* __restrict__ w1t,
    const float* __restrict__ b1, const float* __restrict__ dinv,
    unsigned short* __restrict__ tbuf, unsigned char* __restrict__ t8) {
    __shared__ __align__(16) unsigned short As[128 * 32];
    __shared__ __align__(16) unsigned short Bs[128 * 32];
    int bid = blockIdx.x;
    if (bid < CB) {   // scatter (atomic-free), one histogram slice per block
        int tid = threadIdx.x;
        const unsigned char* bb = base8 + (size_t)bid * 50000;
        int e0 = bid * EPB;
        int e = e0 + tid;
        #pragma unroll 4
        for (int it = 0; it < EPB / 256; ++it, e += 256) {
            int r = er[e], c = ec[e];
            colss[rowptr[r] + (int)bb[r] + (int)rank[e]] = c;
        }
        if (e < e0 + EPB) {   // tail: EPB % 256 = 106 edges
            int r = er[e], c = ec[e];
            colss[rowptr[r] + (int)bb[r] + (int)rank[e]] = c;
        }
        return;
    }
    bid -= CB;
    // ---- gemm1: t = relu(x@W1+b1) -> tbuf bf16 (unscaled) + t8 fp8 (dinv[row]-prescaled) ----
    const int m0 = (bid >> 2) * 128, n0 = (bid & 3) * 128;
    const int tid = threadIdx.x;
    const int wave = tid >> 6, lane = tid & 63;
    const int q = lane >> 4, c = lane & 15;
    const int wm = wave & 1, wn = wave >> 1;

    float4v acc[4][4];
    for (int i = 0; i < 4; ++i)
        for (int j = 0; j < 4; ++j)
            acc[i][j] = (float4v){0.f, 0.f, 0.f, 0.f};

    for (int k0 = 0; k0 < FI; k0 += 32) {
        __syncthreads();
        #pragma unroll
        for (int h = 0; h < 2; ++h) {
            int chunk = h * 256 + wave * 64 + lane;
            int r = chunk >> 2, kc = chunk & 3;
            int gm = m0 + r; gm = gm < NN ? gm : NN - 1;
            async_copy16((char*)As + (size_t)(h * 256 + wave * 64) * 16,
                         xb + (size_t)gm * FI + k0 + kc * 8);
            async_copy16((char*)Bs + (size_t)(h * 256 + wave * 64) * 16,
                         w1t + (size_t)(n0 + r) * FI + k0 + kc * 8);
        }
        __syncthreads();
        short8 a[4], b[4];
        #pragma unroll
        for (int mi = 0; mi < 4; ++mi)
            a[mi] = *(const short8*)(As + ((wm * 64 + mi * 16 + c) * 32 + q * 8));
        #pragma unroll
        for (int ni = 0; ni < 4; ++ni)
            b[ni] = *(const short8*)(Bs + ((wn * 64 + ni * 16 + c) * 32 + q * 8));
        #pragma unroll
        for (int mi = 0; mi < 4; ++mi)
            #pragma unroll
            for (int ni = 0; ni < 4; ++ni)
                acc[mi][ni] = __builtin_amdgcn_mfma_f32_16x16x32_bf16(a[mi], b[ni], acc[mi][ni], 0, 0, 0);
    }
    #pragma unroll
    for (int ni = 0; ni < 4; ++ni) {
        int col = n0 + wn * 64 + ni * 16 + c;
        float bias = b1[col];
        #pragma unroll
        for (int mi = 0; mi < 4; ++mi) {
            int rbase = m0 + wm * 64 + mi * 16 + q * 4;
            #pragma unroll
            for (int r = 0; r < 4; ++r) {
                int row = rbase + r;
                if (row < NN) {
                    float v = acc[mi][ni][r] + bias;
                    v = v > 0.f ? v : 0.f;
                    tbuf[(size_t)row * FI + col] = f2b(v);
                    t8[(size_t)row * FI + col] = f2e4m3(dinv[row] * v);
                }
            }
        }
    }
}

// ================= SpMM (fp8 gather; operand prescaled by dinv[col] -> pure-add inner loop)
// out[i] = di * ( di*t[i] + sum_c src8[c] )   where src8[c] = dinv[c]*t[c] in fp8.
// No per-edge dinv gather, no per-edge scalar multiply: accumulation retires as gathers land.
#define DEC8A(g)                                                            \
    {   f32x2 p0 = __builtin_amdgcn_cvt_pk_f32_fp8((int)(g).x, false);      \
        f32x2 p1 = __builtin_amdgcn_cvt_pk_f32_fp8((int)(g).x, true);       \
        f32x2 p2 = __builtin_amdgcn_cvt_pk_f32_fp8((int)(g).y, false);      \
        f32x2 p3 = __builtin_amdgcn_cvt_pk_f32_fp8((int)(g).y, true);       \
        a0 += p0.x; a1 += p0.y;                                             \
        a2 += p1.x; a3 += p1.y;                                             \
        a4 += p2.x; a5 += p2.y;                                             \
        a6 += p3.x; a7 += p3.y; }

__global__ __launch_bounds__(256) void spmm_kernel(
    const unsigned char* __restrict__ src8, const unsigned short* __restrict__ srcb,
    unsigned short* __restrict__ dstb, unsigned char* __restrict__ dst8,
    const int* __restrict__ rowptr, const int* __restrict__ cols,
    const float* __restrict__ dinv, int write8) {
    int i = blockIdx.x * 4 + (threadIdx.x >> 6);
    if (i >= NN) return;
    int lane = threadIdx.x & 63;
    const float di = dinv[i];
    const unsigned char* bin = src8 + lane * 8;

    float a0, a1, a2, a3, a4, a5, a6, a7;
    {   // self-loop seed: di * t[i] from the unscaled bf16 copy (final *di gives di^2)
        uint4 u = *(const uint4*)(srcb + (size_t)i * FI + lane * 8);
        a0 = di * blo(u.x); a1 = di * bhi(u.x);
        a2 = di * blo(u.y); a3 = di * bhi(u.y);
        a4 = di * blo(u.z); a5 = di * bhi(u.z);
        a6 = di * blo(u.w); a7 = di * bhi(u.w);
    }
    int k = rowptr[i], e = rowptr[i + 1];
    for (; k + 8 <= e; k += 8) {
        int c0 = cols[k + 0], c1 = cols[k + 1], c2 = cols[k + 2], c3 = cols[k + 3];
        int c4 = cols[k + 4], c5 = cols[k + 5], c6 = cols[k + 6], c7 = cols[k + 7];
        uint2 g0 = *(const uint2*)(bin + (size_t)c0 * FI);
        uint2 g1 = *(const uint2*)(bin + (size_t)c1 * FI);
        uint2 g2 = *(const uint2*)(bin + (size_t)c2 * FI);
        uint2 g3 = *(const uint2*)(bin + (size_t)c3 * FI);
        uint2 g4 = *(const uint2*)(bin + (size_t)c4 * FI);
        uint2 g5 = *(const uint2*)(bin + (size_t)c5 * FI);
        uint2 g6 = *(const uint2*)(bin + (size_t)c6 * FI);
        uint2 g7 = *(const uint2*)(bin + (size_t)c7 * FI);
        DEC8A(g0) DEC8A(g1) DEC8A(g2) DEC8A(g3)
        DEC8A(g4) DEC8A(g5) DEC8A(g6) DEC8A(g7)
    }
    for (; k < e; ++k) {
        int cc = cols[k];
        uint2 g = *(const uint2*)(bin + (size_t)cc * FI);
        DEC8A(g)
    }
    a0 *= di; a1 *= di; a2 *= di; a3 *= di;
    a4 *= di; a5 *= di; a6 *= di; a7 *= di;
    uint4 o;
    o.x = ((unsigned int)f2b(a1) << 16) | f2b(a0);
    o.y = ((unsigned int)f2b(a3) << 16) | f2b(a2);
    o.z = ((unsigned int)f2b(a5) << 16) | f2b(a4);
    o.w = ((unsigned int)f2b(a7) << 16) | f2b(a6);
    *(uint4*)(dstb + lane * 8 + (size_t)i * FI) = o;
    if (write8) {   // next pass's operand: prescale by dinv[i]
        float s0 = di * a0, s1 = di * a1, s2 = di * a2, s3 = di * a3;
        float s4 = di * a4, s5 = di * a5, s6 = di * a6, s7 = di * a7;
        unsigned r0 = (unsigned)__builtin_amdgcn_cvt_pk_fp8_f32(s0, s1, 0, false);
        r0 = (unsigned)__builtin_amdgcn_cvt_pk_fp8_f32(s2, s3, (int)r0, true);
        unsigned r1 = (unsigned)__builtin_amdgcn_cvt_pk_fp8_f32(s4, s5, 0, false);
        r1 = (unsigned)__builtin_amdgcn_cvt_pk_fp8_f32(s6, s7, (int)r1, true);
        uint2 o8; o8.x = r0; o8.y = r1;
        *(uint2*)(dst8 + lane * 8 + (size_t)i * FI) = o8;
    }
}

// ================= GEMM2 + log_softmax (fp32 out) =================
__global__ __launch_bounds__(256) void gemm2_kernel(
    const unsigned short* __restrict__ tb, const unsigned short* __restrict__ s1b,
    const unsigned short* __restrict__ s2b, const unsigned short* __restrict__ wct,
    const float* __restrict__ b2p, float* __restrict__ out) {
    int wave = threadIdx.x >> 6, lane = threadIdx.x & 63;
    int q = lane >> 4, c = lane & 15;
    int row0 = blockIdx.x * 64 + wave * 16;
    int ra = row0 + c; ra = ra < NN ? ra : NN - 1;
    const unsigned short* seg[3] = { tb + (size_t)ra * FI + q * 8,
                                     s1b + (size_t)ra * FI + q * 8,
                                     s2b + (size_t)ra * FI + q * 8 };
    const unsigned short* bp0 = wct + (size_t)(c)      * HW + q * 8;
    const unsigned short* bp1 = wct + (size_t)(16 + c) * HW + q * 8;
    const unsigned short* bp2 = wct + (size_t)(32 + c) * HW + q * 8;

    float4v A0 = {0.f,0.f,0.f,0.f}, A1 = {0.f,0.f,0.f,0.f}, A2 = {0.f,0.f,0.f,0.f};
    #pragma unroll
    for (int s = 0; s < 3; ++s) {
        const unsigned short* ap = seg[s];
        #pragma unroll 4
        for (int k0 = 0; k0 < 512; k0 += 32) {
            short8 a  = *(const short8*)(ap + k0);
            short8 b0 = *(const short8*)(bp0 + s * 512 + k0);
            short8 b1 = *(const short8*)(bp1 + s * 512 + k0);
            short8 b2 = *(const short8*)(bp2 + s * 512 + k0);
            A0 = __builtin_amdgcn_mfma_f32_16x16x32_bf16(a, b0, A0, 0, 0, 0);
            A1 = __builtin_amdgcn_mfma_f32_16x16x32_bf16(a, b1, A1, 0, 0, 0);
            A2 = __builtin_amdgcn_mfma_f32_16x16x32_bf16(a, b2, A2, 0, 0, 0);
        }
    }
    float bias0 = b2p[c];
    float bias1 = b2p[16 + c];
    float bias2 = (c < 8) ? b2p[32 + c] : 0.f;
    #pragma unroll
    for (int r = 0; r < 4; ++r) {
        float v0 = A0[r] + bias0;
        float v1 = A1[r] + bias1;
        float v2 = (c < 8) ? (A2[r] + bias2) : -1e30f;
        float mx = fmaxf(fmaxf(v0, v1), v2);
        #pragma unroll
        for (int d = 1; d < 16; d <<= 1) mx = fmaxf(mx, __shfl_xor(mx, d, 64));
        float s = __expf(v0 - mx) + __expf(v1 - mx) + ((c < 8) ? __expf(v2 - mx) : 0.f);
        #pragma unroll
        for (int d = 1; d < 16; d <<= 1) s += __shfl_xor(s, d, 64);
        float lse = mx + __logf(s);
        int rowg = row0 + q * 4 + r;
        if (rowg < NN) {
            out[(size_t)rowg * NC + c]      = v0 - lse;
            out[(size_t)rowg * NC + 16 + c] = v1 - lse;
            if (c < 8) out[(size_t)rowg * NC + 32 + c] = v2 - lse;
        }
    }
}

extern "C" void kernel_launch(void* const* d_in, const int* in_sizes, int n_in,
                              void* d_out, int out_size, void* d_ws, size_t ws_size,
                              hipStream_t stream) {
    const float* x  = (const float*)d_in[0];
    const int*   er = (const int*)d_in[1];
    const int*   ec = (const int*)d_in[2];
    const float* W1 = (const float*)d_in[3];
    const float* b1 = (const float*)d_in[4];
    const float* W2 = (const float*)d_in[5];
    const float* b2 = (const float*)d_in[6];
    float* out = (float*)d_out;

    char* p = (char*)d_ws;
    auto alloc = [&](size_t bytes) { char* r = p; p += (bytes + 255) & ~((size_t)255); return r; };
    int*      cntI   = (int*)      alloc((size_t)NN * 4);
    int*      degI   = (int*)      alloc((size_t)NN * 4);
    int*      rowptr = (int*)      alloc((size_t)(NN + 1) * 4);
    float*    dinv   = (float*)    alloc((size_t)NN * 4);
    int*      bsum   = (int*)      alloc((size_t)SCAN_NB * 4);
    int*      boff   = (int*)      alloc((size_t)SCAN_NB * 4);
    unsigned char* rank = (unsigned char*)alloc((size_t)NE);
    int*      colss  = (int*)      alloc((size_t)NE * 4);
    unsigned* hist_row = (unsigned*)alloc((size_t)CB * HWRD * 4);   // 12.8MB, dead after prep
    unsigned* hist_col = (unsigned*)alloc((size_t)CB * HWRD * 4);   // 12.8MB, dead after prep
    unsigned* base_w   = (unsigned*)alloc((size_t)CB * HWRD * 4);   // 12.8MB, dead after mega2
    unsigned short* w1t  = (unsigned short*)alloc((size_t)512 * 512 * 2);
    unsigned short* wct  = (unsigned short*)alloc((size_t)48 * HW * 2);
    unsigned short* xb   = (unsigned short*)alloc((size_t)NN * FI * 2);
    unsigned short* tbuf = (unsigned short*)alloc((size_t)NN * FI * 2);
    unsigned short* s1b  = (unsigned short*)alloc((size_t)NN * FI * 2);
    unsigned char*  s18  = (unsigned char*)alloc((size_t)NN * FI);
    // aliases: t8 over the (dead after prep) histograms; s2 over (dead after gemm1) xb
    unsigned char*  t8  = (unsigned char*)hist_row;   // 25.6MB needed; hist_row+hist_col = 25.6MB
    unsigned short* s2b = xb;

    // L1: independent prep work, count parts first
    mega1_kernel<<<2 * CB + 12500 + 1024 + 288, 256, 0, stream>>>(
        er, ec, x, W1, W2, rank, hist_row, hist_col, xb, w1t, wct);
    // L2: cross-block prefix (rows) + reduce (cols)
    prep_kernel<<<(2 * HWRD + 255) / 256, 256, 0, stream>>>(hist_row, hist_col, base_w, cntI, degI);
    // L3-5: rowptr scan + dinv
    scan1_kernel<<<SCAN_NB, 1024, 0, stream>>>(cntI, rowptr, bsum);
    scan2_kernel<<<1, 64, 0, stream>>>(bsum, boff);
    scan3_kernel<<<(NN + 255) / 256, 256, 0, stream>>>(rowptr, boff, degI, dinv);
    // L6: scatter (slice blocks) | gemm1 (t8 prescaled by dinv) -- t8 overwrites hist_* (dead)
    mega2_kernel<<<CB + ((NN + 127) / 128) * 4, 256, 0, stream>>>(
        er, ec, rowptr, rank, (const unsigned char*)base_w, colss, xb, w1t, b1, dinv, tbuf, t8);
    // L7-8: SpMMs (fp8 gather, prescaled operand -> pure-add inner loop)
    spmm_kernel<<<(NN + 3) / 4, 256, 0, stream>>>(t8, tbuf, s1b, s18, rowptr, colss, dinv, 1);
    spmm_kernel<<<(NN + 3) / 4, 256, 0, stream>>>(s18, s1b, s2b, (unsigned char*)nullptr, rowptr, colss, dinv, 0);
    // L9: final GEMM + log_softmax
    gemm2_kernel<<<(NN + 63) / 64, 256, 0, stream>>>(tbuf, s1b, s2b, wct, b2, out);
}

// Round 7
// 644.317 us; speedup vs baseline: 1.2200x; 1.0004x over previous
//
#include <hip/hip_runtime.h>
#include <stdint.h>

#define NN 50000
#define NE 1600000
#define FI 512
#define DD 512
#define NC 40
#define HW 1536
#define SCAN_NB 49        // ceil(NN/1024)
#define CB 256            // histogram blocks
#define EPB (NE / CB)     // 6250 edges per histogram block
#define HWRD 12500        // 50000 bins / 4 bytes per word

typedef __attribute__((ext_vector_type(8))) short short8;
typedef __attribute__((ext_vector_type(4))) float float4v;
typedef __attribute__((ext_vector_type(2))) float f32x2;

static __device__ __forceinline__ unsigned short f2b(float f) {
    union { float f; unsigned int i; } v; v.f = f;
    unsigned int r = v.i + 0x7fffu + ((v.i >> 16) & 1u);
    return (unsigned short)(r >> 16);
}
static __device__ __forceinline__ float blo(unsigned int u) {
    union { unsigned int i; float f; } v; v.i = u << 16; return v.f;
}
static __device__ __forceinline__ float bhi(unsigned int u) {
    union { unsigned int i; float f; } v; v.i = u & 0xffff0000u; return v.f;
}
static __device__ __forceinline__ unsigned char f2e4m3(float f) {
    return (unsigned char)(__builtin_amdgcn_cvt_pk_fp8_f32(f, f, 0, false) & 0xFF);
}
static __device__ __forceinline__ void async_copy16(void* lds, const void* g) {
    __builtin_amdgcn_global_load_lds((const __attribute__((address_space(1))) void*)g,
                                     (__attribute__((address_space(3))) void*)lds, 16, 0, 0);
}

// ================= MEGA1: [count_row | count_col | convx | transpose | wcat] =================
__global__ __launch_bounds__(256) void mega1_kernel(
    const int* __restrict__ er, const int* __restrict__ ec,
    const float* __restrict__ x, const float* __restrict__ W1, const float* __restrict__ W2,
    unsigned char* __restrict__ rank, unsigned* __restrict__ hist_row, unsigned* __restrict__ hist_col,
    unsigned short* __restrict__ xb, unsigned short* __restrict__ w1t, unsigned short* __restrict__ wct) {
    __shared__ unsigned hb[HWRD];
    int bid = blockIdx.x, tid = threadIdx.x;
    if (bid < 2 * CB) {
        for (int w = tid; w < HWRD; w += 256) hb[w] = 0;
        __syncthreads();
        int b = bid & (CB - 1);
        int e0 = b * EPB;
        if (bid < CB) {   // row histogram + rank
            for (int e = e0 + tid; e < e0 + EPB; e += 256) {
                int r = er[e];
                unsigned sh = (r & 3) * 8;
                unsigned old = atomicAdd(&hb[r >> 2], 1u << sh);
                rank[e] = (unsigned char)((old >> sh) & 0xFFu);
            }
        } else {          // col histogram (in-degree)
            for (int e = e0 + tid; e < e0 + EPB; e += 256) {
                int c = ec[e];
                atomicAdd(&hb[c >> 2], 1u << ((c & 3) * 8));
            }
        }
        __syncthreads();
        unsigned* dst = (bid < CB ? hist_row : hist_col) + (size_t)b * HWRD;
        for (int w = tid; w < HWRD; w += 256) dst[w] = hb[w];
        return;
    }
    bid -= 2 * CB;
    if (bid < 12500) {    // convx: fp32 -> bf16, 8 elems/thread
        int t = bid * 256 + tid;
        const float* xf = x + (size_t)t * 8;
        float4 v0 = *(const float4*)(xf);
        float4 v1 = *(const float4*)(xf + 4);
        uint4 u;
        u.x = ((unsigned)f2b(v0.y) << 16) | f2b(v0.x);
        u.y = ((unsigned)f2b(v0.w) << 16) | f2b(v0.z);
        u.z = ((unsigned)f2b(v1.y) << 16) | f2b(v1.x);
        u.w = ((unsigned)f2b(v1.w) << 16) | f2b(v1.z);
        *(uint4*)(xb + (size_t)t * 8) = u;
        return;
    }
    bid -= 12500;
    if (bid < 1024) {     // transpose W1 -> bf16 w1t[n][k]
        int t = bid * 256 + tid;
        int n = t & 511, k = t >> 9;
        w1t[n * 512 + k] = f2b(W1[(size_t)k * 512 + n]);
        return;
    }
    bid -= 1024;
    {                     // wcat: combined final weight, transposed, bf16 (48*1536)
        int t = bid * 256 + tid;
        if (t < 48 * HW) {
            int k = t % HW, n = t / HW;
            float v = 0.f;
            if (n < NC) {
                if (k < 512)       v = W2[(size_t)k * NC + n] + W2[(size_t)(k + 512) * NC + n];
                else if (k < 1024) v = W2[(size_t)(k + 512) * NC + n] + W2[(size_t)(k + 1024) * NC + n];
                else               v = W2[(size_t)(k + 1024) * NC + n];
            }
            wct[n * HW + k] = f2b(v);
        }
    }
}

// ================= PREP: SWAR prefix over blocks (rows) + reduce (cols) =================
__global__ __launch_bounds__(256) void prep_kernel(
    const unsigned* __restrict__ hist_row, const unsigned* __restrict__ hist_col,
    unsigned* __restrict__ base_words, int* __restrict__ cntI, int* __restrict__ degI) {
    int t = blockIdx.x * 256 + threadIdx.x;
    if (t < HWRD) {
        unsigned acc = 0;   // 4 packed byte counters; totals <256/byte so no carry
        for (int b = 0; b < CB; ++b) {
            unsigned h = hist_row[(size_t)b * HWRD + t];
            base_words[(size_t)b * HWRD + t] = acc;
            acc += h;
        }
        int4 o; o.x = acc & 0xFF; o.y = (acc >> 8) & 0xFF; o.z = (acc >> 16) & 0xFF; o.w = (acc >> 24) & 0xFF;
        ((int4*)cntI)[t] = o;
    } else if (t < 2 * HWRD) {
        int w = t - HWRD;
        unsigned acc = 0;
        for (int b = 0; b < CB; ++b) acc += hist_col[(size_t)b * HWRD + w];
        int4 o; o.x = acc & 0xFF; o.y = (acc >> 8) & 0xFF; o.z = (acc >> 16) & 0xFF; o.w = (acc >> 24) & 0xFF;
        ((int4*)degI)[w] = o;
    }
}

// ================= scans =================
__global__ __launch_bounds__(1024) void scan1_kernel(const int* __restrict__ cnt,
                                                     int* __restrict__ excl, int* __restrict__ bsum) {
    __shared__ int buf[1024];
    int tid = threadIdx.x, gid = blockIdx.x * 1024 + tid;
    int v = (gid < NN) ? cnt[gid] : 0;
    buf[tid] = v;
    __syncthreads();
    int acc = v;
    for (int off = 1; off < 1024; off <<= 1) {
        int t = (tid >= off) ? buf[tid - off] : 0;
        __syncthreads();
        acc += t;
        buf[tid] = acc;
        __syncthreads();
    }
    if (gid < NN) excl[gid] = acc - v;
    if (tid == 1023) bsum[blockIdx.x] = acc;
}

__global__ void scan2_kernel(const int* __restrict__ bsum, int* __restrict__ boff) {
    int tid = threadIdx.x;  // one wave, SCAN_NB=49
    int orig = (tid < SCAN_NB) ? bsum[tid] : 0;
    int v = orig;
    #pragma unroll
    for (int off = 1; off < 64; off <<= 1) {
        int t = __shfl_up(v, off, 64);
        if (tid >= off) v += t;
    }
    if (tid < SCAN_NB) boff[tid] = v - orig;
}

__global__ void scan3_kernel(int* __restrict__ rowptr, const int* __restrict__ boff,
                             const int* __restrict__ deg, float* __restrict__ dinv) {
    int gid = blockIdx.x * 256 + threadIdx.x;
    if (gid < NN) {
        rowptr[gid] += boff[gid >> 10];
        dinv[gid] = rsqrtf((float)(deg[gid] + 1));
    }
    if (gid == 0) rowptr[NN] = NE;
}

// ================= MEGA2: [scatter | gemm1 BK=64] ==========================================
// gemm1: 128x128 tile, BK=64 as two 32-k panels per barrier (same LDS layout/stride as BK=32,
// so identical bank behavior) -> half the stage-drain stalls per block. 32KB LDS, 5 blocks/CU.
// t8 output prescaled by dinv[row] (spmm pure-add algebra).
__global__ __launch_bounds__(256) void mega2_kernel(
    const int* __restrict__ er, const int* __restrict__ ec, const int* __restrict__ rowptr,
    const unsigned char* __restrict__ rank, const unsigned char* __restrict__ base8,
    int* __restrict__ colss,
    const unsigned short* __restrict__ xb, const unsigned short* __restrict__ w1t,
    const float* __restrict__ b1, const float* __restrict__ dinv,
    unsigned short* __restrict__ tbuf, unsigned char* __restrict__ t8) {
    __shared__ __align__(16) unsigned short As0[128 * 32];
    __shared__ __align__(16) unsigned short Bs0[128 * 32];
    __shared__ __align__(16) unsigned short As1[128 * 32];
    __shared__ __align__(16) unsigned short Bs1[128 * 32];
    int bid = blockIdx.x;
    if (bid < CB) {   // scatter (atomic-free), one histogram slice per block
        int tid = threadIdx.x;
        const unsigned char* bb = base8 + (size_t)bid * 50000;
        int e0 = bid * EPB;
        int e = e0 + tid;
        #pragma unroll 4
        for (int it = 0; it < EPB / 256; ++it, e += 256) {
            int r = er[e], c = ec[e];
            colss[rowptr[r] + (int)bb[r] + (int)rank[e]] = c;
        }
        if (e < e0 + EPB) {   // tail: EPB % 256 = 106 edges
            int r = er[e], c = ec[e];
            colss[rowptr[r] + (int)bb[r] + (int)rank[e]] = c;
        }
        return;
    }
    bid -= CB;
    // ---- gemm1: t = relu(x@W1+b1) -> tbuf bf16 (unscaled) + t8 fp8 (dinv[row]-prescaled) ----
    const int m0 = (bid >> 2) * 128, n0 = (bid & 3) * 128;
    const int tid = threadIdx.x;
    const int wave = tid >> 6, lane = tid & 63;
    const int q = lane >> 4, c = lane & 15;
    const int wm = wave & 1, wn = wave >> 1;

    float4v acc[4][4];
    for (int i = 0; i < 4; ++i)
        for (int j = 0; j < 4; ++j)
            acc[i][j] = (float4v){0.f, 0.f, 0.f, 0.f};

    #define HALF(AS, BS)                                                                   \
    {   short8 a[4], b[4];                                                                 \
        _Pragma("unroll")                                                                  \
        for (int mi = 0; mi < 4; ++mi)                                                     \
            a[mi] = *(const short8*)((AS) + ((wm * 64 + mi * 16 + c) * 32 + q * 8));       \
        _Pragma("unroll")                                                                  \
        for (int ni = 0; ni < 4; ++ni)                                                     \
            b[ni] = *(const short8*)((BS) + ((wn * 64 + ni * 16 + c) * 32 + q * 8));       \
        _Pragma("unroll")                                                                  \
        for (int mi = 0; mi < 4; ++mi)                                                     \
            _Pragma("unroll")                                                              \
            for (int ni = 0; ni < 4; ++ni)                                                 \
                acc[mi][ni] = __builtin_amdgcn_mfma_f32_16x16x32_bf16(a[mi], b[ni], acc[mi][ni], 0, 0, 0); \
    }

    for (int k0 = 0; k0 < FI; k0 += 64) {
        __syncthreads();
        #pragma unroll
        for (int h = 0; h < 2; ++h) {
            int chunk = h * 256 + wave * 64 + lane;
            int r = chunk >> 2, kc = chunk & 3;
            int gm = m0 + r; gm = gm < NN ? gm : NN - 1;
            async_copy16((char*)As0 + (size_t)(h * 256 + wave * 64) * 16,
                         xb + (size_t)gm * FI + k0 + kc * 8);
            async_copy16((char*)Bs0 + (size_t)(h * 256 + wave * 64) * 16,
                         w1t + (size_t)(n0 + r) * FI + k0 + kc * 8);
            async_copy16((char*)As1 + (size_t)(h * 256 + wave * 64) * 16,
                         xb + (size_t)gm * FI + k0 + 32 + kc * 8);
            async_copy16((char*)Bs1 + (size_t)(h * 256 + wave * 64) * 16,
                         w1t + (size_t)(n0 + r) * FI + k0 + 32 + kc * 8);
        }
        __syncthreads();
        HALF(As0, Bs0)
        HALF(As1, Bs1)
    }
    #undef HALF

    #pragma unroll
    for (int ni = 0; ni < 4; ++ni) {
        int col = n0 + wn * 64 + ni * 16 + c;
        float bias = b1[col];
        #pragma unroll
        for (int mi = 0; mi < 4; ++mi) {
            int rbase = m0 + wm * 64 + mi * 16 + q * 4;
            #pragma unroll
            for (int r = 0; r < 4; ++r) {
                int row = rbase + r;
                if (row < NN) {
                    float v = acc[mi][ni][r] + bias;
                    v = v > 0.f ? v : 0.f;
                    tbuf[(size_t)row * FI + col] = f2b(v);
                    t8[(size_t)row * FI + col] = f2e4m3(dinv[row] * v);
                }
            }
        }
    }
}

// ================= SpMM (fp8 gather; prescaled operand, fp8 self-seed -> pure-add loop) ====
// out[i] = di * ( seed + sum_c src8[c] ), seed = decode(src8[i]) = di*t[i]  (exact algebra:
// src8[r] = fp8(dinv[r]*t[r])).  No bf16 source read at all: -51.2 MB fetch per pass.
#define DEC8A(g)                                                            \
    {   f32x2 p0 = __builtin_amdgcn_cvt_pk_f32_fp8((int)(g).x, false);      \
        f32x2 p1 = __builtin_amdgcn_cvt_pk_f32_fp8((int)(g).x, true);       \
        f32x2 p2 = __builtin_amdgcn_cvt_pk_f32_fp8((int)(g).y, false);      \
        f32x2 p3 = __builtin_amdgcn_cvt_pk_f32_fp8((int)(g).y, true);       \
        a0 += p0.x; a1 += p0.y;                                             \
        a2 += p1.x; a3 += p1.y;                                             \
        a4 += p2.x; a5 += p2.y;                                             \
        a6 += p3.x; a7 += p3.y; }

__global__ __launch_bounds__(256) void spmm_kernel(
    const unsigned char* __restrict__ src8,
    unsigned short* __restrict__ dstb, unsigned char* __restrict__ dst8,
    const int* __restrict__ rowptr, const int* __restrict__ cols,
    const float* __restrict__ dinv, int write8) {
    int i = blockIdx.x * 4 + (threadIdx.x >> 6);
    if (i >= NN) return;
    int lane = threadIdx.x & 63;
    const float di = dinv[i];
    const unsigned char* bin = src8 + lane * 8;

    float a0, a1, a2, a3, a4, a5, a6, a7;
    {   // self-loop seed from own fp8 row: decode = di*t[i]; final *di gives di^2*t[i]
        uint2 u = *(const uint2*)(bin + (size_t)i * FI);
        f32x2 p0 = __builtin_amdgcn_cvt_pk_f32_fp8((int)u.x, false);
        f32x2 p1 = __builtin_amdgcn_cvt_pk_f32_fp8((int)u.x, true);
        f32x2 p2 = __builtin_amdgcn_cvt_pk_f32_fp8((int)u.y, false);
        f32x2 p3 = __builtin_amdgcn_cvt_pk_f32_fp8((int)u.y, true);
        a0 = p0.x; a1 = p0.y; a2 = p1.x; a3 = p1.y;
        a4 = p2.x; a5 = p2.y; a6 = p3.x; a7 = p3.y;
    }
    int k = rowptr[i], e = rowptr[i + 1];
    for (; k + 8 <= e; k += 8) {
        int c0 = cols[k + 0], c1 = cols[k + 1], c2 = cols[k + 2], c3 = cols[k + 3];
        int c4 = cols[k + 4], c5 = cols[k + 5], c6 = cols[k + 6], c7 = cols[k + 7];
        uint2 g0 = *(const uint2*)(bin + (size_t)c0 * FI);
        uint2 g1 = *(const uint2*)(bin + (size_t)c1 * FI);
        uint2 g2 = *(const uint2*)(bin + (size_t)c2 * FI);
        uint2 g3 = *(const uint2*)(bin + (size_t)c3 * FI);
        uint2 g4 = *(const uint2*)(bin + (size_t)c4 * FI);
        uint2 g5 = *(const uint2*)(bin + (size_t)c5 * FI);
        uint2 g6 = *(const uint2*)(bin + (size_t)c6 * FI);
        uint2 g7 = *(const uint2*)(bin + (size_t)c7 * FI);
        DEC8A(g0) DEC8A(g1) DEC8A(g2) DEC8A(g3)
        DEC8A(g4) DEC8A(g5) DEC8A(g6) DEC8A(g7)
    }
    for (; k < e; ++k) {
        int cc = cols[k];
        uint2 g = *(const uint2*)(bin + (size_t)cc * FI);
        DEC8A(g)
    }
    a0 *= di; a1 *= di; a2 *= di; a3 *= di;
    a4 *= di; a5 *= di; a6 *= di; a7 *= di;
    uint4 o;
    o.x = ((unsigned int)f2b(a1) << 16) | f2b(a0);
    o.y = ((unsigned int)f2b(a3) << 16) | f2b(a2);
    o.z = ((unsigned int)f2b(a5) << 16) | f2b(a4);
    o.w = ((unsigned int)f2b(a7) << 16) | f2b(a6);
    *(uint4*)(dstb + lane * 8 + (size_t)i * FI) = o;
    if (write8) {   // next pass's operand: prescale by dinv[i]
        float s0 = di * a0, s1 = di * a1, s2 = di * a2, s3 = di * a3;
        float s4 = di * a4, s5 = di * a5, s6 = di * a6, s7 = di * a7;
        unsigned r0 = (unsigned)__builtin_amdgcn_cvt_pk_fp8_f32(s0, s1, 0, false);
        r0 = (unsigned)__builtin_amdgcn_cvt_pk_fp8_f32(s2, s3, (int)r0, true);
        unsigned r1 = (unsigned)__builtin_amdgcn_cvt_pk_fp8_f32(s4, s5, 0, false);
        r1 = (unsigned)__builtin_amdgcn_cvt_pk_fp8_f32(s6, s7, (int)r1, true);
        uint2 o8; o8.x = r0; o8.y = r1;
        *(uint2*)(dst8 + lane * 8 + (size_t)i * FI) = o8;
    }
}

// ================= GEMM2 + log_softmax (fp32 out) =================
__global__ __launch_bounds__(256) void gemm2_kernel(
    const unsigned short* __restrict__ tb, const unsigned short* __restrict__ s1b,
    const unsigned short* __restrict__ s2b, const unsigned short* __restrict__ wct,
    const float* __restrict__ b2p, float* __restrict__ out) {
    int wave = threadIdx.x >> 6, lane = threadIdx.x & 63;
    int q = lane >> 4, c = lane & 15;
    int row0 = blockIdx.x * 64 + wave * 16;
    int ra = row0 + c; ra = ra < NN ? ra : NN - 1;
    const unsigned short* seg[3] = { tb + (size_t)ra * FI + q * 8,
                                     s1b + (size_t)ra * FI + q * 8,
                                     s2b + (size_t)ra * FI + q * 8 };
    const unsigned short* bp0 = wct + (size_t)(c)      * HW + q * 8;
    const unsigned short* bp1 = wct + (size_t)(16 + c) * HW + q * 8;
    const unsigned short* bp2 = wct + (size_t)(32 + c) * HW + q * 8;

    float4v A0 = {0.f,0.f,0.f,0.f}, A1 = {0.f,0.f,0.f,0.f}, A2 = {0.f,0.f,0.f,0.f};
    #pragma unroll
    for (int s = 0; s < 3; ++s) {
        const unsigned short* ap = seg[s];
        #pragma unroll 4
        for (int k0 = 0; k0 < 512; k0 += 32) {
            short8 a  = *(const short8*)(ap + k0);
            short8 b0 = *(const short8*)(bp0 + s * 512 + k0);
            short8 b1 = *(const short8*)(bp1 + s * 512 + k0);
            short8 b2 = *(const short8*)(bp2 + s * 512 + k0);
            A0 = __builtin_amdgcn_mfma_f32_16x16x32_bf16(a, b0, A0, 0, 0, 0);
            A1 = __builtin_amdgcn_mfma_f32_16x16x32_bf16(a, b1, A1, 0, 0, 0);
            A2 = __builtin_amdgcn_mfma_f32_16x16x32_bf16(a, b2, A2, 0, 0, 0);
        }
    }
    float bias0 = b2p[c];
    float bias1 = b2p[16 + c];
    float bias2 = (c < 8) ? b2p[32 + c] : 0.f;
    #pragma unroll
    for (int r = 0; r < 4; ++r) {
        float v0 = A0[r] + bias0;
        float v1 = A1[r] + bias1;
        float v2 = (c < 8) ? (A2[r] + bias2) : -1e30f;
        float mx = fmaxf(fmaxf(v0, v1), v2);
        #pragma unroll
        for (int d = 1; d < 16; d <<= 1) mx = fmaxf(mx, __shfl_xor(mx, d, 64));
        float s = __expf(v0 - mx) + __expf(v1 - mx) + ((c < 8) ? __expf(v2 - mx) : 0.f);
        #pragma unroll
        for (int d = 1; d < 16; d <<= 1) s += __shfl_xor(s, d, 64);
        float lse = mx + __logf(s);
        int rowg = row0 + q * 4 + r;
        if (rowg < NN) {
            out[(size_t)rowg * NC + c]      = v0 - lse;
            out[(size_t)rowg * NC + 16 + c] = v1 - lse;
            if (c < 8) out[(size_t)rowg * NC + 32 + c] = v2 - lse;
        }
    }
}

extern "C" void kernel_launch(void* const* d_in, const int* in_sizes, int n_in,
                              void* d_out, int out_size, void* d_ws, size_t ws_size,
                              hipStream_t stream) {
    const float* x  = (const float*)d_in[0];
    const int*   er = (const int*)d_in[1];
    const int*   ec = (const int*)d_in[2];
    const float* W1 = (const float*)d_in[3];
    const float* b1 = (const float*)d_in[4];
    const float* W2 = (const float*)d_in[5];
    const float* b2 = (const float*)d_in[6];
    float* out = (float*)d_out;

    char* p = (char*)d_ws;
    auto alloc = [&](size_t bytes) { char* r = p; p += (bytes + 255) & ~((size_t)255); return r; };
    int*      cntI   = (int*)      alloc((size_t)NN * 4);
    int*      degI   = (int*)      alloc((size_t)NN * 4);
    int*      rowptr = (int*)      alloc((size_t)(NN + 1) * 4);
    float*    dinv   = (float*)    alloc((size_t)NN * 4);
    int*      bsum   = (int*)      alloc((size_t)SCAN_NB * 4);
    int*      boff   = (int*)      alloc((size_t)SCAN_NB * 4);
    unsigned char* rank = (unsigned char*)alloc((size_t)NE);
    int*      colss  = (int*)      alloc((size_t)NE * 4);
    unsigned* hist_row = (unsigned*)alloc((size_t)CB * HWRD * 4);   // 12.8MB, dead after prep
    unsigned* hist_col = (unsigned*)alloc((size_t)CB * HWRD * 4);   // 12.8MB, dead after prep
    unsigned* base_w   = (unsigned*)alloc((size_t)CB * HWRD * 4);   // 12.8MB, dead after mega2
    unsigned short* w1t  = (unsigned short*)alloc((size_t)512 * 512 * 2);
    unsigned short* wct  = (unsigned short*)alloc((size_t)48 * HW * 2);
    unsigned short* xb   = (unsigned short*)alloc((size_t)NN * FI * 2);
    unsigned short* tbuf = (unsigned short*)alloc((size_t)NN * FI * 2);
    unsigned short* s1b  = (unsigned short*)alloc((size_t)NN * FI * 2);
    unsigned char*  s18  = (unsigned char*)alloc((size_t)NN * FI);
    // aliases: t8 over the (dead after prep) histograms; s2 over (dead after gemm1) xb
    unsigned char*  t8  = (unsigned char*)hist_row;   // 25.6MB needed; hist_row+hist_col = 25.6MB
    unsigned short* s2b = xb;

    // L1: independent prep work, count parts first
    mega1_kernel<<<2 * CB + 12500 + 1024 + 288, 256, 0, stream>>>(
        er, ec, x, W1, W2, rank, hist_row, hist_col, xb, w1t, wct);
    // L2: cross-block prefix (rows) + reduce (cols)
    prep_kernel<<<(2 * HWRD + 255) / 256, 256, 0, stream>>>(hist_row, hist_col, base_w, cntI, degI);
    // L3-5: rowptr scan + dinv
    scan1_kernel<<<SCAN_NB, 1024, 0, stream>>>(cntI, rowptr, bsum);
    scan2_kernel<<<1, 64, 0, stream>>>(bsum, boff);
    scan3_kernel<<<(NN + 255) / 256, 256, 0, stream>>>(rowptr, boff, degI, dinv);
    // L6: scatter | gemm1 (BK=64, t8 prescaled) -- t8 overwrites hist_* (dead), base_w live
    mega2_kernel<<<CB + ((NN + 127) / 128) * 4, 256, 0, stream>>>(
        er, ec, rowptr, rank, (const unsigned char*)base_w, colss, xb, w1t, b1, dinv, tbuf, t8);
    // L7-8: SpMMs (fp8 gather, pure-add, fp8 self-seed)
    spmm_kernel<<<(NN + 3) / 4, 256, 0, stream>>>(t8, s1b, s18, rowptr, colss, dinv, 1);
    spmm_kernel<<<(NN + 3) / 4, 256, 0, stream>>>(s18, s2b, (unsigned char*)nullptr, rowptr, colss, dinv, 0);
    // L9: final GEMM + log_softmax
    gemm2_kernel<<<(NN + 63) / 64, 256, 0, stream>>>(tbuf, s1b, s2b, wct, b2, out);
}

// Round 8
// 609.380 us; speedup vs baseline: 1.2899x; 1.0573x over previous
//
#include <hip/hip_runtime.h>
#include <stdint.h>

#define NN 50000
#define NE 1600000
#define FI 512
#define DD 512
#define NC 40
#define HW 1536
#define SCAN_NB 49        // ceil(NN/1024)
#define CB 256            // histogram blocks
#define EPB (NE / CB)     // 6250 edges per histogram block
#define HWRD 12500        // 50000 bins / 4 bytes per word

typedef __attribute__((ext_vector_type(8))) short short8;
typedef __attribute__((ext_vector_type(4))) float float4v;
typedef __attribute__((ext_vector_type(2))) float f32x2;

static __device__ __forceinline__ unsigned short f2b(float f) {
    union { float f; unsigned int i; } v; v.f = f;
    unsigned int r = v.i + 0x7fffu + ((v.i >> 16) & 1u);
    return (unsigned short)(r >> 16);
}
static __device__ __forceinline__ unsigned char f2e4m3(float f) {
    return (unsigned char)(__builtin_amdgcn_cvt_pk_fp8_f32(f, f, 0, false) & 0xFF);
}
static __device__ __forceinline__ void async_copy16(void* lds, const void* g) {
    __builtin_amdgcn_global_load_lds((const __attribute__((address_space(1))) void*)g,
                                     (__attribute__((address_space(3))) void*)lds, 16, 0, 0);
}
// fp8x8 -> bf16x8 (exact: every e4m3 value is representable in bf16)
static __device__ __forceinline__ short8 dec8b(uint2 g) {
    f32x2 p0 = __builtin_amdgcn_cvt_pk_f32_fp8((int)g.x, false);
    f32x2 p1 = __builtin_amdgcn_cvt_pk_f32_fp8((int)g.x, true);
    f32x2 p2 = __builtin_amdgcn_cvt_pk_f32_fp8((int)g.y, false);
    f32x2 p3 = __builtin_amdgcn_cvt_pk_f32_fp8((int)g.y, true);
    short8 r;
    r[0] = (short)f2b(p0.x); r[1] = (short)f2b(p0.y);
    r[2] = (short)f2b(p1.x); r[3] = (short)f2b(p1.y);
    r[4] = (short)f2b(p2.x); r[5] = (short)f2b(p2.y);
    r[6] = (short)f2b(p3.x); r[7] = (short)f2b(p3.y);
    return r;
}

// ================= MEGA1: [count_row | count_col | convx | transpose | wcat] =================
__global__ __launch_bounds__(256) void mega1_kernel(
    const int* __restrict__ er, const int* __restrict__ ec,
    const float* __restrict__ x, const float* __restrict__ W1, const float* __restrict__ W2,
    unsigned char* __restrict__ rank, unsigned* __restrict__ hist_row, unsigned* __restrict__ hist_col,
    unsigned short* __restrict__ xb, unsigned short* __restrict__ w1t, unsigned short* __restrict__ wct) {
    __shared__ unsigned hb[HWRD];
    int bid = blockIdx.x, tid = threadIdx.x;
    if (bid < 2 * CB) {
        for (int w = tid; w < HWRD; w += 256) hb[w] = 0;
        __syncthreads();
        int b = bid & (CB - 1);
        int e0 = b * EPB;
        if (bid < CB) {   // row histogram + rank
            for (int e = e0 + tid; e < e0 + EPB; e += 256) {
                int r = er[e];
                unsigned sh = (r & 3) * 8;
                unsigned old = atomicAdd(&hb[r >> 2], 1u << sh);
                rank[e] = (unsigned char)((old >> sh) & 0xFFu);
            }
        } else {          // col histogram (in-degree)
            for (int e = e0 + tid; e < e0 + EPB; e += 256) {
                int c = ec[e];
                atomicAdd(&hb[c >> 2], 1u << ((c & 3) * 8));
            }
        }
        __syncthreads();
        unsigned* dst = (bid < CB ? hist_row : hist_col) + (size_t)b * HWRD;
        for (int w = tid; w < HWRD; w += 256) dst[w] = hb[w];
        return;
    }
    bid -= 2 * CB;
    if (bid < 12500) {    // convx: fp32 -> bf16, 8 elems/thread
        int t = bid * 256 + tid;
        const float* xf = x + (size_t)t * 8;
        float4 v0 = *(const float4*)(xf);
        float4 v1 = *(const float4*)(xf + 4);
        uint4 u;
        u.x = ((unsigned)f2b(v0.y) << 16) | f2b(v0.x);
        u.y = ((unsigned)f2b(v0.w) << 16) | f2b(v0.z);
        u.z = ((unsigned)f2b(v1.y) << 16) | f2b(v1.x);
        u.w = ((unsigned)f2b(v1.w) << 16) | f2b(v1.z);
        *(uint4*)(xb + (size_t)t * 8) = u;
        return;
    }
    bid -= 12500;
    if (bid < 1024) {     // transpose W1 -> bf16 w1t[n][k]
        int t = bid * 256 + tid;
        int n = t & 511, k = t >> 9;
        w1t[n * 512 + k] = f2b(W1[(size_t)k * 512 + n]);
        return;
    }
    bid -= 1024;
    {                     // wcat: combined final weight, transposed, bf16 (48*1536)
        int t = bid * 256 + tid;
        if (t < 48 * HW) {
            int k = t % HW, n = t / HW;
            float v = 0.f;
            if (n < NC) {
                if (k < 512)       v = W2[(size_t)k * NC + n] + W2[(size_t)(k + 512) * NC + n];
                else if (k < 1024) v = W2[(size_t)(k + 512) * NC + n] + W2[(size_t)(k + 1024) * NC + n];
                else               v = W2[(size_t)(k + 1024) * NC + n];
            }
            wct[n * HW + k] = f2b(v);
        }
    }
}

// ================= PREP: SWAR prefix over blocks (rows) + reduce (cols) =================
__global__ __launch_bounds__(256) void prep_kernel(
    const unsigned* __restrict__ hist_row, const unsigned* __restrict__ hist_col,
    unsigned* __restrict__ base_words, int* __restrict__ cntI, int* __restrict__ degI) {
    int t = blockIdx.x * 256 + threadIdx.x;
    if (t < HWRD) {
        unsigned acc = 0;   // 4 packed byte counters; totals <256/byte so no carry
        for (int b = 0; b < CB; ++b) {
            unsigned h = hist_row[(size_t)b * HWRD + t];
            base_words[(size_t)b * HWRD + t] = acc;
            acc += h;
        }
        int4 o; o.x = acc & 0xFF; o.y = (acc >> 8) & 0xFF; o.z = (acc >> 16) & 0xFF; o.w = (acc >> 24) & 0xFF;
        ((int4*)cntI)[t] = o;
    } else if (t < 2 * HWRD) {
        int w = t - HWRD;
        unsigned acc = 0;
        for (int b = 0; b < CB; ++b) acc += hist_col[(size_t)b * HWRD + w];
        int4 o; o.x = acc & 0xFF; o.y = (acc >> 8) & 0xFF; o.z = (acc >> 16) & 0xFF; o.w = (acc >> 24) & 0xFF;
        ((int4*)degI)[w] = o;
    }
}

// ================= scans =================
__global__ __launch_bounds__(1024) void scan1_kernel(const int* __restrict__ cnt,
                                                     int* __restrict__ excl, int* __restrict__ bsum) {
    __shared__ int buf[1024];
    int tid = threadIdx.x, gid = blockIdx.x * 1024 + tid;
    int v = (gid < NN) ? cnt[gid] : 0;
    buf[tid] = v;
    __syncthreads();
    int acc = v;
    for (int off = 1; off < 1024; off <<= 1) {
        int t = (tid >= off) ? buf[tid - off] : 0;
        __syncthreads();
        acc += t;
        buf[tid] = acc;
        __syncthreads();
    }
    if (gid < NN) excl[gid] = acc - v;
    if (tid == 1023) bsum[blockIdx.x] = acc;
}

__global__ void scan2_kernel(const int* __restrict__ bsum, int* __restrict__ boff) {
    int tid = threadIdx.x;  // one wave, SCAN_NB=49
    int orig = (tid < SCAN_NB) ? bsum[tid] : 0;
    int v = orig;
    #pragma unroll
    for (int off = 1; off < 64; off <<= 1) {
        int t = __shfl_up(v, off, 64);
        if (tid >= off) v += t;
    }
    if (tid < SCAN_NB) boff[tid] = v - orig;
}

__global__ void scan3_kernel(int* __restrict__ rowptr, const int* __restrict__ boff,
                             const int* __restrict__ deg, float* __restrict__ dinv,
                             float* __restrict__ sdv) {
    int gid = blockIdx.x * 256 + threadIdx.x;
    if (gid < NN) {
        rowptr[gid] += boff[gid >> 10];
        float d = (float)(deg[gid] + 1);
        dinv[gid] = rsqrtf(d);
        sdv[gid] = sqrtf(d);
    }
    if (gid == 0) rowptr[NN] = NE;
}

// ================= MEGA2: [scatter | gemm1 BK=32 (R1/R6 proven structure)] ==================
// gemm1 output: ONLY t8 = fp8(dinv[row] * relu(x@W1+b1))  -- no bf16 copy (gemm2 decodes fp8).
__global__ __launch_bounds__(256) void mega2_kernel(
    const int* __restrict__ er, const int* __restrict__ ec, const int* __restrict__ rowptr,
    const unsigned char* __restrict__ rank, const unsigned char* __restrict__ base8,
    int* __restrict__ colss,
    const unsigned short* __restrict__ xb, const unsigned short* __restrict__ w1t,
    const float* __restrict__ b1, const float* __restrict__ dinv,
    unsigned char* __restrict__ t8) {
    __shared__ __align__(16) unsigned short As[128 * 32];
    __shared__ __align__(16) unsigned short Bs[128 * 32];
    int bid = blockIdx.x;
    if (bid < CB) {   // scatter (atomic-free), one histogram slice per block
        int tid = threadIdx.x;
        const unsigned char* bb = base8 + (size_t)bid * 50000;
        int e0 = bid * EPB;
        int e = e0 + tid;
        #pragma unroll 4
        for (int it = 0; it < EPB / 256; ++it, e += 256) {
            int r = er[e], c = ec[e];
            colss[rowptr[r] + (int)bb[r] + (int)rank[e]] = c;
        }
        if (e < e0 + EPB) {   // tail: EPB % 256 = 106 edges
            int r = er[e], c = ec[e];
            colss[rowptr[r] + (int)bb[r] + (int)rank[e]] = c;
        }
        return;
    }
    bid -= CB;
    // ---- gemm1: t = relu(x@W1+b1) -> t8 fp8 (dinv[row]-prescaled) ----
    const int m0 = (bid >> 2) * 128, n0 = (bid & 3) * 128;
    const int tid = threadIdx.x;
    const int wave = tid >> 6, lane = tid & 63;
    const int q = lane >> 4, c = lane & 15;
    const int wm = wave & 1, wn = wave >> 1;

    float4v acc[4][4];
    for (int i = 0; i < 4; ++i)
        for (int j = 0; j < 4; ++j)
            acc[i][j] = (float4v){0.f, 0.f, 0.f, 0.f};

    for (int k0 = 0; k0 < FI; k0 += 32) {
        __syncthreads();
        #pragma unroll
        for (int h = 0; h < 2; ++h) {
            int chunk = h * 256 + wave * 64 + lane;
            int r = chunk >> 2, kc = chunk & 3;
            int gm = m0 + r; gm = gm < NN ? gm : NN - 1;
            async_copy16((char*)As + (size_t)(h * 256 + wave * 64) * 16,
                         xb + (size_t)gm * FI + k0 + kc * 8);
            async_copy16((char*)Bs + (size_t)(h * 256 + wave * 64) * 16,
                         w1t + (size_t)(n0 + r) * FI + k0 + kc * 8);
        }
        __syncthreads();
        short8 a[4], b[4];
        #pragma unroll
        for (int mi = 0; mi < 4; ++mi)
            a[mi] = *(const short8*)(As + ((wm * 64 + mi * 16 + c) * 32 + q * 8));
        #pragma unroll
        for (int ni = 0; ni < 4; ++ni)
            b[ni] = *(const short8*)(Bs + ((wn * 64 + ni * 16 + c) * 32 + q * 8));
        #pragma unroll
        for (int mi = 0; mi < 4; ++mi)
            #pragma unroll
            for (int ni = 0; ni < 4; ++ni)
                acc[mi][ni] = __builtin_amdgcn_mfma_f32_16x16x32_bf16(a[mi], b[ni], acc[mi][ni], 0, 0, 0);
    }
    // epilogue: per-row dinv hoisted out of the ni loop
    float dv[4][4];
    #pragma unroll
    for (int mi = 0; mi < 4; ++mi) {
        int rbase = m0 + wm * 64 + mi * 16 + q * 4;
        #pragma unroll
        for (int r = 0; r < 4; ++r) {
            int row = rbase + r;
            dv[mi][r] = dinv[row < NN ? row : NN - 1];
        }
    }
    #pragma unroll
    for (int ni = 0; ni < 4; ++ni) {
        int col = n0 + wn * 64 + ni * 16 + c;
        float bias = b1[col];
        #pragma unroll
        for (int mi = 0; mi < 4; ++mi) {
            int rbase = m0 + wm * 64 + mi * 16 + q * 4;
            #pragma unroll
            for (int r = 0; r < 4; ++r) {
                int row = rbase + r;
                if (row < NN) {
                    float v = acc[mi][ni][r] + bias;
                    v = v > 0.f ? v : 0.f;
                    t8[(size_t)row * FI + col] = f2e4m3(dv[mi][r] * v);
                }
            }
        }
    }
}

// ================= SpMM (fp8 gather; prescaled operand; fp8-only output) ====================
// dst8[i] = fp8( dinv[i]^2 * ( decode(src8[i]) + sum_c decode(src8[c]) ) )
//         = fp8( dinv[i] * out[i] )  -- directly the next pass's / gemm2's operand form.
#define DEC8A(g)                                                            \
    {   f32x2 p0 = __builtin_amdgcn_cvt_pk_f32_fp8((int)(g).x, false);      \
        f32x2 p1 = __builtin_amdgcn_cvt_pk_f32_fp8((int)(g).x, true);       \
        f32x2 p2 = __builtin_amdgcn_cvt_pk_f32_fp8((int)(g).y, false);      \
        f32x2 p3 = __builtin_amdgcn_cvt_pk_f32_fp8((int)(g).y, true);       \
        a0 += p0.x; a1 += p0.y;                                             \
        a2 += p1.x; a3 += p1.y;                                             \
        a4 += p2.x; a5 += p2.y;                                             \
        a6 += p3.x; a7 += p3.y; }

__global__ __launch_bounds__(256) void spmm_kernel(
    const unsigned char* __restrict__ src8, unsigned char* __restrict__ dst8,
    const int* __restrict__ rowptr, const int* __restrict__ cols,
    const float* __restrict__ dinv) {
    int i = blockIdx.x * 4 + (threadIdx.x >> 6);
    if (i >= NN) return;
    int lane = threadIdx.x & 63;
    const float di = dinv[i];
    const unsigned char* bin = src8 + lane * 8;

    float a0, a1, a2, a3, a4, a5, a6, a7;
    {   // self-loop seed from own fp8 row: decode = di*t[i]
        uint2 u = *(const uint2*)(bin + (size_t)i * FI);
        f32x2 p0 = __builtin_amdgcn_cvt_pk_f32_fp8((int)u.x, false);
        f32x2 p1 = __builtin_amdgcn_cvt_pk_f32_fp8((int)u.x, true);
        f32x2 p2 = __builtin_amdgcn_cvt_pk_f32_fp8((int)u.y, false);
        f32x2 p3 = __builtin_amdgcn_cvt_pk_f32_fp8((int)u.y, true);
        a0 = p0.x; a1 = p0.y; a2 = p1.x; a3 = p1.y;
        a4 = p2.x; a5 = p2.y; a6 = p3.x; a7 = p3.y;
    }
    int k = rowptr[i], e = rowptr[i + 1];
    for (; k + 8 <= e; k += 8) {
        int c0 = cols[k + 0], c1 = cols[k + 1], c2 = cols[k + 2], c3 = cols[k + 3];
        int c4 = cols[k + 4], c5 = cols[k + 5], c6 = cols[k + 6], c7 = cols[k + 7];
        uint2 g0 = *(const uint2*)(bin + (size_t)c0 * FI);
        uint2 g1 = *(const uint2*)(bin + (size_t)c1 * FI);
        uint2 g2 = *(const uint2*)(bin + (size_t)c2 * FI);
        uint2 g3 = *(const uint2*)(bin + (size_t)c3 * FI);
        uint2 g4 = *(const uint2*)(bin + (size_t)c4 * FI);
        uint2 g5 = *(const uint2*)(bin + (size_t)c5 * FI);
        uint2 g6 = *(const uint2*)(bin + (size_t)c6 * FI);
        uint2 g7 = *(const uint2*)(bin + (size_t)c7 * FI);
        DEC8A(g0) DEC8A(g1) DEC8A(g2) DEC8A(g3)
        DEC8A(g4) DEC8A(g5) DEC8A(g6) DEC8A(g7)
    }
    for (; k < e; ++k) {
        int cc = cols[k];
        uint2 g = *(const uint2*)(bin + (size_t)cc * FI);
        DEC8A(g)
    }
    float s = di * di;   // out = di*total; stored operand = dinv*out = di^2*total
    float s0 = s * a0, s1 = s * a1, s2 = s * a2, s3 = s * a3;
    float s4 = s * a4, s5 = s * a5, s6 = s * a6, s7 = s * a7;
    unsigned r0 = (unsigned)__builtin_amdgcn_cvt_pk_fp8_f32(s0, s1, 0, false);
    r0 = (unsigned)__builtin_amdgcn_cvt_pk_fp8_f32(s2, s3, (int)r0, true);
    unsigned r1 = (unsigned)__builtin_amdgcn_cvt_pk_fp8_f32(s4, s5, 0, false);
    r1 = (unsigned)__builtin_amdgcn_cvt_pk_fp8_f32(s6, s7, (int)r1, true);
    uint2 o8; o8.x = r0; o8.y = r1;
    *(uint2*)(dst8 + lane * 8 + (size_t)i * FI) = o8;
}

// ================= GEMM2 + log_softmax (fp8 A-operands, bf16 W, fp32 out) ===================
// A rows are stored as fp8(dinv[r]*h[r]); logits = sd[r]*(A_dec @ wct) + b2, sd = sqrt(deg+1).
__global__ __launch_bounds__(256) void gemm2_kernel(
    const unsigned char* __restrict__ t8, const unsigned char* __restrict__ s18,
    const unsigned char* __restrict__ s28, const unsigned short* __restrict__ wct,
    const float* __restrict__ b2p, const float* __restrict__ sdv, float* __restrict__ out) {
    int wave = threadIdx.x >> 6, lane = threadIdx.x & 63;
    int q = lane >> 4, c = lane & 15;
    int row0 = blockIdx.x * 64 + wave * 16;
    int ra = row0 + c; ra = ra < NN ? ra : NN - 1;
    const unsigned char* seg[3] = { t8  + (size_t)ra * FI + q * 8,
                                    s18 + (size_t)ra * FI + q * 8,
                                    s28 + (size_t)ra * FI + q * 8 };
    const unsigned short* bp0 = wct + (size_t)(c)      * HW + q * 8;
    const unsigned short* bp1 = wct + (size_t)(16 + c) * HW + q * 8;
    const unsigned short* bp2 = wct + (size_t)(32 + c) * HW + q * 8;

    float4v A0 = {0.f,0.f,0.f,0.f}, A1 = {0.f,0.f,0.f,0.f}, A2 = {0.f,0.f,0.f,0.f};
    #pragma unroll
    for (int s = 0; s < 3; ++s) {
        const unsigned char* ap = seg[s];
        #pragma unroll 4
        for (int k0 = 0; k0 < 512; k0 += 32) {
            uint2 ga = *(const uint2*)(ap + k0);
            short8 a  = dec8b(ga);
            short8 b0 = *(const short8*)(bp0 + s * 512 + k0);
            short8 b1 = *(const short8*)(bp1 + s * 512 + k0);
            short8 b2 = *(const short8*)(bp2 + s * 512 + k0);
            A0 = __builtin_amdgcn_mfma_f32_16x16x32_bf16(a, b0, A0, 0, 0, 0);
            A1 = __builtin_amdgcn_mfma_f32_16x16x32_bf16(a, b1, A1, 0, 0, 0);
            A2 = __builtin_amdgcn_mfma_f32_16x16x32_bf16(a, b2, A2, 0, 0, 0);
        }
    }
    float bias0 = b2p[c];
    float bias1 = b2p[16 + c];
    float bias2 = (c < 8) ? b2p[32 + c] : 0.f;
    float sdr[4];
    #pragma unroll
    for (int r = 0; r < 4; ++r) {
        int rowg = row0 + q * 4 + r;
        sdr[r] = sdv[rowg < NN ? rowg : NN - 1];
    }
    #pragma unroll
    for (int r = 0; r < 4; ++r) {
        float v0 = sdr[r] * A0[r] + bias0;
        float v1 = sdr[r] * A1[r] + bias1;
        float v2 = (c < 8) ? (sdr[r] * A2[r] + bias2) : -1e30f;
        float mx = fmaxf(fmaxf(v0, v1), v2);
        #pragma unroll
        for (int d = 1; d < 16; d <<= 1) mx = fmaxf(mx, __shfl_xor(mx, d, 64));
        float s = __expf(v0 - mx) + __expf(v1 - mx) + ((c < 8) ? __expf(v2 - mx) : 0.f);
        #pragma unroll
        for (int d = 1; d < 16; d <<= 1) s += __shfl_xor(s, d, 64);
        float lse = mx + __logf(s);
        int rowg = row0 + q * 4 + r;
        if (rowg < NN) {
            out[(size_t)rowg * NC + c]      = v0 - lse;
            out[(size_t)rowg * NC + 16 + c] = v1 - lse;
            if (c < 8) out[(size_t)rowg * NC + 32 + c] = v2 - lse;
        }
    }
}

extern "C" void kernel_launch(void* const* d_in, const int* in_sizes, int n_in,
                              void* d_out, int out_size, void* d_ws, size_t ws_size,
                              hipStream_t stream) {
    const float* x  = (const float*)d_in[0];
    const int*   er = (const int*)d_in[1];
    const int*   ec = (const int*)d_in[2];
    const float* W1 = (const float*)d_in[3];
    const float* b1 = (const float*)d_in[4];
    const float* W2 = (const float*)d_in[5];
    const float* b2 = (const float*)d_in[6];
    float* out = (float*)d_out;

    char* p = (char*)d_ws;
    auto alloc = [&](size_t bytes) { char* r = p; p += (bytes + 255) & ~((size_t)255); return r; };
    int*      cntI   = (int*)      alloc((size_t)NN * 4);
    int*      degI   = (int*)      alloc((size_t)NN * 4);
    int*      rowptr = (int*)      alloc((size_t)(NN + 1) * 4);
    float*    dinv   = (float*)    alloc((size_t)NN * 4);
    float*    sdv    = (float*)    alloc((size_t)NN * 4);
    int*      bsum   = (int*)      alloc((size_t)SCAN_NB * 4);
    int*      boff   = (int*)      alloc((size_t)SCAN_NB * 4);
    unsigned char* rank = (unsigned char*)alloc((size_t)NE);
    int*      colss  = (int*)      alloc((size_t)NE * 4);
    unsigned* hist_row = (unsigned*)alloc((size_t)CB * HWRD * 4);   // 12.8MB, dead after prep
    unsigned* hist_col = (unsigned*)alloc((size_t)CB * HWRD * 4);   // 12.8MB, dead after prep
    unsigned* base_w   = (unsigned*)alloc((size_t)CB * HWRD * 4);   // 12.8MB, dead after mega2
    unsigned short* w1t  = (unsigned short*)alloc((size_t)512 * 512 * 2);
    unsigned short* wct  = (unsigned short*)alloc((size_t)48 * HW * 2);
    unsigned short* xb   = (unsigned short*)alloc((size_t)NN * FI * 2);
    unsigned char*  s18  = (unsigned char*)alloc((size_t)NN * FI);
    // aliases: t8 over the (dead after prep) histograms; s2_8 over (dead after gemm1) xb
    unsigned char*  t8  = (unsigned char*)hist_row;   // 25.6MB needed; hist_row+hist_col = 25.6MB
    unsigned char*  s28 = (unsigned char*)xb;

    // L1: independent prep work, count parts first
    mega1_kernel<<<2 * CB + 12500 + 1024 + 288, 256, 0, stream>>>(
        er, ec, x, W1, W2, rank, hist_row, hist_col, xb, w1t, wct);
    // L2: cross-block prefix (rows) + reduce (cols)
    prep_kernel<<<(2 * HWRD + 255) / 256, 256, 0, stream>>>(hist_row, hist_col, base_w, cntI, degI);
    // L3-5: rowptr scan + dinv/sd
    scan1_kernel<<<SCAN_NB, 1024, 0, stream>>>(cntI, rowptr, bsum);
    scan2_kernel<<<1, 64, 0, stream>>>(bsum, boff);
    scan3_kernel<<<(NN + 255) / 256, 256, 0, stream>>>(rowptr, boff, degI, dinv, sdv);
    // L6: scatter | gemm1 (BK=32, fp8-only output) -- t8 overwrites hist_* (dead), base_w live
    mega2_kernel<<<CB + ((NN + 127) / 128) * 4, 256, 0, stream>>>(
        er, ec, rowptr, rank, (const unsigned char*)base_w, colss, xb, w1t, b1, dinv, t8);
    // L7-8: SpMMs (fp8 gather, pure-add, fp8-only outputs)
    spmm_kernel<<<(NN + 3) / 4, 256, 0, stream>>>(t8, s18, rowptr, colss, dinv);
    spmm_kernel<<<(NN + 3) / 4, 256, 0, stream>>>(s18, s28, rowptr, colss, dinv);
    // L9: final GEMM (fp8 A decode) + log_softmax
    gemm2_kernel<<<(NN + 63) / 64, 256, 0, stream>>>(t8, s18, s28, wct, b2, sdv, out);
}

// Round 9
// 605.372 us; speedup vs baseline: 1.2985x; 1.0066x over previous
//
#include <hip/hip_runtime.h>
#include <stdint.h>

#define NN 50000
#define NE 1600000
#define FI 512
#define DD 512
#define NC 40
#define HW 1536
#define SCAN_NB 49        // ceil(NN/1024)
#define CB 256            // histogram blocks
#define EPB (NE / CB)     // 6250 edges per histogram block
#define HWRD 12500        // 50000 bins / 4 bytes per word

typedef __attribute__((ext_vector_type(8))) short short8;
typedef __attribute__((ext_vector_type(4))) float float4v;
typedef __attribute__((ext_vector_type(2))) float f32x2;

static __device__ __forceinline__ unsigned short f2b(float f) {
    union { float f; unsigned int i; } v; v.f = f;
    unsigned int r = v.i + 0x7fffu + ((v.i >> 16) & 1u);
    return (unsigned short)(r >> 16);
}
static __device__ __forceinline__ unsigned char f2e4m3(float f) {
    return (unsigned char)(__builtin_amdgcn_cvt_pk_fp8_f32(f, f, 0, false) & 0xFF);
}
static __device__ __forceinline__ void async_copy16(void* lds, const void* g) {
    __builtin_amdgcn_global_load_lds((const __attribute__((address_space(1))) void*)g,
                                     (__attribute__((address_space(3))) void*)lds, 16, 0, 0);
}
// fp8x8 -> bf16x8 (exact: every e4m3 value is representable in bf16)
static __device__ __forceinline__ short8 dec8b(uint2 g) {
    f32x2 p0 = __builtin_amdgcn_cvt_pk_f32_fp8((int)g.x, false);
    f32x2 p1 = __builtin_amdgcn_cvt_pk_f32_fp8((int)g.x, true);
    f32x2 p2 = __builtin_amdgcn_cvt_pk_f32_fp8((int)g.y, false);
    f32x2 p3 = __builtin_amdgcn_cvt_pk_f32_fp8((int)g.y, true);
    short8 r;
    r[0] = (short)f2b(p0.x); r[1] = (short)f2b(p0.y);
    r[2] = (short)f2b(p1.x); r[3] = (short)f2b(p1.y);
    r[4] = (short)f2b(p2.x); r[5] = (short)f2b(p2.y);
    r[6] = (short)f2b(p3.x); r[7] = (short)f2b(p3.y);
    return r;
}

// ================= MEGA1: [count_row | count_col | convx | transpose | wcat] =================
__global__ __launch_bounds__(256) void mega1_kernel(
    const int* __restrict__ er, const int* __restrict__ ec,
    const float* __restrict__ x, const float* __restrict__ W1, const float* __restrict__ W2,
    unsigned char* __restrict__ rank, unsigned* __restrict__ hist_row, unsigned* __restrict__ hist_col,
    unsigned short* __restrict__ xb, unsigned short* __restrict__ w1t, unsigned short* __restrict__ wct) {
    __shared__ unsigned hb[HWRD];
    int bid = blockIdx.x, tid = threadIdx.x;
    if (bid < 2 * CB) {
        for (int w = tid; w < HWRD; w += 256) hb[w] = 0;
        __syncthreads();
        int b = bid & (CB - 1);
        int e0 = b * EPB;
        if (bid < CB) {   // row histogram + rank
            for (int e = e0 + tid; e < e0 + EPB; e += 256) {
                int r = er[e];
                unsigned sh = (r & 3) * 8;
                unsigned old = atomicAdd(&hb[r >> 2], 1u << sh);
                rank[e] = (unsigned char)((old >> sh) & 0xFFu);
            }
        } else {          // col histogram (in-degree)
            for (int e = e0 + tid; e < e0 + EPB; e += 256) {
                int c = ec[e];
                atomicAdd(&hb[c >> 2], 1u << ((c & 3) * 8));
            }
        }
        __syncthreads();
        unsigned* dst = (bid < CB ? hist_row : hist_col) + (size_t)b * HWRD;
        for (int w = tid; w < HWRD; w += 256) dst[w] = hb[w];
        return;
    }
    bid -= 2 * CB;
    if (bid < 12500) {    // convx: fp32 -> bf16, 8 elems/thread
        int t = bid * 256 + tid;
        const float* xf = x + (size_t)t * 8;
        float4 v0 = *(const float4*)(xf);
        float4 v1 = *(const float4*)(xf + 4);
        uint4 u;
        u.x = ((unsigned)f2b(v0.y) << 16) | f2b(v0.x);
        u.y = ((unsigned)f2b(v0.w) << 16) | f2b(v0.z);
        u.z = ((unsigned)f2b(v1.y) << 16) | f2b(v1.x);
        u.w = ((unsigned)f2b(v1.w) << 16) | f2b(v1.z);
        *(uint4*)(xb + (size_t)t * 8) = u;
        return;
    }
    bid -= 12500;
    if (bid < 1024) {     // transpose W1 -> bf16 w1t[n][k]
        int t = bid * 256 + tid;
        int n = t & 511, k = t >> 9;
        w1t[n * 512 + k] = f2b(W1[(size_t)k * 512 + n]);
        return;
    }
    bid -= 1024;
    {                     // wcat: combined final weight, transposed, bf16 (48*1536)
        int t = bid * 256 + tid;
        if (t < 48 * HW) {
            int k = t % HW, n = t / HW;
            float v = 0.f;
            if (n < NC) {
                if (k < 512)       v = W2[(size_t)k * NC + n] + W2[(size_t)(k + 512) * NC + n];
                else if (k < 1024) v = W2[(size_t)(k + 512) * NC + n] + W2[(size_t)(k + 1024) * NC + n];
                else               v = W2[(size_t)(k + 1024) * NC + n];
            }
            wct[n * HW + k] = f2b(v);
        }
    }
}

// ================= PREP: SWAR prefix over blocks (rows) + reduce (cols) =================
__global__ __launch_bounds__(256) void prep_kernel(
    const unsigned* __restrict__ hist_row, const unsigned* __restrict__ hist_col,
    unsigned* __restrict__ base_words, int* __restrict__ cntI, int* __restrict__ degI) {
    int t = blockIdx.x * 256 + threadIdx.x;
    if (t < HWRD) {
        unsigned acc = 0;   // 4 packed byte counters; totals <256/byte so no carry
        for (int b = 0; b < CB; ++b) {
            unsigned h = hist_row[(size_t)b * HWRD + t];
            base_words[(size_t)b * HWRD + t] = acc;
            acc += h;
        }
        int4 o; o.x = acc & 0xFF; o.y = (acc >> 8) & 0xFF; o.z = (acc >> 16) & 0xFF; o.w = (acc >> 24) & 0xFF;
        ((int4*)cntI)[t] = o;
    } else if (t < 2 * HWRD) {
        int w = t - HWRD;
        unsigned acc = 0;
        for (int b = 0; b < CB; ++b) acc += hist_col[(size_t)b * HWRD + w];
        int4 o; o.x = acc & 0xFF; o.y = (acc >> 8) & 0xFF; o.z = (acc >> 16) & 0xFF; o.w = (acc >> 24) & 0xFF;
        ((int4*)degI)[w] = o;
    }
}

// ================= scans =================
__global__ __launch_bounds__(1024) void scan1_kernel(const int* __restrict__ cnt,
                                                     int* __restrict__ excl, int* __restrict__ bsum) {
    __shared__ int buf[1024];
    int tid = threadIdx.x, gid = blockIdx.x * 1024 + tid;
    int v = (gid < NN) ? cnt[gid] : 0;
    buf[tid] = v;
    __syncthreads();
    int acc = v;
    for (int off = 1; off < 1024; off <<= 1) {
        int t = (tid >= off) ? buf[tid - off] : 0;
        __syncthreads();
        acc += t;
        buf[tid] = acc;
        __syncthreads();
    }
    if (gid < NN) excl[gid] = acc - v;
    if (tid == 1023) bsum[blockIdx.x] = acc;
}

__global__ void scan2_kernel(const int* __restrict__ bsum, int* __restrict__ boff) {
    int tid = threadIdx.x;  // one wave, SCAN_NB=49
    int orig = (tid < SCAN_NB) ? bsum[tid] : 0;
    int v = orig;
    #pragma unroll
    for (int off = 1; off < 64; off <<= 1) {
        int t = __shfl_up(v, off, 64);
        if (tid >= off) v += t;
    }
    if (tid < SCAN_NB) boff[tid] = v - orig;
}

__global__ void scan3_kernel(int* __restrict__ rowptr, const int* __restrict__ boff,
                             const int* __restrict__ deg, float* __restrict__ dinv,
                             float* __restrict__ sdv) {
    int gid = blockIdx.x * 256 + threadIdx.x;
    if (gid < NN) {
        rowptr[gid] += boff[gid >> 10];
        float d = (float)(deg[gid] + 1);
        dinv[gid] = rsqrtf(d);
        sdv[gid] = sqrtf(d);
    }
    if (gid == 0) rowptr[NN] = NE;
}

// ================= MEGA2: [scatter | gemm1 BK=32] ==========================================
// gemm1 output: ONLY t8 = fp8(dinv[row] * relu(x@W1+b1)). Epilogue loads dinv inline
// (R8's dv-hoist cost 8 VGPR and dropped occupancy 27->18.5% -- reverted).
__global__ __launch_bounds__(256) void mega2_kernel(
    const int* __restrict__ er, const int* __restrict__ ec, const int* __restrict__ rowptr,
    const unsigned char* __restrict__ rank, const unsigned char* __restrict__ base8,
    int* __restrict__ colss,
    const unsigned short* __restrict__ xb, const unsigned short* __restrict__ w1t,
    const float* __restrict__ b1, const float* __restrict__ dinv,
    unsigned char* __restrict__ t8) {
    __shared__ __align__(16) unsigned short As[128 * 32];
    __shared__ __align__(16) unsigned short Bs[128 * 32];
    int bid = blockIdx.x;
    if (bid < CB) {   // scatter (atomic-free), one histogram slice per block
        int tid = threadIdx.x;
        const unsigned char* bb = base8 + (size_t)bid * 50000;
        int e0 = bid * EPB;
        int e = e0 + tid;
        #pragma unroll 4
        for (int it = 0; it < EPB / 256; ++it, e += 256) {
            int r = er[e], c = ec[e];
            colss[rowptr[r] + (int)bb[r] + (int)rank[e]] = c;
        }
        if (e < e0 + EPB) {   // tail: EPB % 256 = 106 edges
            int r = er[e], c = ec[e];
            colss[rowptr[r] + (int)bb[r] + (int)rank[e]] = c;
        }
        return;
    }
    bid -= CB;
    // ---- gemm1: t = relu(x@W1+b1) -> t8 fp8 (dinv[row]-prescaled) ----
    const int m0 = (bid >> 2) * 128, n0 = (bid & 3) * 128;
    const int tid = threadIdx.x;
    const int wave = tid >> 6, lane = tid & 63;
    const int q = lane >> 4, c = lane & 15;
    const int wm = wave & 1, wn = wave >> 1;

    float4v acc[4][4];
    for (int i = 0; i < 4; ++i)
        for (int j = 0; j < 4; ++j)
            acc[i][j] = (float4v){0.f, 0.f, 0.f, 0.f};

    for (int k0 = 0; k0 < FI; k0 += 32) {
        __syncthreads();
        #pragma unroll
        for (int h = 0; h < 2; ++h) {
            int chunk = h * 256 + wave * 64 + lane;
            int r = chunk >> 2, kc = chunk & 3;
            int gm = m0 + r; gm = gm < NN ? gm : NN - 1;
            async_copy16((char*)As + (size_t)(h * 256 + wave * 64) * 16,
                         xb + (size_t)gm * FI + k0 + kc * 8);
            async_copy16((char*)Bs + (size_t)(h * 256 + wave * 64) * 16,
                         w1t + (size_t)(n0 + r) * FI + k0 + kc * 8);
        }
        __syncthreads();
        short8 a[4], b[4];
        #pragma unroll
        for (int mi = 0; mi < 4; ++mi)
            a[mi] = *(const short8*)(As + ((wm * 64 + mi * 16 + c) * 32 + q * 8));
        #pragma unroll
        for (int ni = 0; ni < 4; ++ni)
            b[ni] = *(const short8*)(Bs + ((wn * 64 + ni * 16 + c) * 32 + q * 8));
        #pragma unroll
        for (int mi = 0; mi < 4; ++mi)
            #pragma unroll
            for (int ni = 0; ni < 4; ++ni)
                acc[mi][ni] = __builtin_amdgcn_mfma_f32_16x16x32_bf16(a[mi], b[ni], acc[mi][ni], 0, 0, 0);
    }
    #pragma unroll
    for (int ni = 0; ni < 4; ++ni) {
        int col = n0 + wn * 64 + ni * 16 + c;
        float bias = b1[col];
        #pragma unroll
        for (int mi = 0; mi < 4; ++mi) {
            int rbase = m0 + wm * 64 + mi * 16 + q * 4;
            #pragma unroll
            for (int r = 0; r < 4; ++r) {
                int row = rbase + r;
                if (row < NN) {
                    float v = acc[mi][ni][r] + bias;
                    v = v > 0.f ? v : 0.f;
                    t8[(size_t)row * FI + col] = f2e4m3(dinv[row] * v);
                }
            }
        }
    }
}

// ================= SpMM (fp8 gather; packed dual accumulators) ==============================
// dst8[i] = fp8( dinv[i]^2 * ( decode(src8[i]) + sum_c decode(src8[c]) ) )
// f32x2 accumulators -> v_pk_add_f32 (half the add instrs); even/odd edges use separate
// banks (A/B) to break the serial accumulation dependency chain.
#define DECP(g, X0, X1, X2, X3)                                             \
    {   X0 += __builtin_amdgcn_cvt_pk_f32_fp8((int)(g).x, false);           \
        X1 += __builtin_amdgcn_cvt_pk_f32_fp8((int)(g).x, true);            \
        X2 += __builtin_amdgcn_cvt_pk_f32_fp8((int)(g).y, false);           \
        X3 += __builtin_amdgcn_cvt_pk_f32_fp8((int)(g).y, true); }

__global__ __launch_bounds__(256) void spmm_kernel(
    const unsigned char* __restrict__ src8, unsigned char* __restrict__ dst8,
    const int* __restrict__ rowptr, const int* __restrict__ cols,
    const float* __restrict__ dinv) {
    int i = blockIdx.x * 4 + (threadIdx.x >> 6);
    if (i >= NN) return;
    int lane = threadIdx.x & 63;
    const float di = dinv[i];
    const unsigned char* bin = src8 + lane * 8;

    f32x2 A0, A1, A2, A3;
    f32x2 B0 = {0.f, 0.f}, B1 = {0.f, 0.f}, B2 = {0.f, 0.f}, B3 = {0.f, 0.f};
    {   // self-loop seed from own fp8 row: decode = di*t[i]
        uint2 u = *(const uint2*)(bin + (size_t)i * FI);
        A0 = __builtin_amdgcn_cvt_pk_f32_fp8((int)u.x, false);
        A1 = __builtin_amdgcn_cvt_pk_f32_fp8((int)u.x, true);
        A2 = __builtin_amdgcn_cvt_pk_f32_fp8((int)u.y, false);
        A3 = __builtin_amdgcn_cvt_pk_f32_fp8((int)u.y, true);
    }
    int k = rowptr[i], e = rowptr[i + 1];
    for (; k + 8 <= e; k += 8) {
        int c0 = cols[k + 0], c1 = cols[k + 1], c2 = cols[k + 2], c3 = cols[k + 3];
        int c4 = cols[k + 4], c5 = cols[k + 5], c6 = cols[k + 6], c7 = cols[k + 7];
        uint2 g0 = *(const uint2*)(bin + (size_t)c0 * FI);
        uint2 g1 = *(const uint2*)(bin + (size_t)c1 * FI);
        uint2 g2 = *(const uint2*)(bin + (size_t)c2 * FI);
        uint2 g3 = *(const uint2*)(bin + (size_t)c3 * FI);
        uint2 g4 = *(const uint2*)(bin + (size_t)c4 * FI);
        uint2 g5 = *(const uint2*)(bin + (size_t)c5 * FI);
        uint2 g6 = *(const uint2*)(bin + (size_t)c6 * FI);
        uint2 g7 = *(const uint2*)(bin + (size_t)c7 * FI);
        DECP(g0, A0, A1, A2, A3) DECP(g1, B0, B1, B2, B3)
        DECP(g2, A0, A1, A2, A3) DECP(g3, B0, B1, B2, B3)
        DECP(g4, A0, A1, A2, A3) DECP(g5, B0, B1, B2, B3)
        DECP(g6, A0, A1, A2, A3) DECP(g7, B0, B1, B2, B3)
    }
    for (; k < e; ++k) {
        int cc = cols[k];
        uint2 g = *(const uint2*)(bin + (size_t)cc * FI);
        DECP(g, A0, A1, A2, A3)
    }
    A0 += B0; A1 += B1; A2 += B2; A3 += B3;
    float s = di * di;   // out = di*total; stored operand = dinv*out = di^2*total
    unsigned r0 = (unsigned)__builtin_amdgcn_cvt_pk_fp8_f32(s * A0.x, s * A0.y, 0, false);
    r0 = (unsigned)__builtin_amdgcn_cvt_pk_fp8_f32(s * A1.x, s * A1.y, (int)r0, true);
    unsigned r1 = (unsigned)__builtin_amdgcn_cvt_pk_fp8_f32(s * A2.x, s * A2.y, 0, false);
    r1 = (unsigned)__builtin_amdgcn_cvt_pk_fp8_f32(s * A3.x, s * A3.y, (int)r1, true);
    uint2 o8; o8.x = r0; o8.y = r1;
    *(uint2*)(dst8 + lane * 8 + (size_t)i * FI) = o8;
}

// ================= GEMM2 + log_softmax (fp8 A-operands, bf16 W, fp32 out) ===================
// A rows are stored as fp8(dinv[r]*h[r]); logits = sd[r]*(A_dec @ wct) + b2, sd = sqrt(deg+1).
__global__ __launch_bounds__(256) void gemm2_kernel(
    const unsigned char* __restrict__ t8, const unsigned char* __restrict__ s18,
    const unsigned char* __restrict__ s28, const unsigned short* __restrict__ wct,
    const float* __restrict__ b2p, const float* __restrict__ sdv, float* __restrict__ out) {
    int wave = threadIdx.x >> 6, lane = threadIdx.x & 63;
    int q = lane >> 4, c = lane & 15;
    int row0 = blockIdx.x * 64 + wave * 16;
    int ra = row0 + c; ra = ra < NN ? ra : NN - 1;
    const unsigned char* seg[3] = { t8  + (size_t)ra * FI + q * 8,
                                    s18 + (size_t)ra * FI + q * 8,
                                    s28 + (size_t)ra * FI + q * 8 };
    const unsigned short* bp0 = wct + (size_t)(c)      * HW + q * 8;
    const unsigned short* bp1 = wct + (size_t)(16 + c) * HW + q * 8;
    const unsigned short* bp2 = wct + (size_t)(32 + c) * HW + q * 8;

    float4v A0 = {0.f,0.f,0.f,0.f}, A1 = {0.f,0.f,0.f,0.f}, A2 = {0.f,0.f,0.f,0.f};
    #pragma unroll
    for (int s = 0; s < 3; ++s) {
        const unsigned char* ap = seg[s];
        #pragma unroll 4
        for (int k0 = 0; k0 < 512; k0 += 32) {
            uint2 ga = *(const uint2*)(ap + k0);
            short8 a  = dec8b(ga);
            short8 b0 = *(const short8*)(bp0 + s * 512 + k0);
            short8 b1 = *(const short8*)(bp1 + s * 512 + k0);
            short8 b2 = *(const short8*)(bp2 + s * 512 + k0);
            A0 = __builtin_amdgcn_mfma_f32_16x16x32_bf16(a, b0, A0, 0, 0, 0);
            A1 = __builtin_amdgcn_mfma_f32_16x16x32_bf16(a, b1, A1, 0, 0, 0);
            A2 = __builtin_amdgcn_mfma_f32_16x16x32_bf16(a, b2, A2, 0, 0, 0);
        }
    }
    float bias0 = b2p[c];
    float bias1 = b2p[16 + c];
    float bias2 = (c < 8) ? b2p[32 + c] : 0.f;
    float sdr[4];
    #pragma unroll
    for (int r = 0; r < 4; ++r) {
        int rowg = row0 + q * 4 + r;
        sdr[r] = sdv[rowg < NN ? rowg : NN - 1];
    }
    #pragma unroll
    for (int r = 0; r < 4; ++r) {
        float v0 = sdr[r] * A0[r] + bias0;
        float v1 = sdr[r] * A1[r] + bias1;
        float v2 = (c < 8) ? (sdr[r] * A2[r] + bias2) : -1e30f;
        float mx = fmaxf(fmaxf(v0, v1), v2);
        #pragma unroll
        for (int d = 1; d < 16; d <<= 1) mx = fmaxf(mx, __shfl_xor(mx, d, 64));
        float s = __expf(v0 - mx) + __expf(v1 - mx) + ((c < 8) ? __expf(v2 - mx) : 0.f);
        #pragma unroll
        for (int d = 1; d < 16; d <<= 1) s += __shfl_xor(s, d, 64);
        float lse = mx + __logf(s);
        int rowg = row0 + q * 4 + r;
        if (rowg < NN) {
            out[(size_t)rowg * NC + c]      = v0 - lse;
            out[(size_t)rowg * NC + 16 + c] = v1 - lse;
            if (c < 8) out[(size_t)rowg * NC + 32 + c] = v2 - lse;
        }
    }
}

extern "C" void kernel_launch(void* const* d_in, const int* in_sizes, int n_in,
                              void* d_out, int out_size, void* d_ws, size_t ws_size,
                              hipStream_t stream) {
    const float* x  = (const float*)d_in[0];
    const int*   er = (const int*)d_in[1];
    const int*   ec = (const int*)d_in[2];
    const float* W1 = (const float*)d_in[3];
    const float* b1 = (const float*)d_in[4];
    const float* W2 = (const float*)d_in[5];
    const float* b2 = (const float*)d_in[6];
    float* out = (float*)d_out;

    char* p = (char*)d_ws;
    auto alloc = [&](size_t bytes) { char* r = p; p += (bytes + 255) & ~((size_t)255); return r; };
    int*      cntI   = (int*)      alloc((size_t)NN * 4);
    int*      degI   = (int*)      alloc((size_t)NN * 4);
    int*      rowptr = (int*)      alloc((size_t)(NN + 1) * 4);
    float*    dinv   = (float*)    alloc((size_t)NN * 4);
    float*    sdv    = (float*)    alloc((size_t)NN * 4);
    int*      bsum   = (int*)      alloc((size_t)SCAN_NB * 4);
    int*      boff   = (int*)      alloc((size_t)SCAN_NB * 4);
    unsigned char* rank = (unsigned char*)alloc((size_t)NE);
    int*      colss  = (int*)      alloc((size_t)NE * 4);
    unsigned* hist_row = (unsigned*)alloc((size_t)CB * HWRD * 4);   // 12.8MB, dead after prep
    unsigned* hist_col = (unsigned*)alloc((size_t)CB * HWRD * 4);   // 12.8MB, dead after prep
    unsigned* base_w   = (unsigned*)alloc((size_t)CB * HWRD * 4);   // 12.8MB, dead after mega2
    unsigned short* w1t  = (unsigned short*)alloc((size_t)512 * 512 * 2);
    unsigned short* wct  = (unsigned short*)alloc((size_t)48 * HW * 2);
    unsigned short* xb   = (unsigned short*)alloc((size_t)NN * FI * 2);
    unsigned char*  s18  = (unsigned char*)alloc((size_t)NN * FI);
    // aliases: t8 over the (dead after prep) histograms; s2_8 over (dead after gemm1) xb
    unsigned char*  t8  = (unsigned char*)hist_row;   // 25.6MB needed; hist_row+hist_col = 25.6MB
    unsigned char*  s28 = (unsigned char*)xb;

    // L1: independent prep work, count parts first
    mega1_kernel<<<2 * CB + 12500 + 1024 + 288, 256, 0, stream>>>(
        er, ec, x, W1, W2, rank, hist_row, hist_col, xb, w1t, wct);
    // L2: cross-block prefix (rows) + reduce (cols)
    prep_kernel<<<(2 * HWRD + 255) / 256, 256, 0, stream>>>(hist_row, hist_col, base_w, cntI, degI);
    // L3-5: rowptr scan + dinv/sd
    scan1_kernel<<<SCAN_NB, 1024, 0, stream>>>(cntI, rowptr, bsum);
    scan2_kernel<<<1, 64, 0, stream>>>(bsum, boff);
    scan3_kernel<<<(NN + 255) / 256, 256, 0, stream>>>(rowptr, boff, degI, dinv, sdv);
    // L6: scatter | gemm1 (BK=32, fp8-only output) -- t8 overwrites hist_* (dead), base_w live
    mega2_kernel<<<CB + ((NN + 127) / 128) * 4, 256, 0, stream>>>(
        er, ec, rowptr, rank, (const unsigned char*)base_w, colss, xb, w1t, b1, dinv, t8);
    // L7-8: SpMMs (fp8 gather, packed dual accumulators)
    spmm_kernel<<<(NN + 3) / 4, 256, 0, stream>>>(t8, s18, rowptr, colss, dinv);
    spmm_kernel<<<(NN + 3) / 4, 256, 0, stream>>>(s18, s28, rowptr, colss, dinv);
    // L9: final GEMM (fp8 A decode) + log_softmax
    gemm2_kernel<<<(NN + 63) / 64, 256, 0, stream>>>(t8, s18, s28, wct, b2, sdv, out);
}

// Round 10
// 524.060 us; speedup vs baseline: 1.5000x; 1.1552x over previous
//
#include <hip/hip_runtime.h>
#include <stdint.h>

#define NN 50000
#define NE 1600000
#define FI 512
#define DD 512
#define NC 40
#define SCAN_NB 49        // ceil(NN/1024)
#define CB 256            // histogram blocks
#define EPB (NE / CB)     // 6250 edges per histogram block
#define HWRD 12500        // 50000 bins / 4 bytes per word

typedef __attribute__((ext_vector_type(8))) short short8;
typedef __attribute__((ext_vector_type(4))) float float4v;
typedef __attribute__((ext_vector_type(2))) float f32x2;

static __device__ __forceinline__ unsigned short f2b(float f) {
    union { float f; unsigned int i; } v; v.f = f;
    unsigned int r = v.i + 0x7fffu + ((v.i >> 16) & 1u);
    return (unsigned short)(r >> 16);
}
static __device__ __forceinline__ float blo(unsigned int u) {
    union { unsigned int i; float f; } v; v.i = u << 16; return v.f;
}
static __device__ __forceinline__ float bhi(unsigned int u) {
    union { unsigned int i; float f; } v; v.i = u & 0xffff0000u; return v.f;
}
static __device__ __forceinline__ void async_copy16(void* lds, const void* g) {
    __builtin_amdgcn_global_load_lds((const __attribute__((address_space(1))) void*)g,
                                     (__attribute__((address_space(3))) void*)lds, 16, 0, 0);
}

// ================= MEGA1: [count_row | count_col | convx | transpose | wcpt] =================
// wcpt: combined projection weight [128][512] bf16 (row n = output col, col = k):
//   n<40:  g0 = W2[k]+W2[k+512]         (direct t term)
//   n<80:  g1 = W2[k+1024]+W2[k+1536]   (z1 -> A z1)
//   n<120: g2 = W2[k+2048]              (z2 -> A^2 z2)
//   else 0
__global__ __launch_bounds__(256) void mega1_kernel(
    const int* __restrict__ er, const int* __restrict__ ec,
    const float* __restrict__ x, const float* __restrict__ W1, const float* __restrict__ W2,
    unsigned char* __restrict__ rank, unsigned* __restrict__ hist_row, unsigned* __restrict__ hist_col,
    unsigned short* __restrict__ xb, unsigned short* __restrict__ w1t, unsigned short* __restrict__ wcpt) {
    __shared__ unsigned hb[HWRD];
    int bid = blockIdx.x, tid = threadIdx.x;
    if (bid < 2 * CB) {
        for (int w = tid; w < HWRD; w += 256) hb[w] = 0;
        __syncthreads();
        int b = bid & (CB - 1);
        int e0 = b * EPB;
        if (bid < CB) {   // row histogram + rank
            for (int e = e0 + tid; e < e0 + EPB; e += 256) {
                int r = er[e];
                unsigned sh = (r & 3) * 8;
                unsigned old = atomicAdd(&hb[r >> 2], 1u << sh);
                rank[e] = (unsigned char)((old >> sh) & 0xFFu);
            }
        } else {          // col histogram (in-degree)
            for (int e = e0 + tid; e < e0 + EPB; e += 256) {
                int c = ec[e];
                atomicAdd(&hb[c >> 2], 1u << ((c & 3) * 8));
            }
        }
        __syncthreads();
        unsigned* dst = (bid < CB ? hist_row : hist_col) + (size_t)b * HWRD;
        for (int w = tid; w < HWRD; w += 256) dst[w] = hb[w];
        return;
    }
    bid -= 2 * CB;
    if (bid < 12500) {    // convx: fp32 -> bf16, 8 elems/thread
        int t = bid * 256 + tid;
        const float* xf = x + (size_t)t * 8;
        float4 v0 = *(const float4*)(xf);
        float4 v1 = *(const float4*)(xf + 4);
        uint4 u;
        u.x = ((unsigned)f2b(v0.y) << 16) | f2b(v0.x);
        u.y = ((unsigned)f2b(v0.w) << 16) | f2b(v0.z);
        u.z = ((unsigned)f2b(v1.y) << 16) | f2b(v1.x);
        u.w = ((unsigned)f2b(v1.w) << 16) | f2b(v1.z);
        *(uint4*)(xb + (size_t)t * 8) = u;
        return;
    }
    bid -= 12500;
    if (bid < 1024) {     // transpose W1 -> bf16 w1t[n][k]
        int t = bid * 256 + tid;
        int n = t & 511, k = t >> 9;
        w1t[n * 512 + k] = f2b(W1[(size_t)k * 512 + n]);
        return;
    }
    bid -= 1024;
    {                     // wcpt builder: 128*512 elems, 256 blocks
        int t = bid * 256 + tid;   // < 65536 always
        int n = t >> 9, k = t & 511;
        float v = 0.f;
        if (n < 40)       v = W2[(size_t)k * NC + n] + W2[(size_t)(k + 512) * NC + n];
        else if (n < 80)  v = W2[(size_t)(k + 1024) * NC + (n - 40)] + W2[(size_t)(k + 1536) * NC + (n - 40)];
        else if (n < 120) v = W2[(size_t)(k + 2048) * NC + (n - 80)];
        wcpt[n * 512 + k] = f2b(v);
    }
}

// ================= PREP: SWAR prefix over blocks (rows) + reduce (cols) =================
__global__ __launch_bounds__(256) void prep_kernel(
    const unsigned* __restrict__ hist_row, const unsigned* __restrict__ hist_col,
    unsigned* __restrict__ base_words, int* __restrict__ cntI, int* __restrict__ degI) {
    int t = blockIdx.x * 256 + threadIdx.x;
    if (t < HWRD) {
        unsigned acc = 0;   // 4 packed byte counters; totals <256/byte so no carry
        for (int b = 0; b < CB; ++b) {
            unsigned h = hist_row[(size_t)b * HWRD + t];
            base_words[(size_t)b * HWRD + t] = acc;
            acc += h;
        }
        int4 o; o.x = acc & 0xFF; o.y = (acc >> 8) & 0xFF; o.z = (acc >> 16) & 0xFF; o.w = (acc >> 24) & 0xFF;
        ((int4*)cntI)[t] = o;
    } else if (t < 2 * HWRD) {
        int w = t - HWRD;
        unsigned acc = 0;
        for (int b = 0; b < CB; ++b) acc += hist_col[(size_t)b * HWRD + w];
        int4 o; o.x = acc & 0xFF; o.y = (acc >> 8) & 0xFF; o.z = (acc >> 16) & 0xFF; o.w = (acc >> 24) & 0xFF;
        ((int4*)degI)[w] = o;
    }
}

// ================= scans =================
__global__ __launch_bounds__(1024) void scan1_kernel(const int* __restrict__ cnt,
                                                     int* __restrict__ excl, int* __restrict__ bsum) {
    __shared__ int buf[1024];
    int tid = threadIdx.x, gid = blockIdx.x * 1024 + tid;
    int v = (gid < NN) ? cnt[gid] : 0;
    buf[tid] = v;
    __syncthreads();
    int acc = v;
    for (int off = 1; off < 1024; off <<= 1) {
        int t = (tid >= off) ? buf[tid - off] : 0;
        __syncthreads();
        acc += t;
        buf[tid] = acc;
        __syncthreads();
    }
    if (gid < NN) excl[gid] = acc - v;
    if (tid == 1023) bsum[blockIdx.x] = acc;
}

__global__ void scan2_kernel(const int* __restrict__ bsum, int* __restrict__ boff) {
    int tid = threadIdx.x;  // one wave, SCAN_NB=49
    int orig = (tid < SCAN_NB) ? bsum[tid] : 0;
    int v = orig;
    #pragma unroll
    for (int off = 1; off < 64; off <<= 1) {
        int t = __shfl_up(v, off, 64);
        if (tid >= off) v += t;
    }
    if (tid < SCAN_NB) boff[tid] = v - orig;
}

__global__ void scan3_kernel(int* __restrict__ rowptr, const int* __restrict__ boff,
                             const int* __restrict__ deg, float* __restrict__ dinv) {
    int gid = blockIdx.x * 256 + threadIdx.x;
    if (gid < NN) {
        rowptr[gid] += boff[gid >> 10];
        dinv[gid] = rsqrtf((float)(deg[gid] + 1));
    }
    if (gid == 0) rowptr[NN] = NE;
}

// ================= MEGA2: [scatter | gemm1 BK=32]  -> tbuf bf16 only =======================
__global__ __launch_bounds__(256) void mega2_kernel(
    const int* __restrict__ er, const int* __restrict__ ec, const int* __restrict__ rowptr,
    const unsigned char* __restrict__ rank, const unsigned char* __restrict__ base8,
    int* __restrict__ colss,
    const unsigned short* __restrict__ xb, const unsigned short* __restrict__ w1t,
    const float* __restrict__ b1, unsigned short* __restrict__ tbuf) {
    __shared__ __align__(16) unsigned short As[128 * 32];
    __shared__ __align__(16) unsigned short Bs[128 * 32];
    int bid = blockIdx.x;
    if (bid < CB) {   // scatter (atomic-free), one histogram slice per block
        int tid = threadIdx.x;
        const unsigned char* bb = base8 + (size_t)bid * 50000;
        int e0 = bid * EPB;
        int e = e0 + tid;
        #pragma unroll 4
        for (int it = 0; it < EPB / 256; ++it, e += 256) {
            int r = er[e], c = ec[e];
            colss[rowptr[r] + (int)bb[r] + (int)rank[e]] = c;
        }
        if (e < e0 + EPB) {   // tail: EPB % 256 = 106 edges
            int r = er[e], c = ec[e];
            colss[rowptr[r] + (int)bb[r] + (int)rank[e]] = c;
        }
        return;
    }
    bid -= CB;
    // ---- gemm1: t = relu(x@W1+b1) -> tbuf bf16 ----
    const int m0 = (bid >> 2) * 128, n0 = (bid & 3) * 128;
    const int tid = threadIdx.x;
    const int wave = tid >> 6, lane = tid & 63;
    const int q = lane >> 4, c = lane & 15;
    const int wm = wave & 1, wn = wave >> 1;

    float4v acc[4][4];
    for (int i = 0; i < 4; ++i)
        for (int j = 0; j < 4; ++j)
            acc[i][j] = (float4v){0.f, 0.f, 0.f, 0.f};

    for (int k0 = 0; k0 < FI; k0 += 32) {
        __syncthreads();
        #pragma unroll
        for (int h = 0; h < 2; ++h) {
            int chunk = h * 256 + wave * 64 + lane;
            int r = chunk >> 2, kc = chunk & 3;
            int gm = m0 + r; gm = gm < NN ? gm : NN - 1;
            async_copy16((char*)As + (size_t)(h * 256 + wave * 64) * 16,
                         xb + (size_t)gm * FI + k0 + kc * 8);
            async_copy16((char*)Bs + (size_t)(h * 256 + wave * 64) * 16,
                         w1t + (size_t)(n0 + r) * FI + k0 + kc * 8);
        }
        __syncthreads();
        short8 a[4], b[4];
        #pragma unroll
        for (int mi = 0; mi < 4; ++mi)
            a[mi] = *(const short8*)(As + ((wm * 64 + mi * 16 + c) * 32 + q * 8));
        #pragma unroll
        for (int ni = 0; ni < 4; ++ni)
            b[ni] = *(const short8*)(Bs + ((wn * 64 + ni * 16 + c) * 32 + q * 8));
        #pragma unroll
        for (int mi = 0; mi < 4; ++mi)
            #pragma unroll
            for (int ni = 0; ni < 4; ++ni)
                acc[mi][ni] = __builtin_amdgcn_mfma_f32_16x16x32_bf16(a[mi], b[ni], acc[mi][ni], 0, 0, 0);
    }
    #pragma unroll
    for (int ni = 0; ni < 4; ++ni) {
        int col = n0 + wn * 64 + ni * 16 + c;
        float bias = b1[col];
        #pragma unroll
        for (int mi = 0; mi < 4; ++mi) {
            int rbase = m0 + wm * 64 + mi * 16 + q * 4;
            #pragma unroll
            for (int r = 0; r < 4; ++r) {
                int row = rbase + r;
                if (row < NN) {
                    float v = acc[mi][ni][r] + bias;
                    v = v > 0.f ? v : 0.f;
                    tbuf[(size_t)row * FI + col] = f2b(v);
                }
            }
        }
    }
}

// ================= PROJ: [d0 | z1 | z2] = t @ wcpt^T  (N x 512 x 120 MFMA GEMM) ============
// d0f[i][j]   = t[i]@g0   (f32, direct logit term)
// zs12p[i][.] = bf16(dinv[i] * [z1(40) pad(24) z2(40) pad(24)])   (128 cols, pads ZERO)
__global__ __launch_bounds__(256) void proj_kernel(
    const unsigned short* __restrict__ tb, const unsigned short* __restrict__ wcpt,
    const float* __restrict__ dinv, float* __restrict__ d0f,
    unsigned short* __restrict__ zs12p) {
    int wave = threadIdx.x >> 6, lane = threadIdx.x & 63;
    int q = lane >> 4, c = lane & 15;
    int row0 = blockIdx.x * 64 + wave * 16;
    int ra = row0 + c; ra = ra < NN ? ra : NN - 1;
    const unsigned short* ap = tb + (size_t)ra * FI + q * 8;

    float4v A[8];
    #pragma unroll
    for (int g = 0; g < 8; ++g) A[g] = (float4v){0.f, 0.f, 0.f, 0.f};
    #pragma unroll 2
    for (int k0 = 0; k0 < 512; k0 += 32) {
        short8 a = *(const short8*)(ap + k0);
        #pragma unroll
        for (int g = 0; g < 8; ++g) {
            short8 b = *(const short8*)(wcpt + (size_t)(g * 16 + c) * 512 + q * 8 + k0);
            A[g] = __builtin_amdgcn_mfma_f32_16x16x32_bf16(a, b, A[g], 0, 0, 0);
        }
    }
    #pragma unroll
    for (int r = 0; r < 4; ++r) {
        int rowg = row0 + q * 4 + r;
        if (rowg < NN) {
            float dv = dinv[rowg];
            #pragma unroll
            for (int g = 0; g < 8; ++g) {
                int j = g * 16 + c;
                float pv = A[g][r];
                if (j < 40)      d0f[(size_t)rowg * 40 + j] = pv;
                else if (j < 80) zs12p[(size_t)rowg * 128 + (j - 40)] = f2b(dv * pv);
                else             zs12p[(size_t)rowg * 128 + (j - 16)] = f2b(dv * pv); // j>=120 -> wcpt rows zero -> writes 0
            }
        }
    }
    // zero the remaining pad cols: 40-63 and 112-127 (40 cols) for this wave's 16 rows
    for (int idx = lane; idx < 16 * 40; idx += 64) {
        int rr = row0 + idx / 40, pc = idx % 40;
        if (rr < NN) zs12p[(size_t)rr * 128 + (pc < 24 ? 40 + pc : 88 + pc)] = 0;
    }
}

// ================= SpMM A (128-col bf16 gather; emits u1 f32 + wp bf16) ====================
// u1[i] = di*(zs1[i] + sum zs1[c]);  wp[i] = di^2*(zs2[i] + sum zs2[c]) = dinv*w (prescaled)
__global__ __launch_bounds__(256) void spmma_kernel(
    const unsigned* __restrict__ zs,     // [N][64] dwords = 128 bf16 cols
    const int* __restrict__ rowptr, const int* __restrict__ cols,
    const float* __restrict__ dinv,
    float* __restrict__ u1b,             // [N][40] f32
    unsigned* __restrict__ wpb) {        // [N][32] dwords = 64 bf16 (40 used, pads=0)
    int i = blockIdx.x * 4 + (threadIdx.x >> 6);
    if (i >= NN) return;
    int lane = threadIdx.x & 63;
    const float di = dinv[i];
    const unsigned* base = zs + lane;

    f32x2 A, B = {0.f, 0.f};
    {   unsigned u = zs[(size_t)i * 64 + lane];   // self-seed (prescaled)
        A.x = blo(u); A.y = bhi(u);
    }
    int k = rowptr[i], e = rowptr[i + 1];
    for (; k + 4 <= e; k += 4) {
        int c0 = cols[k], c1 = cols[k + 1], c2 = cols[k + 2], c3 = cols[k + 3];
        unsigned g0 = base[(size_t)c0 * 64];
        unsigned g1 = base[(size_t)c1 * 64];
        unsigned g2 = base[(size_t)c2 * 64];
        unsigned g3 = base[(size_t)c3 * 64];
        A.x += blo(g0); A.y += bhi(g0);
        B.x += blo(g1); B.y += bhi(g1);
        A.x += blo(g2); A.y += bhi(g2);
        B.x += blo(g3); B.y += bhi(g3);
    }
    for (; k < e; ++k) {
        unsigned g = base[(size_t)cols[k] * 64];
        A.x += blo(g); A.y += bhi(g);
    }
    A.x += B.x; A.y += B.y;
    if (lane < 20) {                       // zs1 cols 2l,2l+1
        float2 o; o.x = di * A.x; o.y = di * A.y;
        *(float2*)(u1b + (size_t)i * 40 + lane * 2) = o;
    } else if (lane >= 32) {               // zs2 cols (dword l-32); lanes 52-63 carry 0-pads
        float s = di * di;
        wpb[(size_t)i * 32 + (lane - 32)] = ((unsigned)f2b(s * A.y) << 16) | f2b(s * A.x);
    }
}

// ================= SpMM B + logits + log_softmax ===========================================
// u2[i] = di*(wp[i] + sum wp[c]);  out = log_softmax(d0 + u1 + u2 + b2)
__global__ __launch_bounds__(256) void spmmb_kernel(
    const unsigned* __restrict__ wpb,    // [N][32] dwords
    const int* __restrict__ rowptr, const int* __restrict__ cols,
    const float* __restrict__ dinv, const float* __restrict__ d0f,
    const float* __restrict__ u1b, const float* __restrict__ b2p,
    float* __restrict__ out) {
    int i = blockIdx.x * 4 + (threadIdx.x >> 6);
    if (i >= NN) return;
    int lane = threadIdx.x & 63;
    int half = lane >> 5, dl = lane & 31;
    const float di = dinv[i];

    f32x2 A = {0.f, 0.f};
    if (half == 0) {   // self-seed (prescaled) into half 0 only
        unsigned u = wpb[(size_t)i * 32 + dl];
        A.x = blo(u); A.y = bhi(u);
    }
    int k = rowptr[i], e = rowptr[i + 1];
    for (; k + 2 <= e; k += 2) {           // 2 edges/iter: half0 <- k, half1 <- k+1
        int cc = cols[k + half];
        unsigned g = wpb[(size_t)cc * 32 + dl];
        A.x += blo(g); A.y += bhi(g);
    }
    if (k < e && half == 0) {
        unsigned g = wpb[(size_t)cols[k] * 32 + dl];
        A.x += blo(g); A.y += bhi(g);
    }
    A.x += __shfl_xor(A.x, 32, 64);        // merge halves (both now hold full sum)
    A.y += __shfl_xor(A.y, 32, 64);
    float u2x = di * A.x, u2y = di * A.y;

    float vx = -1e30f, vy = -1e30f;
    if (dl < 20) {
        float2 dd = *(const float2*)(d0f + (size_t)i * 40 + dl * 2);
        float2 uu = *(const float2*)(u1b + (size_t)i * 40 + dl * 2);
        vx = dd.x + uu.x + u2x + b2p[dl * 2];
        vy = dd.y + uu.y + u2y + b2p[dl * 2 + 1];
    }
    float mx = fmaxf(vx, vy);
    #pragma unroll
    for (int d = 1; d < 32; d <<= 1) mx = fmaxf(mx, __shfl_xor(mx, d, 64));
    float s = (dl < 20) ? (__expf(vx - mx) + __expf(vy - mx)) : 0.f;
    #pragma unroll
    for (int d = 1; d < 32; d <<= 1) s += __shfl_xor(s, d, 64);
    float lse = mx + __logf(s);
    if (half == 0 && dl < 20) {
        float2 o; o.x = vx - lse; o.y = vy - lse;
        *(float2*)(out + (size_t)i * 40 + dl * 2) = o;
    }
}

extern "C" void kernel_launch(void* const* d_in, const int* in_sizes, int n_in,
                              void* d_out, int out_size, void* d_ws, size_t ws_size,
                              hipStream_t stream) {
    const float* x  = (const float*)d_in[0];
    const int*   er = (const int*)d_in[1];
    const int*   ec = (const int*)d_in[2];
    const float* W1 = (const float*)d_in[3];
    const float* b1 = (const float*)d_in[4];
    const float* W2 = (const float*)d_in[5];
    const float* b2 = (const float*)d_in[6];
    float* out = (float*)d_out;

    char* p = (char*)d_ws;
    auto alloc = [&](size_t bytes) { char* r = p; p += (bytes + 255) & ~((size_t)255); return r; };
    int*      cntI   = (int*)      alloc((size_t)NN * 4);
    int*      degI   = (int*)      alloc((size_t)NN * 4);
    int*      rowptr = (int*)      alloc((size_t)(NN + 1) * 4);
    float*    dinv   = (float*)    alloc((size_t)NN * 4);
    int*      bsum   = (int*)      alloc((size_t)SCAN_NB * 4);
    int*      boff   = (int*)      alloc((size_t)SCAN_NB * 4);
    unsigned char* rank = (unsigned char*)alloc((size_t)NE);
    int*      colss  = (int*)      alloc((size_t)NE * 4);
    unsigned* hist_row = (unsigned*)alloc((size_t)CB * HWRD * 4);   // 12.8MB, dead after prep
    unsigned* hist_col = (unsigned*)alloc((size_t)CB * HWRD * 4);   // 12.8MB, dead after prep
    unsigned* base_w   = (unsigned*)alloc((size_t)CB * HWRD * 4);   // 12.8MB, dead after mega2
    unsigned short* w1t  = (unsigned short*)alloc((size_t)512 * 512 * 2);
    unsigned short* wcpt = (unsigned short*)alloc((size_t)128 * 512 * 2);
    unsigned short* xb   = (unsigned short*)alloc((size_t)NN * FI * 2);   // 51.2MB
    unsigned short* tbuf = (unsigned short*)alloc((size_t)NN * FI * 2);   // 51.2MB
    unsigned short* zs12p = (unsigned short*)alloc((size_t)NN * 128 * 2); // 12.8MB
    float*    d0f  = (float*)alloc((size_t)NN * 40 * 4);                  // 8MB
    float*    u1b  = (float*)alloc((size_t)NN * 40 * 4);                  // 8MB
    unsigned* wpb  = (unsigned*)alloc((size_t)NN * 32 * 4);               // 6.4MB

    // L1: independent prep work, count parts first
    mega1_kernel<<<2 * CB + 12500 + 1024 + 256, 256, 0, stream>>>(
        er, ec, x, W1, W2, rank, hist_row, hist_col, xb, w1t, wcpt);
    // L2: cross-block prefix (rows) + reduce (cols)
    prep_kernel<<<(2 * HWRD + 255) / 256, 256, 0, stream>>>(hist_row, hist_col, base_w, cntI, degI);
    // L3-5: rowptr scan + dinv
    scan1_kernel<<<SCAN_NB, 1024, 0, stream>>>(cntI, rowptr, bsum);
    scan2_kernel<<<1, 64, 0, stream>>>(bsum, boff);
    scan3_kernel<<<(NN + 255) / 256, 256, 0, stream>>>(rowptr, boff, degI, dinv);
    // L6: scatter | gemm1 -> tbuf bf16
    mega2_kernel<<<CB + ((NN + 127) / 128) * 4, 256, 0, stream>>>(
        er, ec, rowptr, rank, (const unsigned char*)base_w, colss, xb, w1t, b1, tbuf);
    // L7: projection GEMM -> d0 + prescaled [z1|z2]
    proj_kernel<<<(NN + 63) / 64, 256, 0, stream>>>(tbuf, wcpt, dinv, d0f, zs12p);
    // L8: SpMM over 128-col z -> u1 + prescaled w
    spmma_kernel<<<(NN + 3) / 4, 256, 0, stream>>>((const unsigned*)zs12p, rowptr, colss, dinv, u1b, wpb);
    // L9: SpMM over 64-col w + fused logits/log_softmax
    spmmb_kernel<<<(NN + 3) / 4, 256, 0, stream>>>(wpb, rowptr, colss, dinv, d0f, u1b, b2, out);
}

// Round 11
// 476.473 us; speedup vs baseline: 1.6498x; 1.0999x over previous
//
#include <hip/hip_runtime.h>
#include <stdint.h>

#define NN 50000
#define NE 1600000
#define FI 512
#define DD 512
#define NC 40
#define SCAN_NB 49        // ceil(NN/1024)
#define CB 256            // histogram blocks
#define EPB (NE / CB)     // 6250 edges per histogram block
#define HWRD 12500        // 50000 bins / 4 bytes per word

typedef __attribute__((ext_vector_type(8))) short short8;
typedef __attribute__((ext_vector_type(4))) float float4v;
typedef __attribute__((ext_vector_type(2))) float f32x2;

static __device__ __forceinline__ unsigned short f2b(float f) {
    union { float f; unsigned int i; } v; v.f = f;
    unsigned int r = v.i + 0x7fffu + ((v.i >> 16) & 1u);
    return (unsigned short)(r >> 16);
}
static __device__ __forceinline__ float blo(unsigned int u) {
    union { unsigned int i; float f; } v; v.i = u << 16; return v.f;
}
static __device__ __forceinline__ float bhi(unsigned int u) {
    union { unsigned int i; float f; } v; v.i = u & 0xffff0000u; return v.f;
}
static __device__ __forceinline__ void async_copy16(void* lds, const void* g) {
    __builtin_amdgcn_global_load_lds((const __attribute__((address_space(1))) void*)g,
                                     (__attribute__((address_space(3))) void*)lds, 16, 0, 0);
}

// ================= MEGA1: [count_row | count_col | convx | transpose | wcpt] =================
__global__ __launch_bounds__(256) void mega1_kernel(
    const int* __restrict__ er, const int* __restrict__ ec,
    const float* __restrict__ x, const float* __restrict__ W1, const float* __restrict__ W2,
    unsigned char* __restrict__ rank, unsigned* __restrict__ hist_row, unsigned* __restrict__ hist_col,
    unsigned short* __restrict__ xb, unsigned short* __restrict__ w1t, unsigned short* __restrict__ wcpt) {
    __shared__ unsigned hb[HWRD];
    int bid = blockIdx.x, tid = threadIdx.x;
    if (bid < 2 * CB) {
        for (int w = tid; w < HWRD; w += 256) hb[w] = 0;
        __syncthreads();
        int b = bid & (CB - 1);
        int e0 = b * EPB;
        if (bid < CB) {   // row histogram + rank
            for (int e = e0 + tid; e < e0 + EPB; e += 256) {
                int r = er[e];
                unsigned sh = (r & 3) * 8;
                unsigned old = atomicAdd(&hb[r >> 2], 1u << sh);
                rank[e] = (unsigned char)((old >> sh) & 0xFFu);
            }
        } else {          // col histogram (in-degree)
            for (int e = e0 + tid; e < e0 + EPB; e += 256) {
                int c = ec[e];
                atomicAdd(&hb[c >> 2], 1u << ((c & 3) * 8));
            }
        }
        __syncthreads();
        unsigned* dst = (bid < CB ? hist_row : hist_col) + (size_t)b * HWRD;
        for (int w = tid; w < HWRD; w += 256) dst[w] = hb[w];
        return;
    }
    bid -= 2 * CB;
    if (bid < 12500) {    // convx: fp32 -> bf16, 8 elems/thread
        int t = bid * 256 + tid;
        const float* xf = x + (size_t)t * 8;
        float4 v0 = *(const float4*)(xf);
        float4 v1 = *(const float4*)(xf + 4);
        uint4 u;
        u.x = ((unsigned)f2b(v0.y) << 16) | f2b(v0.x);
        u.y = ((unsigned)f2b(v0.w) << 16) | f2b(v0.z);
        u.z = ((unsigned)f2b(v1.y) << 16) | f2b(v1.x);
        u.w = ((unsigned)f2b(v1.w) << 16) | f2b(v1.z);
        *(uint4*)(xb + (size_t)t * 8) = u;
        return;
    }
    bid -= 12500;
    if (bid < 1024) {     // transpose W1 -> bf16 w1t[n][k]
        int t = bid * 256 + tid;
        int n = t & 511, k = t >> 9;
        w1t[n * 512 + k] = f2b(W1[(size_t)k * 512 + n]);
        return;
    }
    bid -= 1024;
    {                     // wcpt builder: 128*512 elems, 256 blocks
        int t = bid * 256 + tid;   // < 65536 always
        int n = t >> 9, k = t & 511;
        float v = 0.f;
        if (n < 40)       v = W2[(size_t)k * NC + n] + W2[(size_t)(k + 512) * NC + n];
        else if (n < 80)  v = W2[(size_t)(k + 1024) * NC + (n - 40)] + W2[(size_t)(k + 1536) * NC + (n - 40)];
        else if (n < 120) v = W2[(size_t)(k + 2048) * NC + (n - 80)];
        wcpt[n * 512 + k] = f2b(v);
    }
}

// ================= PREP: SWAR prefix over blocks (rows) + reduce (cols) =================
__global__ __launch_bounds__(256) void prep_kernel(
    const unsigned* __restrict__ hist_row, const unsigned* __restrict__ hist_col,
    unsigned* __restrict__ base_words, int* __restrict__ cntI, int* __restrict__ degI) {
    int t = blockIdx.x * 256 + threadIdx.x;
    if (t < HWRD) {
        unsigned acc = 0;   // 4 packed byte counters; totals <256/byte so no carry
        for (int b = 0; b < CB; ++b) {
            unsigned h = hist_row[(size_t)b * HWRD + t];
            base_words[(size_t)b * HWRD + t] = acc;
            acc += h;
        }
        int4 o; o.x = acc & 0xFF; o.y = (acc >> 8) & 0xFF; o.z = (acc >> 16) & 0xFF; o.w = (acc >> 24) & 0xFF;
        ((int4*)cntI)[t] = o;
    } else if (t < 2 * HWRD) {
        int w = t - HWRD;
        unsigned acc = 0;
        for (int b = 0; b < CB; ++b) acc += hist_col[(size_t)b * HWRD + w];
        int4 o; o.x = acc & 0xFF; o.y = (acc >> 8) & 0xFF; o.z = (acc >> 16) & 0xFF; o.w = (acc >> 24) & 0xFF;
        ((int4*)degI)[w] = o;
    }
}

// ================= scans =================
__global__ __launch_bounds__(1024) void scan1_kernel(const int* __restrict__ cnt,
                                                     int* __restrict__ excl, int* __restrict__ bsum) {
    __shared__ int buf[1024];
    int tid = threadIdx.x, gid = blockIdx.x * 1024 + tid;
    int v = (gid < NN) ? cnt[gid] : 0;
    buf[tid] = v;
    __syncthreads();
    int acc = v;
    for (int off = 1; off < 1024; off <<= 1) {
        int t = (tid >= off) ? buf[tid - off] : 0;
        __syncthreads();
        acc += t;
        buf[tid] = acc;
        __syncthreads();
    }
    if (gid < NN) excl[gid] = acc - v;
    if (tid == 1023) bsum[blockIdx.x] = acc;
}

__global__ void scan2_kernel(const int* __restrict__ bsum, int* __restrict__ boff) {
    int tid = threadIdx.x;  // one wave, SCAN_NB=49
    int orig = (tid < SCAN_NB) ? bsum[tid] : 0;
    int v = orig;
    #pragma unroll
    for (int off = 1; off < 64; off <<= 1) {
        int t = __shfl_up(v, off, 64);
        if (tid >= off) v += t;
    }
    if (tid < SCAN_NB) boff[tid] = v - orig;
}

__global__ void scan3_kernel(int* __restrict__ rowptr, const int* __restrict__ boff,
                             const int* __restrict__ deg, float* __restrict__ dinv) {
    int gid = blockIdx.x * 256 + threadIdx.x;
    if (gid < NN) {
        rowptr[gid] += boff[gid >> 10];
        dinv[gid] = rsqrtf((float)(deg[gid] + 1));
    }
    if (gid == 0) rowptr[NN] = NE;
}

// ================= MEGA2: [scatter | gemm1 BK=32]  -> tbuf bf16 only =======================
__global__ __launch_bounds__(256) void mega2_kernel(
    const int* __restrict__ er, const int* __restrict__ ec, const int* __restrict__ rowptr,
    const unsigned char* __restrict__ rank, const unsigned char* __restrict__ base8,
    int* __restrict__ colss,
    const unsigned short* __restrict__ xb, const unsigned short* __restrict__ w1t,
    const float* __restrict__ b1, unsigned short* __restrict__ tbuf) {
    __shared__ __align__(16) unsigned short As[128 * 32];
    __shared__ __align__(16) unsigned short Bs[128 * 32];
    int bid = blockIdx.x;
    if (bid < CB) {   // scatter (atomic-free), one histogram slice per block
        int tid = threadIdx.x;
        const unsigned char* bb = base8 + (size_t)bid * 50000;
        int e0 = bid * EPB;
        int e = e0 + tid;
        #pragma unroll 4
        for (int it = 0; it < EPB / 256; ++it, e += 256) {
            int r = er[e], c = ec[e];
            colss[rowptr[r] + (int)bb[r] + (int)rank[e]] = c;
        }
        if (e < e0 + EPB) {   // tail: EPB % 256 = 106 edges
            int r = er[e], c = ec[e];
            colss[rowptr[r] + (int)bb[r] + (int)rank[e]] = c;
        }
        return;
    }
    bid -= CB;
    // ---- gemm1: t = relu(x@W1+b1) -> tbuf bf16 ----
    const int m0 = (bid >> 2) * 128, n0 = (bid & 3) * 128;
    const int tid = threadIdx.x;
    const int wave = tid >> 6, lane = tid & 63;
    const int q = lane >> 4, c = lane & 15;
    const int wm = wave & 1, wn = wave >> 1;

    float4v acc[4][4];
    for (int i = 0; i < 4; ++i)
        for (int j = 0; j < 4; ++j)
            acc[i][j] = (float4v){0.f, 0.f, 0.f, 0.f};

    for (int k0 = 0; k0 < FI; k0 += 32) {
        __syncthreads();
        #pragma unroll
        for (int h = 0; h < 2; ++h) {
            int chunk = h * 256 + wave * 64 + lane;
            int r = chunk >> 2, kc = chunk & 3;
            int gm = m0 + r; gm = gm < NN ? gm : NN - 1;
            async_copy16((char*)As + (size_t)(h * 256 + wave * 64) * 16,
                         xb + (size_t)gm * FI + k0 + kc * 8);
            async_copy16((char*)Bs + (size_t)(h * 256 + wave * 64) * 16,
                         w1t + (size_t)(n0 + r) * FI + k0 + kc * 8);
        }
        __syncthreads();
        short8 a[4], b[4];
        #pragma unroll
        for (int mi = 0; mi < 4; ++mi)
            a[mi] = *(const short8*)(As + ((wm * 64 + mi * 16 + c) * 32 + q * 8));
        #pragma unroll
        for (int ni = 0; ni < 4; ++ni)
            b[ni] = *(const short8*)(Bs + ((wn * 64 + ni * 16 + c) * 32 + q * 8));
        #pragma unroll
        for (int mi = 0; mi < 4; ++mi)
            #pragma unroll
            for (int ni = 0; ni < 4; ++ni)
                acc[mi][ni] = __builtin_amdgcn_mfma_f32_16x16x32_bf16(a[mi], b[ni], acc[mi][ni], 0, 0, 0);
    }
    #pragma unroll
    for (int ni = 0; ni < 4; ++ni) {
        int col = n0 + wn * 64 + ni * 16 + c;
        float bias = b1[col];
        #pragma unroll
        for (int mi = 0; mi < 4; ++mi) {
            int rbase = m0 + wm * 64 + mi * 16 + q * 4;
            #pragma unroll
            for (int r = 0; r < 4; ++r) {
                int row = rbase + r;
                if (row < NN) {
                    float v = acc[mi][ni][r] + bias;
                    v = v > 0.f ? v : 0.f;
                    tbuf[(size_t)row * FI + col] = f2b(v);
                }
            }
        }
    }
}

// ================= PROJ: [d0 | z1 | z2] = t @ wcpt^T  (N x 512 x 120 MFMA GEMM) ============
__global__ __launch_bounds__(256) void proj_kernel(
    const unsigned short* __restrict__ tb, const unsigned short* __restrict__ wcpt,
    const float* __restrict__ dinv, float* __restrict__ d0f,
    unsigned short* __restrict__ zs12p) {
    int wave = threadIdx.x >> 6, lane = threadIdx.x & 63;
    int q = lane >> 4, c = lane & 15;
    int row0 = blockIdx.x * 64 + wave * 16;
    int ra = row0 + c; ra = ra < NN ? ra : NN - 1;
    const unsigned short* ap = tb + (size_t)ra * FI + q * 8;

    float4v A[8];
    #pragma unroll
    for (int g = 0; g < 8; ++g) A[g] = (float4v){0.f, 0.f, 0.f, 0.f};
    #pragma unroll 2
    for (int k0 = 0; k0 < 512; k0 += 32) {
        short8 a = *(const short8*)(ap + k0);
        #pragma unroll
        for (int g = 0; g < 8; ++g) {
            short8 b = *(const short8*)(wcpt + (size_t)(g * 16 + c) * 512 + q * 8 + k0);
            A[g] = __builtin_amdgcn_mfma_f32_16x16x32_bf16(a, b, A[g], 0, 0, 0);
        }
    }
    #pragma unroll
    for (int r = 0; r < 4; ++r) {
        int rowg = row0 + q * 4 + r;
        if (rowg < NN) {
            float dv = dinv[rowg];
            #pragma unroll
            for (int g = 0; g < 8; ++g) {
                int j = g * 16 + c;
                float pv = A[g][r];
                if (j < 40)      d0f[(size_t)rowg * 40 + j] = pv;
                else if (j < 80) zs12p[(size_t)rowg * 128 + (j - 40)] = f2b(dv * pv);
                else             zs12p[(size_t)rowg * 128 + (j - 16)] = f2b(dv * pv); // j>=120 -> wcpt rows zero -> writes 0
            }
        }
    }
    // zero the remaining pad cols: 40-63 and 112-127 (40 cols) for this wave's 16 rows
    for (int idx = lane; idx < 16 * 40; idx += 64) {
        int rr = row0 + idx / 40, pc = idx % 40;
        if (rr < NN) zs12p[(size_t)rr * 128 + (pc < 24 ? 40 + pc : 88 + pc)] = 0;
    }
}

// ================= SpMM A (uint2/lane, 2 edges/wave, 8 in flight) ==========================
// u1[i] = di*(zs1[i] + sum zs1[c]);  wp[i] = di^2*(zs2[i] + sum zs2[c]) (prescaled)
__global__ __launch_bounds__(256) void spmma_kernel(
    const unsigned* __restrict__ zs,     // [N][64] dwords = 128 bf16 cols
    const int* __restrict__ rowptr, const int* __restrict__ cols,
    const float* __restrict__ dinv,
    float* __restrict__ u1b,             // [N][40] f32
    unsigned* __restrict__ wpb) {        // [N][32] dwords = 64 bf16 (40 used, pads=0)
    int i = blockIdx.x * 4 + (threadIdx.x >> 6);
    if (i >= NN) return;
    int lane = threadIdx.x & 63;
    int h = lane >> 5, l = lane & 31;    // h = edge parity, l covers 4 bf16 cols
    const float di = dinv[i];
    const unsigned* base = zs + l * 2;

    float a0 = 0.f, a1 = 0.f, a2 = 0.f, a3 = 0.f;
    float b0 = 0.f, b1 = 0.f, b2 = 0.f, b3 = 0.f;
    if (h == 0) {   // self-seed (prescaled), counted once
        uint2 u = *(const uint2*)(zs + (size_t)i * 64 + l * 2);
        a0 = blo(u.x); a1 = bhi(u.x); a2 = blo(u.y); a3 = bhi(u.y);
    }
    int k = rowptr[i], e = rowptr[i + 1];
    for (; k + 8 <= e; k += 8) {   // 8 edges in flight: 4 gathers/lane, 2 banks
        int c0 = cols[k + h], c1 = cols[k + 2 + h], c2 = cols[k + 4 + h], c3 = cols[k + 6 + h];
        uint2 g0 = *(const uint2*)(base + (size_t)c0 * 64);
        uint2 g1 = *(const uint2*)(base + (size_t)c1 * 64);
        uint2 g2 = *(const uint2*)(base + (size_t)c2 * 64);
        uint2 g3 = *(const uint2*)(base + (size_t)c3 * 64);
        a0 += blo(g0.x); a1 += bhi(g0.x); a2 += blo(g0.y); a3 += bhi(g0.y);
        b0 += blo(g1.x); b1 += bhi(g1.x); b2 += blo(g1.y); b3 += bhi(g1.y);
        a0 += blo(g2.x); a1 += bhi(g2.x); a2 += blo(g2.y); a3 += bhi(g2.y);
        b0 += blo(g3.x); b1 += bhi(g3.x); b2 += blo(g3.y); b3 += bhi(g3.y);
    }
    for (; k + 2 <= e; k += 2) {
        int cc = cols[k + h];
        uint2 g = *(const uint2*)(base + (size_t)cc * 64);
        a0 += blo(g.x); a1 += bhi(g.x); a2 += blo(g.y); a3 += bhi(g.y);
    }
    if (k < e && h == 0) {         // odd tail edge
        int cc = cols[k];
        uint2 g = *(const uint2*)(base + (size_t)cc * 64);
        a0 += blo(g.x); a1 += bhi(g.x); a2 += blo(g.y); a3 += bhi(g.y);
    }
    a0 += b0; a1 += b1; a2 += b2; a3 += b3;
    a0 += __shfl_xor(a0, 32, 64); a1 += __shfl_xor(a1, 32, 64);
    a2 += __shfl_xor(a2, 32, 64); a3 += __shfl_xor(a3, 32, 64);
    if (h == 0) {
        if (l < 10) {                        // z1 cols 4l..4l+3 -> u1 f32
            float4 o; o.x = di * a0; o.y = di * a1; o.z = di * a2; o.w = di * a3;
            *(float4*)(u1b + (size_t)i * 40 + l * 4) = o;
        } else if (l >= 16) {                // z2 cols (incl. zero pads) -> wp bf16
            float s = di * di;
            uint2 o;
            o.x = ((unsigned)f2b(s * a1) << 16) | f2b(s * a0);
            o.y = ((unsigned)f2b(s * a3) << 16) | f2b(s * a2);
            *(uint2*)(wpb + (size_t)i * 32 + (size_t)(l - 16) * 2) = o;
        }
    }
}

// ================= SpMM B (uint2/lane, 4 edges/wave) + logits + log_softmax ================
// u2[i] = di*(wp[i] + sum wp[c]);  out = log_softmax(d0 + u1 + u2 + b2)
__global__ __launch_bounds__(256) void spmmb_kernel(
    const unsigned* __restrict__ wpb,    // [N][32] dwords
    const int* __restrict__ rowptr, const int* __restrict__ cols,
    const float* __restrict__ dinv, const float* __restrict__ d0f,
    const float* __restrict__ u1b, const float* __restrict__ b2p,
    float* __restrict__ out) {
    int i = blockIdx.x * 4 + (threadIdx.x >> 6);
    if (i >= NN) return;
    int lane = threadIdx.x & 63;
    int q = lane >> 4, l = lane & 15;    // q = edge slot, l covers 4 bf16 cols
    const float di = dinv[i];
    const unsigned* base = wpb + l * 2;

    float a0 = 0.f, a1 = 0.f, a2 = 0.f, a3 = 0.f;
    float b0 = 0.f, b1 = 0.f, b2 = 0.f, b3 = 0.f;
    if (q == 0) {   // self-seed (prescaled), counted once
        uint2 u = *(const uint2*)(wpb + (size_t)i * 32 + l * 2);
        a0 = blo(u.x); a1 = bhi(u.x); a2 = blo(u.y); a3 = bhi(u.y);
    }
    int k = rowptr[i], e = rowptr[i + 1];
    for (; k + 8 <= e; k += 8) {   // 8 edges in flight: 2 gathers/lane, 2 banks
        int c0 = cols[k + q], c1 = cols[k + 4 + q];
        uint2 g0 = *(const uint2*)(base + (size_t)c0 * 32);
        uint2 g1 = *(const uint2*)(base + (size_t)c1 * 32);
        a0 += blo(g0.x); a1 += bhi(g0.x); a2 += blo(g0.y); a3 += bhi(g0.y);
        b0 += blo(g1.x); b1 += bhi(g1.x); b2 += blo(g1.y); b3 += bhi(g1.y);
    }
    for (; k + 4 <= e; k += 4) {
        int cc = cols[k + q];
        uint2 g = *(const uint2*)(base + (size_t)cc * 32);
        a0 += blo(g.x); a1 += bhi(g.x); a2 += blo(g.y); a3 += bhi(g.y);
    }
    if (k + q < e) {               // tail (<4 edges), slot q takes edge k+q
        int cc = cols[k + q];
        uint2 g = *(const uint2*)(base + (size_t)cc * 32);
        a0 += blo(g.x); a1 += bhi(g.x); a2 += blo(g.y); a3 += bhi(g.y);
    }
    a0 += b0; a1 += b1; a2 += b2; a3 += b3;
    a0 += __shfl_xor(a0, 16, 64); a1 += __shfl_xor(a1, 16, 64);
    a2 += __shfl_xor(a2, 16, 64); a3 += __shfl_xor(a3, 16, 64);
    a0 += __shfl_xor(a0, 32, 64); a1 += __shfl_xor(a1, 32, 64);
    a2 += __shfl_xor(a2, 32, 64); a3 += __shfl_xor(a3, 32, 64);

    float v0 = -1e30f, v1 = -1e30f, v2 = -1e30f, v3 = -1e30f;
    bool act = (q == 0) && (l < 10);
    if (act) {
        float4 dd = *(const float4*)(d0f + (size_t)i * 40 + l * 4);
        float4 uu = *(const float4*)(u1b + (size_t)i * 40 + l * 4);
        float4 bb = *(const float4*)(b2p + l * 4);
        v0 = dd.x + uu.x + di * a0 + bb.x;
        v1 = dd.y + uu.y + di * a1 + bb.y;
        v2 = dd.z + uu.z + di * a2 + bb.z;
        v3 = dd.w + uu.w + di * a3 + bb.w;
    }
    float mx = fmaxf(fmaxf(v0, v1), fmaxf(v2, v3));
    #pragma unroll
    for (int d = 1; d < 64; d <<= 1) mx = fmaxf(mx, __shfl_xor(mx, d, 64));
    float s = act ? (__expf(v0 - mx) + __expf(v1 - mx) + __expf(v2 - mx) + __expf(v3 - mx)) : 0.f;
    #pragma unroll
    for (int d = 1; d < 64; d <<= 1) s += __shfl_xor(s, d, 64);
    float lse = mx + __logf(s);
    if (act) {
        float4 o; o.x = v0 - lse; o.y = v1 - lse; o.z = v2 - lse; o.w = v3 - lse;
        *(float4*)(out + (size_t)i * 40 + l * 4) = o;
    }
}

extern "C" void kernel_launch(void* const* d_in, const int* in_sizes, int n_in,
                              void* d_out, int out_size, void* d_ws, size_t ws_size,
                              hipStream_t stream) {
    const float* x  = (const float*)d_in[0];
    const int*   er = (const int*)d_in[1];
    const int*   ec = (const int*)d_in[2];
    const float* W1 = (const float*)d_in[3];
    const float* b1 = (const float*)d_in[4];
    const float* W2 = (const float*)d_in[5];
    const float* b2 = (const float*)d_in[6];
    float* out = (float*)d_out;

    char* p = (char*)d_ws;
    auto alloc = [&](size_t bytes) { char* r = p; p += (bytes + 255) & ~((size_t)255); return r; };
    int*      cntI   = (int*)      alloc((size_t)NN * 4);
    int*      degI   = (int*)      alloc((size_t)NN * 4);
    int*      rowptr = (int*)      alloc((size_t)(NN + 1) * 4);
    float*    dinv   = (float*)    alloc((size_t)NN * 4);
    int*      bsum   = (int*)      alloc((size_t)SCAN_NB * 4);
    int*      boff   = (int*)      alloc((size_t)SCAN_NB * 4);
    unsigned char* rank = (unsigned char*)alloc((size_t)NE);
    int*      colss  = (int*)      alloc((size_t)NE * 4);
    unsigned* hist_row = (unsigned*)alloc((size_t)CB * HWRD * 4);   // 12.8MB, dead after prep
    unsigned* hist_col = (unsigned*)alloc((size_t)CB * HWRD * 4);   // 12.8MB, dead after prep
    unsigned* base_w   = (unsigned*)alloc((size_t)CB * HWRD * 4);   // 12.8MB, dead after mega2
    unsigned short* w1t  = (unsigned short*)alloc((size_t)512 * 512 * 2);
    unsigned short* wcpt = (unsigned short*)alloc((size_t)128 * 512 * 2);
    unsigned short* xb   = (unsigned short*)alloc((size_t)NN * FI * 2);   // 51.2MB
    unsigned short* tbuf = (unsigned short*)alloc((size_t)NN * FI * 2);   // 51.2MB
    unsigned short* zs12p = (unsigned short*)alloc((size_t)NN * 128 * 2); // 12.8MB
    float*    d0f  = (float*)alloc((size_t)NN * 40 * 4);                  // 8MB
    float*    u1b  = (float*)alloc((size_t)NN * 40 * 4);                  // 8MB
    unsigned* wpb  = (unsigned*)alloc((size_t)NN * 32 * 4);               // 6.4MB

    // L1: independent prep work, count parts first
    mega1_kernel<<<2 * CB + 12500 + 1024 + 256, 256, 0, stream>>>(
        er, ec, x, W1, W2, rank, hist_row, hist_col, xb, w1t, wcpt);
    // L2: cross-block prefix (rows) + reduce (cols)
    prep_kernel<<<(2 * HWRD + 255) / 256, 256, 0, stream>>>(hist_row, hist_col, base_w, cntI, degI);
    // L3-5: rowptr scan + dinv
    scan1_kernel<<<SCAN_NB, 1024, 0, stream>>>(cntI, rowptr, bsum);
    scan2_kernel<<<1, 64, 0, stream>>>(bsum, boff);
    scan3_kernel<<<(NN + 255) / 256, 256, 0, stream>>>(rowptr, boff, degI, dinv);
    // L6: scatter | gemm1 -> tbuf bf16
    mega2_kernel<<<CB + ((NN + 127) / 128) * 4, 256, 0, stream>>>(
        er, ec, rowptr, rank, (const unsigned char*)base_w, colss, xb, w1t, b1, tbuf);
    // L7: projection GEMM -> d0 + prescaled [z1|z2]
    proj_kernel<<<(NN + 63) / 64, 256, 0, stream>>>(tbuf, wcpt, dinv, d0f, zs12p);
    // L8: SpMM over 128-col z -> u1 + prescaled w
    spmma_kernel<<<(NN + 3) / 4, 256, 0, stream>>>((const unsigned*)zs12p, rowptr, colss, dinv, u1b, wpb);
    // L9: SpMM over 64-col w + fused logits/log_softmax
    spmmb_kernel<<<(NN + 3) / 4, 256, 0, stream>>>(wpb, rowptr, colss, dinv, d0f, u1b, b2, out);
}

// Round 12
// 455.944 us; speedup vs baseline: 1.7240x; 1.0450x over previous
//
#include <hip/hip_runtime.h>
#include <stdint.h>

#define NN 50000
#define NE 1600000
#define FI 512
#define DD 512
#define NC 40
#define SCAN_NB 49        // ceil(NN/1024)
#define CB 256            // histogram blocks
#define EPB (NE / CB)     // 6250 edges per histogram block
#define HWRD 12500        // 50000 bins / 4 bytes per word
#define MT 391            // m-tiles (128 rows)
#define GEMMB 3136        // 8 xcd * 392 slots (m/8-major, n minor)

typedef __attribute__((ext_vector_type(8))) short short8;
typedef __attribute__((ext_vector_type(4))) float float4v;
typedef __attribute__((ext_vector_type(2))) float f32x2;

static __device__ __forceinline__ unsigned short f2b(float f) {
    union { float f; unsigned int i; } v; v.f = f;
    unsigned int r = v.i + 0x7fffu + ((v.i >> 16) & 1u);
    return (unsigned short)(r >> 16);
}
static __device__ __forceinline__ float blo(unsigned int u) {
    union { unsigned int i; float f; } v; v.i = u << 16; return v.f;
}
static __device__ __forceinline__ float bhi(unsigned int u) {
    union { unsigned int i; float f; } v; v.i = u & 0xffff0000u; return v.f;
}
static __device__ __forceinline__ void async_copy16(void* lds, const void* g) {
    __builtin_amdgcn_global_load_lds((const __attribute__((address_space(1))) void*)g,
                                     (__attribute__((address_space(3))) void*)lds, 16, 0, 0);
}

// ================= MEGA1: [count_row | count_col | convx | transpose | wcpt] =================
__global__ __launch_bounds__(256) void mega1_kernel(
    const int* __restrict__ er, const int* __restrict__ ec,
    const float* __restrict__ x, const float* __restrict__ W1, const float* __restrict__ W2,
    unsigned char* __restrict__ rank, unsigned* __restrict__ hist_row, unsigned* __restrict__ hist_col,
    unsigned short* __restrict__ xb, unsigned short* __restrict__ w1t, unsigned short* __restrict__ wcpt) {
    __shared__ unsigned hb[HWRD];
    int bid = blockIdx.x, tid = threadIdx.x;
    if (bid < 2 * CB) {
        for (int w = tid; w < HWRD; w += 256) hb[w] = 0;
        __syncthreads();
        int b = bid & (CB - 1);
        int e0 = b * EPB;
        if (bid < CB) {   // row histogram + rank
            for (int e = e0 + tid; e < e0 + EPB; e += 256) {
                int r = er[e];
                unsigned sh = (r & 3) * 8;
                unsigned old = atomicAdd(&hb[r >> 2], 1u << sh);
                rank[e] = (unsigned char)((old >> sh) & 0xFFu);
            }
        } else {          // col histogram (in-degree)
            for (int e = e0 + tid; e < e0 + EPB; e += 256) {
                int c = ec[e];
                atomicAdd(&hb[c >> 2], 1u << ((c & 3) * 8));
            }
        }
        __syncthreads();
        unsigned* dst = (bid < CB ? hist_row : hist_col) + (size_t)b * HWRD;
        for (int w = tid; w < HWRD; w += 256) dst[w] = hb[w];
        return;
    }
    bid -= 2 * CB;
    if (bid < 12500) {    // convx: fp32 -> bf16, 8 elems/thread
        int t = bid * 256 + tid;
        const float* xf = x + (size_t)t * 8;
        float4 v0 = *(const float4*)(xf);
        float4 v1 = *(const float4*)(xf + 4);
        uint4 u;
        u.x = ((unsigned)f2b(v0.y) << 16) | f2b(v0.x);
        u.y = ((unsigned)f2b(v0.w) << 16) | f2b(v0.z);
        u.z = ((unsigned)f2b(v1.y) << 16) | f2b(v1.x);
        u.w = ((unsigned)f2b(v1.w) << 16) | f2b(v1.z);
        *(uint4*)(xb + (size_t)t * 8) = u;
        return;
    }
    bid -= 12500;
    if (bid < 1024) {     // transpose W1 -> bf16 w1t[n][k]
        int t = bid * 256 + tid;
        int n = t & 511, k = t >> 9;
        w1t[n * 512 + k] = f2b(W1[(size_t)k * 512 + n]);
        return;
    }
    bid -= 1024;
    {                     // wcpt builder: 128*512 elems, 256 blocks
        int t = bid * 256 + tid;   // < 65536 always
        int n = t >> 9, k = t & 511;
        float v = 0.f;
        if (n < 40)       v = W2[(size_t)k * NC + n] + W2[(size_t)(k + 512) * NC + n];
        else if (n < 80)  v = W2[(size_t)(k + 1024) * NC + (n - 40)] + W2[(size_t)(k + 1536) * NC + (n - 40)];
        else if (n < 120) v = W2[(size_t)(k + 2048) * NC + (n - 80)];
        wcpt[n * 512 + k] = f2b(v);
    }
}

// ================= PREP: SWAR prefix over blocks (rows) + reduce (cols) =================
__global__ __launch_bounds__(256) void prep_kernel(
    const unsigned* __restrict__ hist_row, const unsigned* __restrict__ hist_col,
    unsigned* __restrict__ base_words, int* __restrict__ cntI, int* __restrict__ degI) {
    int t = blockIdx.x * 256 + threadIdx.x;
    if (t < HWRD) {
        unsigned acc = 0;   // 4 packed byte counters; totals <256/byte so no carry
        for (int b = 0; b < CB; ++b) {
            unsigned h = hist_row[(size_t)b * HWRD + t];
            base_words[(size_t)b * HWRD + t] = acc;
            acc += h;
        }
        int4 o; o.x = acc & 0xFF; o.y = (acc >> 8) & 0xFF; o.z = (acc >> 16) & 0xFF; o.w = (acc >> 24) & 0xFF;
        ((int4*)cntI)[t] = o;
    } else if (t < 2 * HWRD) {
        int w = t - HWRD;
        unsigned acc = 0;
        for (int b = 0; b < CB; ++b) acc += hist_col[(size_t)b * HWRD + w];
        int4 o; o.x = acc & 0xFF; o.y = (acc >> 8) & 0xFF; o.z = (acc >> 16) & 0xFF; o.w = (acc >> 24) & 0xFF;
        ((int4*)degI)[w] = o;
    }
}

// ================= scans =================
__global__ __launch_bounds__(1024) void scan1_kernel(const int* __restrict__ cnt,
                                                     int* __restrict__ excl, int* __restrict__ bsum) {
    __shared__ int buf[1024];
    int tid = threadIdx.x, gid = blockIdx.x * 1024 + tid;
    int v = (gid < NN) ? cnt[gid] : 0;
    buf[tid] = v;
    __syncthreads();
    int acc = v;
    for (int off = 1; off < 1024; off <<= 1) {
        int t = (tid >= off) ? buf[tid - off] : 0;
        __syncthreads();
        acc += t;
        buf[tid] = acc;
        __syncthreads();
    }
    if (gid < NN) excl[gid] = acc - v;
    if (tid == 1023) bsum[blockIdx.x] = acc;
}

__global__ void scan2_kernel(const int* __restrict__ bsum, int* __restrict__ boff) {
    int tid = threadIdx.x;  // one wave, SCAN_NB=49
    int orig = (tid < SCAN_NB) ? bsum[tid] : 0;
    int v = orig;
    #pragma unroll
    for (int off = 1; off < 64; off <<= 1) {
        int t = __shfl_up(v, off, 64);
        if (tid >= off) v += t;
    }
    if (tid < SCAN_NB) boff[tid] = v - orig;
}

__global__ void scan3_kernel(int* __restrict__ rowptr, const int* __restrict__ boff,
                             const int* __restrict__ deg, float* __restrict__ dinv) {
    int gid = blockIdx.x * 256 + threadIdx.x;
    if (gid < NN) {
        rowptr[gid] += boff[gid >> 10];
        dinv[gid] = rsqrtf((float)(deg[gid] + 1));
    }
    if (gid == 0) rowptr[NN] = NE;
}

// ================= MEGA2: [scatter | gemm1 128x64, XCD-affine] =============================
// gemm1: 128x64 tile, 4 waves (2m x 2n), acc 4x2 (32 AGPR) -> ~100 unified regs ->
// higher occupancy (latency-bound kernel; R2/R7 showed occupancy is the binding axis).
// All 8 n-tiles of an m-tile map to the SAME XCD (gb%8 == m%8, consecutive slots) so the
// A-panel (128KB) is fetched once per XCD and L2-hits the other 7.
__global__ __launch_bounds__(256) void mega2_kernel(
    const int* __restrict__ er, const int* __restrict__ ec, const int* __restrict__ rowptr,
    const unsigned char* __restrict__ rank, const unsigned char* __restrict__ base8,
    int* __restrict__ colss,
    const unsigned short* __restrict__ xb, const unsigned short* __restrict__ w1t,
    const float* __restrict__ b1, unsigned short* __restrict__ tbuf) {
    __shared__ __align__(16) unsigned short As[128 * 32];
    __shared__ __align__(16) unsigned short Bs[64 * 32];
    int bid = blockIdx.x;
    if (bid < CB) {   // scatter (atomic-free), one histogram slice per block
        int tid = threadIdx.x;
        const unsigned char* bb = base8 + (size_t)bid * 50000;
        int e0 = bid * EPB;
        int e = e0 + tid;
        #pragma unroll 4
        for (int it = 0; it < EPB / 256; ++it, e += 256) {
            int r = er[e], c = ec[e];
            colss[rowptr[r] + (int)bb[r] + (int)rank[e]] = c;
        }
        if (e < e0 + EPB) {   // tail: EPB % 256 = 106 edges
            int r = er[e], c = ec[e];
            colss[rowptr[r] + (int)bb[r] + (int)rank[e]] = c;
        }
        return;
    }
    // ---- gemm1: t = relu(x@W1+b1) -> tbuf bf16 ----
    int gb = bid - CB;                      // 0..GEMMB-1
    int xcd = gb & 7, slot = gb >> 3;       // slot in [0,392)
    int m = xcd + 8 * (slot >> 3), n = slot & 7;
    if (m >= MT) return;
    const int m0 = m * 128, n0 = n * 64;
    const int tid = threadIdx.x;
    const int wave = tid >> 6, lane = tid & 63;
    const int q = lane >> 4, c = lane & 15;
    const int wm = wave & 1, wn = wave >> 1;   // 2m x 2n wave grid

    float4v acc[4][2];
    #pragma unroll
    for (int i = 0; i < 4; ++i)
        #pragma unroll
        for (int j = 0; j < 2; ++j)
            acc[i][j] = (float4v){0.f, 0.f, 0.f, 0.f};

    for (int k0 = 0; k0 < FI; k0 += 32) {
        __syncthreads();
        #pragma unroll
        for (int h = 0; h < 2; ++h) {       // A: 512 chunks of 16B
            int chunk = h * 256 + wave * 64 + lane;
            int r = chunk >> 2, kc = chunk & 3;
            int gm = m0 + r; gm = gm < NN ? gm : NN - 1;
            async_copy16((char*)As + (size_t)chunk * 16,
                         xb + (size_t)gm * FI + k0 + kc * 8);
        }
        {                                    // B: 256 chunks of 16B
            int chunk = wave * 64 + lane;
            int rb = chunk >> 2, kb = chunk & 3;
            async_copy16((char*)Bs + (size_t)chunk * 16,
                         w1t + (size_t)(n0 + rb) * FI + k0 + kb * 8);
        }
        __syncthreads();
        short8 a[4], b[2];
        #pragma unroll
        for (int mi = 0; mi < 4; ++mi)
            a[mi] = *(const short8*)(As + ((wm * 64 + mi * 16 + c) * 32 + q * 8));
        #pragma unroll
        for (int ni = 0; ni < 2; ++ni)
            b[ni] = *(const short8*)(Bs + ((wn * 32 + ni * 16 + c) * 32 + q * 8));
        #pragma unroll
        for (int mi = 0; mi < 4; ++mi)
            #pragma unroll
            for (int ni = 0; ni < 2; ++ni)
                acc[mi][ni] = __builtin_amdgcn_mfma_f32_16x16x32_bf16(a[mi], b[ni], acc[mi][ni], 0, 0, 0);
    }
    #pragma unroll
    for (int ni = 0; ni < 2; ++ni) {
        int col = n0 + wn * 32 + ni * 16 + c;
        float bias = b1[col];
        #pragma unroll
        for (int mi = 0; mi < 4; ++mi) {
            int rbase = m0 + wm * 64 + mi * 16 + q * 4;
            #pragma unroll
            for (int r = 0; r < 4; ++r) {
                int row = rbase + r;
                if (row < NN) {
                    float v = acc[mi][ni][r] + bias;
                    v = v > 0.f ? v : 0.f;
                    tbuf[(size_t)row * FI + col] = f2b(v);
                }
            }
        }
    }
}

// ================= PROJ: [d0 | z1 | z2] = t @ wcpt^T  -> packed zsp (80 cols, no pads) =====
__global__ __launch_bounds__(256) void proj_kernel(
    const unsigned short* __restrict__ tb, const unsigned short* __restrict__ wcpt,
    const float* __restrict__ dinv, float* __restrict__ d0f,
    unsigned short* __restrict__ zsp) {
    int wave = threadIdx.x >> 6, lane = threadIdx.x & 63;
    int q = lane >> 4, c = lane & 15;
    int row0 = blockIdx.x * 64 + wave * 16;
    int ra = row0 + c; ra = ra < NN ? ra : NN - 1;
    const unsigned short* ap = tb + (size_t)ra * FI + q * 8;

    float4v A[8];
    #pragma unroll
    for (int g = 0; g < 8; ++g) A[g] = (float4v){0.f, 0.f, 0.f, 0.f};
    #pragma unroll 2
    for (int k0 = 0; k0 < 512; k0 += 32) {
        short8 a = *(const short8*)(ap + k0);
        #pragma unroll
        for (int g = 0; g < 8; ++g) {
            short8 b = *(const short8*)(wcpt + (size_t)(g * 16 + c) * 512 + q * 8 + k0);
            A[g] = __builtin_amdgcn_mfma_f32_16x16x32_bf16(a, b, A[g], 0, 0, 0);
        }
    }
    #pragma unroll
    for (int r = 0; r < 4; ++r) {
        int rowg = row0 + q * 4 + r;
        if (rowg < NN) {
            float dv = dinv[rowg];
            #pragma unroll
            for (int g = 0; g < 8; ++g) {
                int j = g * 16 + c;
                float pv = A[g][r];
                if (j < 40)       d0f[(size_t)rowg * 40 + j] = pv;
                else if (j < 120) zsp[(size_t)rowg * 80 + (j - 40)] = f2b(dv * pv);
                // j >= 120: dead (wcpt rows zero)
            }
        }
    }
}

// ================= SpMM A (packed 80-col rows; 2 edges/wave, 8 in flight) ==================
// u1[i] = di*(zs1[i] + sum zs1[c]);  wp[i] = di^2*(zs2[i] + sum zs2[c]) (prescaled, packed)
__global__ __launch_bounds__(256) void spmma_kernel(
    const unsigned* __restrict__ zs,     // [N][40] dwords = 80 bf16 cols (z1|z2)
    const int* __restrict__ rowptr, const int* __restrict__ cols,
    const float* __restrict__ dinv,
    float* __restrict__ u1b,             // [N][40] f32
    unsigned* __restrict__ wpb) {        // [N][20] dwords = 40 bf16
    int i = blockIdx.x * 4 + (threadIdx.x >> 6);
    if (i >= NN) return;
    int lane = threadIdx.x & 63;
    int h = lane >> 5, l = lane & 31;    // h = edge parity, l covers dwords 2l,2l+1
    if (l >= 20) return;                 // 80-B rows need 20 lanes/edge
    const float di = dinv[i];
    const unsigned* base = zs + l * 2;

    float a0 = 0.f, a1 = 0.f, a2 = 0.f, a3 = 0.f;
    float b0 = 0.f, b1 = 0.f, b2 = 0.f, b3 = 0.f;
    if (h == 0) {   // self-seed (prescaled), counted once
        uint2 u = *(const uint2*)(zs + (size_t)i * 40 + l * 2);
        a0 = blo(u.x); a1 = bhi(u.x); a2 = blo(u.y); a3 = bhi(u.y);
    }
    int k = rowptr[i], e = rowptr[i + 1];
    for (; k + 8 <= e; k += 8) {   // 8 edges in flight: 4 gathers/lane, 2 banks
        int c0 = cols[k + h], c1 = cols[k + 2 + h], c2 = cols[k + 4 + h], c3 = cols[k + 6 + h];
        uint2 g0 = *(const uint2*)(base + (size_t)c0 * 40);
        uint2 g1 = *(const uint2*)(base + (size_t)c1 * 40);
        uint2 g2 = *(const uint2*)(base + (size_t)c2 * 40);
        uint2 g3 = *(const uint2*)(base + (size_t)c3 * 40);
        a0 += blo(g0.x); a1 += bhi(g0.x); a2 += blo(g0.y); a3 += bhi(g0.y);
        b0 += blo(g1.x); b1 += bhi(g1.x); b2 += blo(g1.y); b3 += bhi(g1.y);
        a0 += blo(g2.x); a1 += bhi(g2.x); a2 += blo(g2.y); a3 += bhi(g2.y);
        b0 += blo(g3.x); b1 += bhi(g3.x); b2 += blo(g3.y); b3 += bhi(g3.y);
    }
    for (; k + 2 <= e; k += 2) {
        int cc = cols[k + h];
        uint2 g = *(const uint2*)(base + (size_t)cc * 40);
        a0 += blo(g.x); a1 += bhi(g.x); a2 += blo(g.y); a3 += bhi(g.y);
    }
    if (k < e && h == 0) {         // odd tail edge
        int cc = cols[k];
        uint2 g = *(const uint2*)(base + (size_t)cc * 40);
        a0 += blo(g.x); a1 += bhi(g.x); a2 += blo(g.y); a3 += bhi(g.y);
    }
    a0 += b0; a1 += b1; a2 += b2; a3 += b3;
    a0 += __shfl_xor(a0, 32, 64); a1 += __shfl_xor(a1, 32, 64);
    a2 += __shfl_xor(a2, 32, 64); a3 += __shfl_xor(a3, 32, 64);
    if (h == 0) {
        if (l < 10) {                        // z1 dwords 2l,2l+1 = cols 4l..4l+3 -> u1 f32
            float4 o; o.x = di * a0; o.y = di * a1; o.z = di * a2; o.w = di * a3;
            *(float4*)(u1b + (size_t)i * 40 + l * 4) = o;
        } else {                             // z2 dwords -> wp (packed 20 dwords)
            float s = di * di;
            uint2 o;
            o.x = ((unsigned)f2b(s * a1) << 16) | f2b(s * a0);
            o.y = ((unsigned)f2b(s * a3) << 16) | f2b(s * a2);
            *(uint2*)(wpb + (size_t)i * 20 + (size_t)(l - 10) * 2) = o;
        }
    }
}

// ================= SpMM B (packed 20-dword rows; 2 edges/wave, 8 in flight) + softmax ======
// u2[i] = di*(wp[i] + sum wp[c]);  out = log_softmax(d0 + u1 + u2 + b2)
__global__ __launch_bounds__(256) void spmmb_kernel(
    const unsigned* __restrict__ wpb,    // [N][20] dwords
    const int* __restrict__ rowptr, const int* __restrict__ cols,
    const float* __restrict__ dinv, const float* __restrict__ d0f,
    const float* __restrict__ u1b, const float* __restrict__ b2p,
    float* __restrict__ out) {
    int i = blockIdx.x * 4 + (threadIdx.x >> 6);
    if (i >= NN) return;
    int lane = threadIdx.x & 63;
    int h = lane >> 5, l = lane & 31;    // h = edge parity, l covers dword l (cols 2l,2l+1)
    const float di = dinv[i];
    bool lact = (l < 20);
    const unsigned* base = wpb + l;

    float a0 = 0.f, a1 = 0.f;
    float b0 = 0.f, b1 = 0.f;
    if (lact && h == 0) {   // self-seed (prescaled), counted once
        unsigned u = wpb[(size_t)i * 20 + l];
        a0 = blo(u); a1 = bhi(u);
    }
    if (lact) {
        int k = rowptr[i], e = rowptr[i + 1];
        for (; k + 8 <= e; k += 8) {   // 8 edges in flight: 4 loads/lane, 2 banks
            int c0 = cols[k + h], c1 = cols[k + 2 + h], c2 = cols[k + 4 + h], c3 = cols[k + 6 + h];
            unsigned g0 = base[(size_t)c0 * 20];
            unsigned g1 = base[(size_t)c1 * 20];
            unsigned g2 = base[(size_t)c2 * 20];
            unsigned g3 = base[(size_t)c3 * 20];
            a0 += blo(g0); a1 += bhi(g0);
            b0 += blo(g1); b1 += bhi(g1);
            a0 += blo(g2); a1 += bhi(g2);
            b0 += blo(g3); b1 += bhi(g3);
        }
        for (; k + 2 <= e; k += 2) {
            unsigned g = base[(size_t)cols[k + h] * 20];
            a0 += blo(g); a1 += bhi(g);
        }
        if (k < e && h == 0) {
            unsigned g = base[(size_t)cols[k] * 20];
            a0 += blo(g); a1 += bhi(g);
        }
        a0 += b0; a1 += b1;
        a0 += __shfl_xor(a0, 32, 64);
        a1 += __shfl_xor(a1, 32, 64);
    }
    float vx = -1e30f, vy = -1e30f;
    bool act = lact && (h == 0);
    if (act) {
        float2 dd = *(const float2*)(d0f + (size_t)i * 40 + l * 2);
        float2 uu = *(const float2*)(u1b + (size_t)i * 40 + l * 2);
        float2 bb = *(const float2*)(b2p + l * 2);
        vx = dd.x + uu.x + di * a0 + bb.x;
        vy = dd.y + uu.y + di * a1 + bb.y;
    }
    float mx = fmaxf(vx, vy);
    #pragma unroll
    for (int d = 1; d < 32; d <<= 1) mx = fmaxf(mx, __shfl_xor(mx, d, 64));
    float s = act ? (__expf(vx - mx) + __expf(vy - mx)) : 0.f;
    #pragma unroll
    for (int d = 1; d < 32; d <<= 1) s += __shfl_xor(s, d, 64);
    float lse = mx + __logf(s);
    if (act) {
        float2 o; o.x = vx - lse; o.y = vy - lse;
        *(float2*)(out + (size_t)i * 40 + l * 2) = o;
    }
}

extern "C" void kernel_launch(void* const* d_in, const int* in_sizes, int n_in,
                              void* d_out, int out_size, void* d_ws, size_t ws_size,
                              hipStream_t stream) {
    const float* x  = (const float*)d_in[0];
    const int*   er = (const int*)d_in[1];
    const int*   ec = (const int*)d_in[2];
    const float* W1 = (const float*)d_in[3];
    const float* b1 = (const float*)d_in[4];
    const float* W2 = (const float*)d_in[5];
    const float* b2 = (const float*)d_in[6];
    float* out = (float*)d_out;

    char* p = (char*)d_ws;
    auto alloc = [&](size_t bytes) { char* r = p; p += (bytes + 255) & ~((size_t)255); return r; };
    int*      cntI   = (int*)      alloc((size_t)NN * 4);
    int*      degI   = (int*)      alloc((size_t)NN * 4);
    int*      rowptr = (int*)      alloc((size_t)(NN + 1) * 4);
    float*    dinv   = (float*)    alloc((size_t)NN * 4);
    int*      bsum   = (int*)      alloc((size_t)SCAN_NB * 4);
    int*      boff   = (int*)      alloc((size_t)SCAN_NB * 4);
    unsigned char* rank = (unsigned char*)alloc((size_t)NE);
    int*      colss  = (int*)      alloc((size_t)NE * 4);
    unsigned* hist_row = (unsigned*)alloc((size_t)CB * HWRD * 4);   // 12.8MB, dead after prep
    unsigned* hist_col = (unsigned*)alloc((size_t)CB * HWRD * 4);   // 12.8MB, dead after prep
    unsigned* base_w   = (unsigned*)alloc((size_t)CB * HWRD * 4);   // 12.8MB, dead after mega2
    unsigned short* w1t  = (unsigned short*)alloc((size_t)512 * 512 * 2);
    unsigned short* wcpt = (unsigned short*)alloc((size_t)128 * 512 * 2);
    unsigned short* xb   = (unsigned short*)alloc((size_t)NN * FI * 2);   // 51.2MB
    unsigned short* tbuf = (unsigned short*)alloc((size_t)NN * FI * 2);   // 51.2MB
    unsigned short* zsp  = (unsigned short*)alloc((size_t)NN * 80 * 2);   // 8MB packed
    float*    d0f  = (float*)alloc((size_t)NN * 40 * 4);                  // 8MB
    float*    u1b  = (float*)alloc((size_t)NN * 40 * 4);                  // 8MB
    unsigned* wpb  = (unsigned*)alloc((size_t)NN * 20 * 4);               // 4MB packed

    // L1: independent prep work, count parts first
    mega1_kernel<<<2 * CB + 12500 + 1024 + 256, 256, 0, stream>>>(
        er, ec, x, W1, W2, rank, hist_row, hist_col, xb, w1t, wcpt);
    // L2: cross-block prefix (rows) + reduce (cols)
    prep_kernel<<<(2 * HWRD + 255) / 256, 256, 0, stream>>>(hist_row, hist_col, base_w, cntI, degI);
    // L3-5: rowptr scan + dinv
    scan1_kernel<<<SCAN_NB, 1024, 0, stream>>>(cntI, rowptr, bsum);
    scan2_kernel<<<1, 64, 0, stream>>>(bsum, boff);
    scan3_kernel<<<(NN + 255) / 256, 256, 0, stream>>>(rowptr, boff, degI, dinv);
    // L6: scatter | gemm1 (128x64 tiles, XCD-affine n-tiles) -> tbuf bf16
    mega2_kernel<<<CB + GEMMB, 256, 0, stream>>>(
        er, ec, rowptr, rank, (const unsigned char*)base_w, colss, xb, w1t, b1, tbuf);
    // L7: projection GEMM -> d0 + prescaled packed [z1|z2]
    proj_kernel<<<(NN + 63) / 64, 256, 0, stream>>>(tbuf, wcpt, dinv, d0f, zsp);
    // L8: SpMM over packed 80-col z -> u1 + prescaled packed w
    spmma_kernel<<<(NN + 3) / 4, 256, 0, stream>>>((const unsigned*)zsp, rowptr, colss, dinv, u1b, wpb);
    // L9: SpMM over packed 40-col w + fused logits/log_softmax
    spmmb_kernel<<<(NN + 3) / 4, 256, 0, stream>>>(wpb, rowptr, colss, dinv, d0f, u1b, b2, out);
}

// Round 13
// 437.449 us; speedup vs baseline: 1.7969x; 1.0423x over previous
//
#include <hip/hip_runtime.h>
#include <stdint.h>

#define NN 50000
#define NE 1600000
#define FI 512
#define DD 512
#define NC 40
#define SCAN_NB 49        // ceil(NN/1024)
#define CB 256            // histogram blocks
#define EPB (NE / CB)     // 6250 edges per histogram block
#define HWRD 12500        // 50000 bins / 4 bytes per word
#define MT 391            // m-tiles (128 rows)
#define GEMMB 3136        // 8 xcd * 392 slots (m/8-major, n minor)

typedef __attribute__((ext_vector_type(8))) short short8;
typedef __attribute__((ext_vector_type(4))) float float4v;
typedef __attribute__((ext_vector_type(2))) float f32x2;

static __device__ __forceinline__ unsigned short f2b(float f) {
    union { float f; unsigned int i; } v; v.f = f;
    unsigned int r = v.i + 0x7fffu + ((v.i >> 16) & 1u);
    return (unsigned short)(r >> 16);
}
static __device__ __forceinline__ float blo(unsigned int u) {
    union { unsigned int i; float f; } v; v.i = u << 16; return v.f;
}
static __device__ __forceinline__ float bhi(unsigned int u) {
    union { unsigned int i; float f; } v; v.i = u & 0xffff0000u; return v.f;
}
static __device__ __forceinline__ unsigned char f2e4m3(float f) {
    return (unsigned char)(__builtin_amdgcn_cvt_pk_fp8_f32(f, f, 0, false) & 0xFF);
}
static __device__ __forceinline__ void async_copy16(void* lds, const void* g) {
    __builtin_amdgcn_global_load_lds((const __attribute__((address_space(1))) void*)g,
                                     (__attribute__((address_space(3))) void*)lds, 16, 0, 0);
}

// decode uint2 (8 fp8) and accumulate into 8 scalar accumulators
#define D8(g, A0, A1, A2, A3, A4, A5, A6, A7)                               \
    {   f32x2 p0 = __builtin_amdgcn_cvt_pk_f32_fp8((int)(g).x, false);      \
        f32x2 p1 = __builtin_amdgcn_cvt_pk_f32_fp8((int)(g).x, true);       \
        f32x2 p2 = __builtin_amdgcn_cvt_pk_f32_fp8((int)(g).y, false);      \
        f32x2 p3 = __builtin_amdgcn_cvt_pk_f32_fp8((int)(g).y, true);       \
        A0 += p0.x; A1 += p0.y; A2 += p1.x; A3 += p1.y;                     \
        A4 += p2.x; A5 += p2.y; A6 += p3.x; A7 += p3.y; }

// ================= MEGA1: [count_row | count_col | convx | transpose | wcpt] =================
__global__ __launch_bounds__(256) void mega1_kernel(
    const int* __restrict__ er, const int* __restrict__ ec,
    const float* __restrict__ x, const float* __restrict__ W1, const float* __restrict__ W2,
    unsigned char* __restrict__ rank, unsigned* __restrict__ hist_row, unsigned* __restrict__ hist_col,
    unsigned short* __restrict__ xb, unsigned short* __restrict__ w1t, unsigned short* __restrict__ wcpt) {
    __shared__ unsigned hb[HWRD];
    int bid = blockIdx.x, tid = threadIdx.x;
    if (bid < 2 * CB) {
        for (int w = tid; w < HWRD; w += 256) hb[w] = 0;
        __syncthreads();
        int b = bid & (CB - 1);
        int e0 = b * EPB;
        if (bid < CB) {   // row histogram + rank
            for (int e = e0 + tid; e < e0 + EPB; e += 256) {
                int r = er[e];
                unsigned sh = (r & 3) * 8;
                unsigned old = atomicAdd(&hb[r >> 2], 1u << sh);
                rank[e] = (unsigned char)((old >> sh) & 0xFFu);
            }
        } else {          // col histogram (in-degree)
            for (int e = e0 + tid; e < e0 + EPB; e += 256) {
                int c = ec[e];
                atomicAdd(&hb[c >> 2], 1u << ((c & 3) * 8));
            }
        }
        __syncthreads();
        unsigned* dst = (bid < CB ? hist_row : hist_col) + (size_t)b * HWRD;
        for (int w = tid; w < HWRD; w += 256) dst[w] = hb[w];
        return;
    }
    bid -= 2 * CB;
    if (bid < 12500) {    // convx: fp32 -> bf16, 8 elems/thread
        int t = bid * 256 + tid;
        const float* xf = x + (size_t)t * 8;
        float4 v0 = *(const float4*)(xf);
        float4 v1 = *(const float4*)(xf + 4);
        uint4 u;
        u.x = ((unsigned)f2b(v0.y) << 16) | f2b(v0.x);
        u.y = ((unsigned)f2b(v0.w) << 16) | f2b(v0.z);
        u.z = ((unsigned)f2b(v1.y) << 16) | f2b(v1.x);
        u.w = ((unsigned)f2b(v1.w) << 16) | f2b(v1.z);
        *(uint4*)(xb + (size_t)t * 8) = u;
        return;
    }
    bid -= 12500;
    if (bid < 1024) {     // transpose W1 -> bf16 w1t[n][k]
        int t = bid * 256 + tid;
        int n = t & 511, k = t >> 9;
        w1t[n * 512 + k] = f2b(W1[(size_t)k * 512 + n]);
        return;
    }
    bid -= 1024;
    {                     // wcpt builder: 128*512 elems, 256 blocks
        int t = bid * 256 + tid;   // < 65536 always
        int n = t >> 9, k = t & 511;
        float v = 0.f;
        if (n < 40)       v = W2[(size_t)k * NC + n] + W2[(size_t)(k + 512) * NC + n];
        else if (n < 80)  v = W2[(size_t)(k + 1024) * NC + (n - 40)] + W2[(size_t)(k + 1536) * NC + (n - 40)];
        else if (n < 120) v = W2[(size_t)(k + 2048) * NC + (n - 80)];
        wcpt[n * 512 + k] = f2b(v);
    }
}

// ================= PREP: SWAR prefix over blocks (rows) + reduce (cols) =================
__global__ __launch_bounds__(256) void prep_kernel(
    const unsigned* __restrict__ hist_row, const unsigned* __restrict__ hist_col,
    unsigned* __restrict__ base_words, int* __restrict__ cntI, int* __restrict__ degI) {
    int t = blockIdx.x * 256 + threadIdx.x;
    if (t < HWRD) {
        unsigned acc = 0;   // 4 packed byte counters; totals <256/byte so no carry
        for (int b = 0; b < CB; ++b) {
            unsigned h = hist_row[(size_t)b * HWRD + t];
            base_words[(size_t)b * HWRD + t] = acc;
            acc += h;
        }
        int4 o; o.x = acc & 0xFF; o.y = (acc >> 8) & 0xFF; o.z = (acc >> 16) & 0xFF; o.w = (acc >> 24) & 0xFF;
        ((int4*)cntI)[t] = o;
    } else if (t < 2 * HWRD) {
        int w = t - HWRD;
        unsigned acc = 0;
        for (int b = 0; b < CB; ++b) acc += hist_col[(size_t)b * HWRD + w];
        int4 o; o.x = acc & 0xFF; o.y = (acc >> 8) & 0xFF; o.z = (acc >> 16) & 0xFF; o.w = (acc >> 24) & 0xFF;
        ((int4*)degI)[w] = o;
    }
}

// ================= scans =================
__global__ __launch_bounds__(1024) void scan1_kernel(const int* __restrict__ cnt,
                                                     int* __restrict__ excl, int* __restrict__ bsum) {
    __shared__ int buf[1024];
    int tid = threadIdx.x, gid = blockIdx.x * 1024 + tid;
    int v = (gid < NN) ? cnt[gid] : 0;
    buf[tid] = v;
    __syncthreads();
    int acc = v;
    for (int off = 1; off < 1024; off <<= 1) {
        int t = (tid >= off) ? buf[tid - off] : 0;
        __syncthreads();
        acc += t;
        buf[tid] = acc;
        __syncthreads();
    }
    if (gid < NN) excl[gid] = acc - v;
    if (tid == 1023) bsum[blockIdx.x] = acc;
}

__global__ void scan2_kernel(const int* __restrict__ bsum, int* __restrict__ boff) {
    int tid = threadIdx.x;  // one wave, SCAN_NB=49
    int orig = (tid < SCAN_NB) ? bsum[tid] : 0;
    int v = orig;
    #pragma unroll
    for (int off = 1; off < 64; off <<= 1) {
        int t = __shfl_up(v, off, 64);
        if (tid >= off) v += t;
    }
    if (tid < SCAN_NB) boff[tid] = v - orig;
}

__global__ void scan3_kernel(int* __restrict__ rowptr, const int* __restrict__ boff,
                             const int* __restrict__ deg, float* __restrict__ dinv) {
    int gid = blockIdx.x * 256 + threadIdx.x;
    if (gid < NN) {
        rowptr[gid] += boff[gid >> 10];
        dinv[gid] = rsqrtf((float)(deg[gid] + 1));
    }
    if (gid == 0) rowptr[NN] = NE;
}

// ================= MEGA2: [scatter | gemm1 128x64, XCD-affine]  (R12 proven) ===============
__global__ __launch_bounds__(256) void mega2_kernel(
    const int* __restrict__ er, const int* __restrict__ ec, const int* __restrict__ rowptr,
    const unsigned char* __restrict__ rank, const unsigned char* __restrict__ base8,
    int* __restrict__ colss,
    const unsigned short* __restrict__ xb, const unsigned short* __restrict__ w1t,
    const float* __restrict__ b1, unsigned short* __restrict__ tbuf) {
    __shared__ __align__(16) unsigned short As[128 * 32];
    __shared__ __align__(16) unsigned short Bs[64 * 32];
    int bid = blockIdx.x;
    if (bid < CB) {   // scatter (atomic-free), one histogram slice per block
        int tid = threadIdx.x;
        const unsigned char* bb = base8 + (size_t)bid * 50000;
        int e0 = bid * EPB;
        int e = e0 + tid;
        #pragma unroll 4
        for (int it = 0; it < EPB / 256; ++it, e += 256) {
            int r = er[e], c = ec[e];
            colss[rowptr[r] + (int)bb[r] + (int)rank[e]] = c;
        }
        if (e < e0 + EPB) {   // tail: EPB % 256 = 106 edges
            int r = er[e], c = ec[e];
            colss[rowptr[r] + (int)bb[r] + (int)rank[e]] = c;
        }
        return;
    }
    // ---- gemm1: t = relu(x@W1+b1) -> tbuf bf16 ----
    int gb = bid - CB;                      // 0..GEMMB-1
    int xcd = gb & 7, slot = gb >> 3;       // slot in [0,392)
    int m = xcd + 8 * (slot >> 3), n = slot & 7;
    if (m >= MT) return;
    const int m0 = m * 128, n0 = n * 64;
    const int tid = threadIdx.x;
    const int wave = tid >> 6, lane = tid & 63;
    const int q = lane >> 4, c = lane & 15;
    const int wm = wave & 1, wn = wave >> 1;   // 2m x 2n wave grid

    float4v acc[4][2];
    #pragma unroll
    for (int i = 0; i < 4; ++i)
        #pragma unroll
        for (int j = 0; j < 2; ++j)
            acc[i][j] = (float4v){0.f, 0.f, 0.f, 0.f};

    for (int k0 = 0; k0 < FI; k0 += 32) {
        __syncthreads();
        #pragma unroll
        for (int h = 0; h < 2; ++h) {       // A: 512 chunks of 16B
            int chunk = h * 256 + wave * 64 + lane;
            int r = chunk >> 2, kc = chunk & 3;
            int gm = m0 + r; gm = gm < NN ? gm : NN - 1;
            async_copy16((char*)As + (size_t)chunk * 16,
                         xb + (size_t)gm * FI + k0 + kc * 8);
        }
        {                                    // B: 256 chunks of 16B
            int chunk = wave * 64 + lane;
            int rb = chunk >> 2, kb = chunk & 3;
            async_copy16((char*)Bs + (size_t)chunk * 16,
                         w1t + (size_t)(n0 + rb) * FI + k0 + kb * 8);
        }
        __syncthreads();
        short8 a[4], b[2];
        #pragma unroll
        for (int mi = 0; mi < 4; ++mi)
            a[mi] = *(const short8*)(As + ((wm * 64 + mi * 16 + c) * 32 + q * 8));
        #pragma unroll
        for (int ni = 0; ni < 2; ++ni)
            b[ni] = *(const short8*)(Bs + ((wn * 32 + ni * 16 + c) * 32 + q * 8));
        #pragma unroll
        for (int mi = 0; mi < 4; ++mi)
            #pragma unroll
            for (int ni = 0; ni < 2; ++ni)
                acc[mi][ni] = __builtin_amdgcn_mfma_f32_16x16x32_bf16(a[mi], b[ni], acc[mi][ni], 0, 0, 0);
    }
    #pragma unroll
    for (int ni = 0; ni < 2; ++ni) {
        int col = n0 + wn * 32 + ni * 16 + c;
        float bias = b1[col];
        #pragma unroll
        for (int mi = 0; mi < 4; ++mi) {
            int rbase = m0 + wm * 64 + mi * 16 + q * 4;
            #pragma unroll
            for (int r = 0; r < 4; ++r) {
                int row = rbase + r;
                if (row < NN) {
                    float v = acc[mi][ni][r] + bias;
                    v = v > 0.f ? v : 0.f;
                    tbuf[(size_t)row * FI + col] = f2b(v);
                }
            }
        }
    }
}

// ================= PROJ: [d0 | z1 | z2] = t @ wcpt^T  -> fp8 packed zsp (80 B/row) =========
__global__ __launch_bounds__(256) void proj_kernel(
    const unsigned short* __restrict__ tb, const unsigned short* __restrict__ wcpt,
    const float* __restrict__ dinv, float* __restrict__ d0f,
    unsigned char* __restrict__ zs8) {
    int wave = threadIdx.x >> 6, lane = threadIdx.x & 63;
    int q = lane >> 4, c = lane & 15;
    int row0 = blockIdx.x * 64 + wave * 16;
    int ra = row0 + c; ra = ra < NN ? ra : NN - 1;
    const unsigned short* ap = tb + (size_t)ra * FI + q * 8;

    float4v A[8];
    #pragma unroll
    for (int g = 0; g < 8; ++g) A[g] = (float4v){0.f, 0.f, 0.f, 0.f};
    #pragma unroll 2
    for (int k0 = 0; k0 < 512; k0 += 32) {
        short8 a = *(const short8*)(ap + k0);
        #pragma unroll
        for (int g = 0; g < 8; ++g) {
            short8 b = *(const short8*)(wcpt + (size_t)(g * 16 + c) * 512 + q * 8 + k0);
            A[g] = __builtin_amdgcn_mfma_f32_16x16x32_bf16(a, b, A[g], 0, 0, 0);
        }
    }
    #pragma unroll
    for (int r = 0; r < 4; ++r) {
        int rowg = row0 + q * 4 + r;
        if (rowg < NN) {
            float dv = dinv[rowg];
            #pragma unroll
            for (int g = 0; g < 8; ++g) {
                int j = g * 16 + c;
                float pv = A[g][r];
                if (j < 40)       d0f[(size_t)rowg * 40 + j] = pv;
                else if (j < 120) zs8[(size_t)rowg * 80 + (j - 40)] = f2e4m3(dv * pv);
                // j >= 120: dead (wcpt rows zero)
            }
        }
    }
}

// ================= SpMM A (fp8 80B rows; 4 edge slots x 10 lanes, 8 in flight) =============
// u1[i] = di*(zs1[i] + sum zs1[c]);  wp8[i] = fp8( di^2*(zs2[i] + sum zs2[c]) )
__global__ __launch_bounds__(256) void spmma_kernel(
    const unsigned char* __restrict__ zs8,   // [N][80] bytes (z1|z2 fp8, prescaled)
    const int* __restrict__ rowptr, const int* __restrict__ cols,
    const float* __restrict__ dinv,
    float* __restrict__ u1b,                 // [N][40] f32
    unsigned char* __restrict__ wp8) {       // [N][40] bytes fp8
    int i = blockIdx.x * 4 + (threadIdx.x >> 6);
    if (i >= NN) return;
    int lane = threadIdx.x & 63;
    int q = lane >> 4, l = lane & 15;        // 4 edge slots; lanes 0..9 active (8 cols each)
    bool lact = (l < 10);
    const float di = dinv[i];
    const unsigned char* base = zs8 + l * 8;

    float a0 = 0.f, a1 = 0.f, a2 = 0.f, a3 = 0.f, a4 = 0.f, a5 = 0.f, a6 = 0.f, a7 = 0.f;
    float b0 = 0.f, b1 = 0.f, b2 = 0.f, b3 = 0.f, b4 = 0.f, b5 = 0.f, b6 = 0.f, b7 = 0.f;
    if (lact && q == 0) {   // self-seed (prescaled), counted once
        uint2 u = *(const uint2*)(zs8 + (size_t)i * 80 + l * 8);
        D8(u, a0, a1, a2, a3, a4, a5, a6, a7)
    }
    if (lact) {
        int k = rowptr[i], e = rowptr[i + 1];
        for (; k + 8 <= e; k += 8) {   // 8 edges in flight: 2 gathers/lane, 2 banks
            int c0 = cols[k + q], c1 = cols[k + 4 + q];
            uint2 g0 = *(const uint2*)(base + (size_t)c0 * 80);
            uint2 g1 = *(const uint2*)(base + (size_t)c1 * 80);
            D8(g0, a0, a1, a2, a3, a4, a5, a6, a7)
            D8(g1, b0, b1, b2, b3, b4, b5, b6, b7)
        }
        for (; k + 4 <= e; k += 4) {
            int cc = cols[k + q];
            uint2 g = *(const uint2*)(base + (size_t)cc * 80);
            D8(g, a0, a1, a2, a3, a4, a5, a6, a7)
        }
        if (k + q < e) {               // tail (<4 edges), slot q takes edge k+q
            int cc = cols[k + q];
            uint2 g = *(const uint2*)(base + (size_t)cc * 80);
            D8(g, a0, a1, a2, a3, a4, a5, a6, a7)
        }
        a0 += b0; a1 += b1; a2 += b2; a3 += b3;
        a4 += b4; a5 += b5; a6 += b6; a7 += b7;
    }
    // merge 4 slots
    a0 += __shfl_xor(a0, 16, 64); a1 += __shfl_xor(a1, 16, 64);
    a2 += __shfl_xor(a2, 16, 64); a3 += __shfl_xor(a3, 16, 64);
    a4 += __shfl_xor(a4, 16, 64); a5 += __shfl_xor(a5, 16, 64);
    a6 += __shfl_xor(a6, 16, 64); a7 += __shfl_xor(a7, 16, 64);
    a0 += __shfl_xor(a0, 32, 64); a1 += __shfl_xor(a1, 32, 64);
    a2 += __shfl_xor(a2, 32, 64); a3 += __shfl_xor(a3, 32, 64);
    a4 += __shfl_xor(a4, 32, 64); a5 += __shfl_xor(a5, 32, 64);
    a6 += __shfl_xor(a6, 32, 64); a7 += __shfl_xor(a7, 32, 64);
    if (q == 0 && lact) {
        if (l < 5) {                         // z1 cols l*8..l*8+7 -> u1 f32
            float4 o1; o1.x = di * a0; o1.y = di * a1; o1.z = di * a2; o1.w = di * a3;
            float4 o2; o2.x = di * a4; o2.y = di * a5; o2.z = di * a6; o2.w = di * a7;
            *(float4*)(u1b + (size_t)i * 40 + l * 8) = o1;
            *(float4*)(u1b + (size_t)i * 40 + l * 8 + 4) = o2;
        } else {                             // z2 cols -> wp8 fp8 (prescaled by di^2)
            float s = di * di;
            unsigned r0 = (unsigned)__builtin_amdgcn_cvt_pk_fp8_f32(s * a0, s * a1, 0, false);
            r0 = (unsigned)__builtin_amdgcn_cvt_pk_fp8_f32(s * a2, s * a3, (int)r0, true);
            unsigned r1 = (unsigned)__builtin_amdgcn_cvt_pk_fp8_f32(s * a4, s * a5, 0, false);
            r1 = (unsigned)__builtin_amdgcn_cvt_pk_fp8_f32(s * a6, s * a7, (int)r1, true);
            uint2 o; o.x = r0; o.y = r1;
            *(uint2*)(wp8 + (size_t)i * 40 + (size_t)(l - 5) * 8) = o;
        }
    }
}

// ================= SpMM B (fp8 40B rows; 8 edge slots x 5 lanes) + logits + softmax ========
// u2[i] = di*(wp[i] + sum wp[c]);  out = log_softmax(d0 + u1 + u2 + b2)
__global__ __launch_bounds__(256) void spmmb_kernel(
    const unsigned char* __restrict__ wp8,   // [N][40] bytes fp8 (prescaled)
    const int* __restrict__ rowptr, const int* __restrict__ cols,
    const float* __restrict__ dinv, const float* __restrict__ d0f,
    const float* __restrict__ u1b, const float* __restrict__ b2p,
    float* __restrict__ out) {
    int i = blockIdx.x * 4 + (threadIdx.x >> 6);
    if (i >= NN) return;
    int lane = threadIdx.x & 63;
    int q = lane >> 3, l = lane & 7;         // 8 edge slots; lanes 0..4 active (8 cols each)
    bool lact = (l < 5);
    const float di = dinv[i];
    const unsigned char* base = wp8 + l * 8;

    float a0 = 0.f, a1 = 0.f, a2 = 0.f, a3 = 0.f, a4 = 0.f, a5 = 0.f, a6 = 0.f, a7 = 0.f;
    float b0 = 0.f, b1 = 0.f, b2 = 0.f, b3 = 0.f, b4 = 0.f, b5 = 0.f, b6 = 0.f, b7 = 0.f;
    if (lact && q == 0) {   // self-seed (prescaled), counted once
        uint2 u = *(const uint2*)(wp8 + (size_t)i * 40 + l * 8);
        D8(u, a0, a1, a2, a3, a4, a5, a6, a7)
    }
    if (lact) {
        int k = rowptr[i], e = rowptr[i + 1];
        for (; k + 16 <= e; k += 16) {   // 16 edges in flight: 2 loads/lane, 2 banks
            int c0 = cols[k + q], c1 = cols[k + 8 + q];
            uint2 g0 = *(const uint2*)(base + (size_t)c0 * 40);
            uint2 g1 = *(const uint2*)(base + (size_t)c1 * 40);
            D8(g0, a0, a1, a2, a3, a4, a5, a6, a7)
            D8(g1, b0, b1, b2, b3, b4, b5, b6, b7)
        }
        for (; k + 8 <= e; k += 8) {
            int cc = cols[k + q];
            uint2 g = *(const uint2*)(base + (size_t)cc * 40);
            D8(g, a0, a1, a2, a3, a4, a5, a6, a7)
        }
        if (k + q < e) {                 // tail (<8 edges), slot q takes edge k+q
            int cc = cols[k + q];
            uint2 g = *(const uint2*)(base + (size_t)cc * 40);
            D8(g, a0, a1, a2, a3, a4, a5, a6, a7)
        }
        a0 += b0; a1 += b1; a2 += b2; a3 += b3;
        a4 += b4; a5 += b5; a6 += b6; a7 += b7;
    }
    // merge 8 slots
    #pragma unroll
    for (int d = 8; d < 64; d <<= 1) {
        a0 += __shfl_xor(a0, d, 64); a1 += __shfl_xor(a1, d, 64);
        a2 += __shfl_xor(a2, d, 64); a3 += __shfl_xor(a3, d, 64);
        a4 += __shfl_xor(a4, d, 64); a5 += __shfl_xor(a5, d, 64);
        a6 += __shfl_xor(a6, d, 64); a7 += __shfl_xor(a7, d, 64);
    }
    float v0 = -1e30f, v1 = -1e30f, v2 = -1e30f, v3 = -1e30f;
    float v4 = -1e30f, v5 = -1e30f, v6 = -1e30f, v7 = -1e30f;
    bool act = (q == 0) && lact;
    if (act) {
        float4 dd0 = *(const float4*)(d0f + (size_t)i * 40 + l * 8);
        float4 dd1 = *(const float4*)(d0f + (size_t)i * 40 + l * 8 + 4);
        float4 uu0 = *(const float4*)(u1b + (size_t)i * 40 + l * 8);
        float4 uu1 = *(const float4*)(u1b + (size_t)i * 40 + l * 8 + 4);
        float4 bb0 = *(const float4*)(b2p + l * 8);
        float4 bb1 = *(const float4*)(b2p + l * 8 + 4);
        v0 = dd0.x + uu0.x + di * a0 + bb0.x;
        v1 = dd0.y + uu0.y + di * a1 + bb0.y;
        v2 = dd0.z + uu0.z + di * a2 + bb0.z;
        v3 = dd0.w + uu0.w + di * a3 + bb0.w;
        v4 = dd1.x + uu1.x + di * a4 + bb1.x;
        v5 = dd1.y + uu1.y + di * a5 + bb1.y;
        v6 = dd1.z + uu1.z + di * a6 + bb1.z;
        v7 = dd1.w + uu1.w + di * a7 + bb1.w;
    }
    float mx = fmaxf(fmaxf(fmaxf(v0, v1), fmaxf(v2, v3)), fmaxf(fmaxf(v4, v5), fmaxf(v6, v7)));
    #pragma unroll
    for (int d = 1; d < 8; d <<= 1) mx = fmaxf(mx, __shfl_xor(mx, d, 64));
    float s = act ? (__expf(v0 - mx) + __expf(v1 - mx) + __expf(v2 - mx) + __expf(v3 - mx)
                   + __expf(v4 - mx) + __expf(v5 - mx) + __expf(v6 - mx) + __expf(v7 - mx)) : 0.f;
    #pragma unroll
    for (int d = 1; d < 8; d <<= 1) s += __shfl_xor(s, d, 64);
    float lse = mx + __logf(s);
    if (act) {
        float4 o1; o1.x = v0 - lse; o1.y = v1 - lse; o1.z = v2 - lse; o1.w = v3 - lse;
        float4 o2; o2.x = v4 - lse; o2.y = v5 - lse; o2.z = v6 - lse; o2.w = v7 - lse;
        *(float4*)(out + (size_t)i * 40 + l * 8) = o1;
        *(float4*)(out + (size_t)i * 40 + l * 8 + 4) = o2;
    }
}

extern "C" void kernel_launch(void* const* d_in, const int* in_sizes, int n_in,
                              void* d_out, int out_size, void* d_ws, size_t ws_size,
                              hipStream_t stream) {
    const float* x  = (const float*)d_in[0];
    const int*   er = (const int*)d_in[1];
    const int*   ec = (const int*)d_in[2];
    const float* W1 = (const float*)d_in[3];
    const float* b1 = (const float*)d_in[4];
    const float* W2 = (const float*)d_in[5];
    const float* b2 = (const float*)d_in[6];
    float* out = (float*)d_out;

    char* p = (char*)d_ws;
    auto alloc = [&](size_t bytes) { char* r = p; p += (bytes + 255) & ~((size_t)255); return r; };
    int*      cntI   = (int*)      alloc((size_t)NN * 4);
    int*      degI   = (int*)      alloc((size_t)NN * 4);
    int*      rowptr = (int*)      alloc((size_t)(NN + 1) * 4);
    float*    dinv   = (float*)    alloc((size_t)NN * 4);
    int*      bsum   = (int*)      alloc((size_t)SCAN_NB * 4);
    int*      boff   = (int*)      alloc((size_t)SCAN_NB * 4);
    unsigned char* rank = (unsigned char*)alloc((size_t)NE);
    int*      colss  = (int*)      alloc((size_t)NE * 4);
    unsigned* hist_row = (unsigned*)alloc((size_t)CB * HWRD * 4);   // 12.8MB, dead after prep
    unsigned* hist_col = (unsigned*)alloc((size_t)CB * HWRD * 4);   // 12.8MB, dead after prep
    unsigned* base_w   = (unsigned*)alloc((size_t)CB * HWRD * 4);   // 12.8MB, dead after mega2
    unsigned short* w1t  = (unsigned short*)alloc((size_t)512 * 512 * 2);
    unsigned short* wcpt = (unsigned short*)alloc((size_t)128 * 512 * 2);
    unsigned short* xb   = (unsigned short*)alloc((size_t)NN * FI * 2);   // 51.2MB
    unsigned short* tbuf = (unsigned short*)alloc((size_t)NN * FI * 2);   // 51.2MB
    unsigned char*  zs8  = (unsigned char*)alloc((size_t)NN * 80);        // 4MB fp8 packed
    float*    d0f  = (float*)alloc((size_t)NN * 40 * 4);                  // 8MB
    float*    u1b  = (float*)alloc((size_t)NN * 40 * 4);                  // 8MB
    unsigned char* wp8 = (unsigned char*)alloc((size_t)NN * 40);          // 2MB fp8 packed

    // L1: independent prep work, count parts first
    mega1_kernel<<<2 * CB + 12500 + 1024 + 256, 256, 0, stream>>>(
        er, ec, x, W1, W2, rank, hist_row, hist_col, xb, w1t, wcpt);
    // L2: cross-block prefix (rows) + reduce (cols)
    prep_kernel<<<(2 * HWRD + 255) / 256, 256, 0, stream>>>(hist_row, hist_col, base_w, cntI, degI);
    // L3-5: rowptr scan + dinv
    scan1_kernel<<<SCAN_NB, 1024, 0, stream>>>(cntI, rowptr, bsum);
    scan2_kernel<<<1, 64, 0, stream>>>(bsum, boff);
    scan3_kernel<<<(NN + 255) / 256, 256, 0, stream>>>(rowptr, boff, degI, dinv);
    // L6: scatter | gemm1 (128x64 tiles, XCD-affine n-tiles) -> tbuf bf16
    mega2_kernel<<<CB + GEMMB, 256, 0, stream>>>(
        er, ec, rowptr, rank, (const unsigned char*)base_w, colss, xb, w1t, b1, tbuf);
    // L7: projection GEMM -> d0 f32 + fp8 packed prescaled [z1|z2]
    proj_kernel<<<(NN + 63) / 64, 256, 0, stream>>>(tbuf, wcpt, dinv, d0f, zs8);
    // L8: SpMM over fp8 80B rows (L2-resident 4MB) -> u1 + fp8 prescaled w
    spmma_kernel<<<(NN + 3) / 4, 256, 0, stream>>>(zs8, rowptr, colss, dinv, u1b, wp8);
    // L9: SpMM over fp8 40B rows (2MB) + fused logits/log_softmax
    spmmb_kernel<<<(NN + 3) / 4, 256, 0, stream>>>(wp8, rowptr, colss, dinv, d0f, u1b, b2, out);
}